// Round 9
// baseline (861.570 us; speedup 1.0000x reference)
//
#include <hip/hip_runtime.h>
#include <math.h>

#define NB   8
#define LLEN 2048
#define HDIM 1024
#define LNEPS 1e-5f

#define BM 256
#define BN 256
#define BK 64
#define NT_K (HDIM / BK)    // 16 bf16 K-tiles
#define NT_K8 (HDIM / 128)  // 8 fp8 K-tiles
#define NTHR 512
#define SLOT (BM * BK)      // 32 KiB per bf16 operand slot
#define SLOT8 32768         // 32 KiB per fp8 operand slot (256 rows x 128 B)

typedef __attribute__((ext_vector_type(8))) short short8;
typedef __attribute__((ext_vector_type(4))) unsigned short ushort4v;
typedef __attribute__((ext_vector_type(4))) float f32x4;
typedef __attribute__((ext_vector_type(4))) int int4v;
typedef __attribute__((ext_vector_type(8))) int int8v;
typedef __attribute__((ext_vector_type(8))) unsigned char uchar8;

typedef __attribute__((address_space(3))) void lds_void;
typedef const __attribute__((address_space(1))) void glob_void;

__device__ __forceinline__ unsigned short f2bf(float f) {
    union { float f; unsigned u; } v; v.f = f;
    unsigned r = v.u + 0x7FFFu + ((v.u >> 16) & 1u);
    return (unsigned short)(r >> 16);
}
__device__ __forceinline__ float bf2f(unsigned short h) {
    union { unsigned u; float f; } v; v.u = ((unsigned)h) << 16;
    return v.f;
}

// OCP e4m3fn encode, RNE (HW-verified numerically in round 8).
__device__ __forceinline__ unsigned char f2fp8(float x) {
    union { float f; unsigned u; } v; v.f = x;
    unsigned s = (v.u >> 24) & 0x80u;
    float a = fabsf(x);
    if (!(a < 448.f)) return (unsigned char)(s | 0x7E);
    int e = (int)((v.u >> 23) & 0xFF) - 127;
    if (e < -6) e = -6;
    float q = rintf(ldexpf(a, 3 - e));
    if (q >= 16.f) { q *= 0.5f; e += 1; }
    int qi = (int)q;
    unsigned byte = (qi < 8) ? (unsigned)qi
                             : (((unsigned)(e + 7) << 3) | (unsigned)(qi - 8));
    return (unsigned char)(s | byte);
}
// e4m3fn decode
__device__ __forceinline__ float fp8d(unsigned char b) {
    int e = (b >> 3) & 15, m = b & 7;
    float v = e ? ldexpf((float)(8 + m), e - 10) : ldexpf((float)m, -9);
    return (b & 0x80) ? -v : v;
}

__device__ __forceinline__ void wg_barrier() {
    asm volatile("" ::: "memory");
    __builtin_amdgcn_s_barrier();
    asm volatile("" ::: "memory");
}

// ---------------- bf16 pipeline (round-7, proven) ----------------
__device__ __forceinline__ void stage_tile(
    const unsigned short* __restrict__ src, int R0, int kcol0,
    unsigned short* ldsDst, int w, int lane)
{
    const int rsub = lane >> 3;
    const int csw  = 8 * ((lane & 7) ^ rsub);
    #pragma unroll
    for (int s = 0; s < 4; ++s) {
        const int r = (s*8 + w)*8 + rsub;
        const unsigned short* g = src + (size_t)(R0 + r) * HDIM + kcol0 + csw;
        __builtin_amdgcn_global_load_lds(
            (glob_void*)g, (lds_void*)(ldsDst + (s*8 + w)*512), 16, 0, 0);
    }
}

__device__ __forceinline__ void run_pipeline(
    const unsigned short* __restrict__ srcA,
    const unsigned short* __restrict__ srcB,
    int rowBase, int colBase,
    unsigned short* lds, f32x4 (&acc)[8][4])
{
    const int t = threadIdx.x, w = t >> 6, l = t & 63;
    const int wr = w >> 2, wc = w & 3;
    const int lr = l & 15;
    const int sw = (l & 7) << 4;
    const int aRB = (wr*128 + lr) * 128;
    const int bRB = (wc*64  + lr) * 128;
    const int c0 = ((l >> 4) * 16) ^ sw;
    const int c1 = (64 + ((l >> 4) * 16)) ^ sw;

    unsigned short* sA[2] = { lds,            lds + 2*SLOT };
    unsigned short* sB[2] = { lds + SLOT,     lds + 3*SLOT };

    stage_tile(srcA, rowBase, 0,  sA[0], w, l);
    stage_tile(srcB, colBase, 0,  sB[0], w, l);
    stage_tile(srcA, rowBase, BK, sA[1], w, l);
    stage_tile(srcB, colBase, BK, sB[1], w, l);
    asm volatile("s_waitcnt vmcnt(8)" ::: "memory");
    wg_barrier();

    for (int kt = 0; kt < NT_K; ++kt) {
        const char* bufA = (const char*)sA[kt & 1];
        const char* bufB = (const char*)sB[kt & 1];
        #pragma unroll
        for (int kk = 0; kk < 2; ++kk) {
            const int cc = kk ? c1 : c0;
            short8 af[8], bfr[4];
            #pragma unroll
            for (int mi = 0; mi < 8; ++mi)
                af[mi] = *(const short8*)(bufA + aRB + mi*2048 + cc);
            #pragma unroll
            for (int ni = 0; ni < 4; ++ni)
                bfr[ni] = *(const short8*)(bufB + bRB + ni*2048 + cc);
            #pragma unroll
            for (int mi = 0; mi < 8; ++mi)
                #pragma unroll
                for (int ni = 0; ni < 4; ++ni)
                    acc[mi][ni] = __builtin_amdgcn_mfma_f32_16x16x32_bf16(
                        af[mi], bfr[ni], acc[mi][ni], 0, 0, 0);
        }
        if (kt == NT_K - 1) break;
        wg_barrier();
        if (kt + 2 < NT_K) {
            stage_tile(srcA, rowBase, (kt+2)*BK, sA[kt&1], w, l);
            stage_tile(srcB, colBase, (kt+2)*BK, sB[kt&1], w, l);
            asm volatile("s_waitcnt vmcnt(8)" ::: "memory");
        } else {
            asm volatile("s_waitcnt vmcnt(0)" ::: "memory");
        }
        wg_barrier();
    }
}

// ---------------- fp8 pipeline (round-8, numerically proven) ----------------
__device__ __forceinline__ void stage_tile8(
    const unsigned char* __restrict__ src, int R0, int kcol0,
    unsigned char* ldsDst, int w, int lane)
{
    const int rsub = lane >> 3;
    const int csw  = ((lane & 7) ^ rsub) << 4;
    #pragma unroll
    for (int s = 0; s < 4; ++s) {
        const int r = (s*8 + w)*8 + rsub;
        __builtin_amdgcn_global_load_lds(
            (glob_void*)(src + (size_t)(R0 + r) * HDIM + kcol0 + csw),
            (lds_void*)(ldsDst + (s*8 + w)*1024), 16, 0, 0);
    }
}

// Only the PRODUCT of sa/sb matters (uniform e8m0 scales commute with the dot).
__device__ __forceinline__ void run_pipeline_fp8(
    const unsigned char* __restrict__ srcA,
    const unsigned char* __restrict__ srcB,
    int rowBase, int colBase,
    unsigned char* lds, f32x4 (&acc)[8][4],
    unsigned sa, unsigned sb)
{
    const int t = threadIdx.x, w = t >> 6, l = t & 63;
    const int wr = w >> 2, wc = w & 3;
    const int lr = l & 15;
    const int sw = (l & 7) << 4;
    const int aRB = (wr*128 + lr) * 128;
    const int bRB = (wc*64  + lr) * 128;
    const int g0 = (l >> 4) * 32;
    const int cc0 = g0 ^ sw;
    const int cc1 = (g0 + 16) ^ sw;

    unsigned char* sA[2] = { lds,             lds + 2*SLOT8 };
    unsigned char* sB[2] = { lds + SLOT8,     lds + 3*SLOT8 };

    stage_tile8(srcA, rowBase, 0,   sA[0], w, l);
    stage_tile8(srcB, colBase, 0,   sB[0], w, l);
    stage_tile8(srcA, rowBase, 128, sA[1], w, l);
    stage_tile8(srcB, colBase, 128, sB[1], w, l);
    asm volatile("s_waitcnt vmcnt(8)" ::: "memory");
    wg_barrier();

    for (int kt = 0; kt < NT_K8; ++kt) {
        const char* bufA = (const char*)sA[kt & 1];
        const char* bufB = (const char*)sB[kt & 1];
        int8v b8[4];
        #pragma unroll
        for (int ni = 0; ni < 4; ++ni) {
            int4v lo = *(const int4v*)(bufB + bRB + ni*2048 + cc0);
            int4v hi = *(const int4v*)(bufB + bRB + ni*2048 + cc1);
            b8[ni][0]=lo[0]; b8[ni][1]=lo[1]; b8[ni][2]=lo[2]; b8[ni][3]=lo[3];
            b8[ni][4]=hi[0]; b8[ni][5]=hi[1]; b8[ni][6]=hi[2]; b8[ni][7]=hi[3];
        }
        #pragma unroll
        for (int mi = 0; mi < 8; ++mi) {
            int4v lo = *(const int4v*)(bufA + aRB + mi*2048 + cc0);
            int4v hi = *(const int4v*)(bufA + aRB + mi*2048 + cc1);
            int8v a8;
            a8[0]=lo[0]; a8[1]=lo[1]; a8[2]=lo[2]; a8[3]=lo[3];
            a8[4]=hi[0]; a8[5]=hi[1]; a8[6]=hi[2]; a8[7]=hi[3];
            #pragma unroll
            for (int ni = 0; ni < 4; ++ni)
                acc[mi][ni] = __builtin_amdgcn_mfma_scale_f32_16x16x128_f8f6f4(
                    a8, b8[ni], acc[mi][ni], 0, 0, 0, sa, 0, sb);
        }
        if (kt == NT_K8 - 1) break;
        wg_barrier();
        if (kt + 2 < NT_K8) {
            stage_tile8(srcA, rowBase, (kt+2)*128, sA[kt&1], w, l);
            stage_tile8(srcB, colBase, (kt+2)*128, sB[kt&1], w, l);
            asm volatile("s_waitcnt vmcnt(8)" ::: "memory");
        } else {
            asm volatile("s_waitcnt vmcnt(0)" ::: "memory");
        }
        wg_barrier();
    }
}

// ---- bf16 multi-output GEMM (Wqk + FF) ----
__global__ __launch_bounds__(NTHR, 2) void gemm_proj(
    const unsigned short* __restrict__ A,
    const unsigned short* __restrict__ Bt,
    const float* __restrict__ bias0, const float* __restrict__ bias1,
    const float* __restrict__ bias2,
    unsigned short* __restrict__ C0, unsigned short* __restrict__ C1,
    unsigned short* __restrict__ C2,
    float al0, float al1, float al2, int gx)
{
    __shared__ __align__(16) unsigned short lds[4 * SLOT];
    const int nwg = gridDim.x, bid = blockIdx.x;
    const int swz = (bid & 7) * (nwg >> 3) + (bid >> 3);
    const int bx = swz % gx, by = swz / gx;
    const int rowBase = by * BM, colBase = bx * BN;

    f32x4 acc[8][4] = {};
    run_pipeline(A, Bt, rowBase, colBase, lds, acc);

    const int t = threadIdx.x, w = t >> 6, l = t & 63;
    const int wr = w >> 2, wc = w & 3;
    const int lr = l & 15;

    const int mat = colBase >> 10;
    unsigned short* Cm = (mat == 0) ? C0 : (mat == 1 ? C1 : C2);
    const float* bm    = (mat == 0) ? bias0 : (mat == 1 ? bias1 : bias2);
    const float am     = (mat == 0) ? al0 : (mat == 1 ? al1 : al2);
    const int lcb = colBase & (HDIM - 1);

    #pragma unroll
    for (int ni = 0; ni < 4; ++ni) {
        const int col = lcb + wc*64 + ni*16 + lr;
        const float bv = bm[col];
        #pragma unroll
        for (int mi = 0; mi < 8; ++mi) {
            const int row0 = rowBase + wr*128 + mi*16 + (l >> 4) * 4;
            #pragma unroll
            for (int j = 0; j < 4; ++j)
                Cm[(size_t)(row0 + j) * HDIM + col] = f2bf(am * (acc[mi][ni][j] + bv));
        }
    }
}

// ---- fp8 fused proj: [Xq8 | V8] = fp8( al_mat * (Xb8 @ W8^T + bias_mat) ) ----
__global__ __launch_bounds__(NTHR, 2) void gemm_proj_fp8(
    const unsigned char* __restrict__ A,
    const unsigned char* __restrict__ Bt,
    const float* __restrict__ bias0, const float* __restrict__ bias1,
    unsigned char* __restrict__ C0, unsigned char* __restrict__ C1,
    float al0, float al1, unsigned sb0, unsigned sb1, int gx)
{
    __shared__ __align__(16) unsigned char lds8[4 * SLOT8];
    const int nwg = gridDim.x, bid = blockIdx.x;
    const int swz = (bid & 7) * (nwg >> 3) + (bid >> 3);
    const int bx = swz % gx, by = swz / gx;
    const int rowBase = by * BM, colBase = bx * BN;

    const int mat = colBase >> 10;
    const unsigned sb = mat ? sb1 : sb0;

    f32x4 acc[8][4] = {};
    run_pipeline_fp8(A, Bt, rowBase, colBase, lds8, acc, 0x7F7F7F7Fu, sb);

    const int t = threadIdx.x, w = t >> 6, l = t & 63;
    const int wr = w >> 2, wc = w & 3;
    const int lr = l & 15;

    unsigned char* Cm  = mat ? C1 : C0;
    const float* bm    = mat ? bias1 : bias0;
    const float am     = mat ? al1 : al0;
    const int lcb = colBase & (HDIM - 1);

    #pragma unroll
    for (int ni = 0; ni < 4; ++ni) {
        const int col = lcb + wc*64 + ni*16 + lr;
        const float bv = bm[col];
        #pragma unroll
        for (int mi = 0; mi < 8; ++mi) {
            const int row0 = rowBase + wr*128 + mi*16 + (l >> 4) * 4;
            #pragma unroll
            for (int j = 0; j < 4; ++j)
                Cm[(size_t)(row0 + j) * HDIM + col] = f2fp8(am * (acc[mi][ni][j] + bv));
        }
    }
}

// ---- fp8 qk: S[a,b]=Xq8[a,:]·Xb8[b,:]*2^-10; colsum[b]+=sum_a exp(S+u[a]); diag=S ----
__global__ __launch_bounds__(NTHR, 2) void qk_colsum_diag_fp8(
    const unsigned char* __restrict__ Xq8,
    const unsigned char* __restrict__ Xb8,
    const float* __restrict__ uvec,
    float* __restrict__ colsum, float* __restrict__ diagv)
{
    __shared__ __align__(16) unsigned char lds8[4 * SLOT8];
    const int n = blockIdx.z;
    const unsigned char* An = Xq8 + (size_t)n * LLEN * HDIM;
    const unsigned char* Bn = Xb8 + (size_t)n * LLEN * HDIM;
    const int rowBase = blockIdx.y * BM;
    const int colBase = blockIdx.x * BN;

    f32x4 acc[8][4] = {};
    run_pipeline_fp8(An, Bn, rowBase, colBase, lds8, acc, 0x75757575u, 0x7F7F7F7Fu);

    const int t = threadIdx.x, w = t >> 6, l = t & 63;
    const int wr = w >> 2, wc = w & 3;
    const int lr = l & 15;

    float ur[8][4];
    #pragma unroll
    for (int mi = 0; mi < 8; ++mi)
        #pragma unroll
        for (int j = 0; j < 4; ++j)
            ur[mi][j] = uvec[(size_t)n * LLEN + rowBase + wr*128 + mi*16 + (l>>4)*4 + j];

    #pragma unroll
    for (int ni = 0; ni < 4; ++ni) {
        float s = 0.f;
        #pragma unroll
        for (int mi = 0; mi < 8; ++mi)
            #pragma unroll
            for (int j = 0; j < 4; ++j)
                s += __expf(acc[mi][ni][j] + ur[mi][j]);
        s += __shfl_xor(s, 16);
        s += __shfl_xor(s, 32);
        if (l < 16)
            atomicAdd(&colsum[(size_t)n * LLEN + colBase + wc*64 + ni*16 + l], s);
    }

    if (rowBase == colBase && (wc >> 1) == wr) {
        #pragma unroll
        for (int mi = 0; mi < 8; ++mi)
            #pragma unroll
            for (int ni = 0; ni < 4; ++ni)
                #pragma unroll
                for (int j = 0; j < 4; ++j) {
                    const int rr = wr*128 + mi*16 + (l >> 4)*4 + j;
                    const int cc = wc*64 + ni*16 + lr;
                    if (rr == cc)
                        diagv[(size_t)n * LLEN + rowBase + rr] = acc[mi][ni][j];
                }
    }
}

// ---- X f32 -> fp8 ----
__global__ __launch_bounds__(256) void cast_f32_fp8(
    const float* __restrict__ in, unsigned char* __restrict__ outp, int n8)
{
    int i = blockIdx.x * 256 + threadIdx.x;
    if (i >= n8) return;
    const float4* p = reinterpret_cast<const float4*>(in) + (size_t)i * 2;
    float4 a = p[0], b = p[1];
    float f[8] = {a.x,a.y,a.z,a.w,b.x,b.y,b.z,b.w};
    uchar8 o8;
    #pragma unroll
    for (int j = 0; j < 8; ++j) o8[j] = f2fp8(f[j]);
    *(reinterpret_cast<uchar8*>(outp) + i) = o8;
}

// ---- bf16 -> fp8 (WqkT -> Wqk8T) ----
__global__ __launch_bounds__(256) void cast_bf16_fp8(
    const unsigned short* __restrict__ in, unsigned char* __restrict__ outp, int n8)
{
    int i = blockIdx.x * 256 + threadIdx.x;
    if (i >= n8) return;
    short8 v = *(reinterpret_cast<const short8*>(in) + i);
    uchar8 o8;
    #pragma unroll
    for (int j = 0; j < 8; ++j) o8[j] = f2fp8(bf2f((unsigned short)v[j]));
    *(reinterpret_cast<uchar8*>(outp) + i) = o8;
}

// ---- fp32 -> bf16 ----
__global__ __launch_bounds__(256) void cast_f32_bf16(
    const float* __restrict__ in, unsigned short* __restrict__ outp, int n8)
{
    int i = blockIdx.x * 256 + threadIdx.x;
    if (i >= n8) return;
    const float4* p = reinterpret_cast<const float4*>(in) + (size_t)i * 2;
    float4 a = p[0], b = p[1];
    short8 o;
    o[0] = (short)f2bf(a.x); o[1] = (short)f2bf(a.y);
    o[2] = (short)f2bf(a.z); o[3] = (short)f2bf(a.w);
    o[4] = (short)f2bf(b.x); o[5] = (short)f2bf(b.y);
    o[6] = (short)f2bf(b.z); o[7] = (short)f2bf(b.w);
    *(reinterpret_cast<short8*>(outp) + i) = o;
}

// ---- W (K x N fp32) -> bf16 N x K ----
__global__ __launch_bounds__(256) void transpose_cast_bf16(
    const float* __restrict__ W, unsigned short* __restrict__ Wt)
{
    __shared__ float tile[32][33];
    const int tx = threadIdx.x & 31, ty = threadIdx.x >> 5;
    const int c0 = blockIdx.x * 32, r0 = blockIdx.y * 32;
    #pragma unroll
    for (int r = 0; r < 4; ++r)
        tile[ty + r*8][tx] = W[(size_t)(r0 + ty + r*8) * HDIM + c0 + tx];
    __syncthreads();
    #pragma unroll
    for (int r = 0; r < 4; ++r)
        Wt[(size_t)(c0 + ty + r*8) * HDIM + r0 + tx] = f2bf(tile[tx][ty + r*8]);
}

// ---- W (K x N fp32) -> fp8 N x K, value scaled by `scale` ----
__global__ __launch_bounds__(256) void transpose_cast_fp8(
    const float* __restrict__ W, unsigned char* __restrict__ Wt, float scale)
{
    __shared__ float tile[32][33];
    const int tx = threadIdx.x & 31, ty = threadIdx.x >> 5;
    const int c0 = blockIdx.x * 32, r0 = blockIdx.y * 32;
    #pragma unroll
    for (int r = 0; r < 4; ++r)
        tile[ty + r*8][tx] = W[(size_t)(r0 + ty + r*8) * HDIM + c0 + tx];
    __syncthreads();
    #pragma unroll
    for (int r = 0; r < 4; ++r)
        Wt[(size_t)(c0 + ty + r*8) * HDIM + r0 + tx] = f2fp8(tile[tx][ty + r*8] * scale);
}

// ---- p[i] = Wq[i,:] . bk ----
__global__ __launch_bounds__(256) void pvec_kernel(
    const float* __restrict__ Wq, const float* __restrict__ bk,
    float* __restrict__ p)
{
    const int row = blockIdx.x * 4 + (threadIdx.x >> 6);
    const int l = threadIdx.x & 63;
    float s = 0.f;
    #pragma unroll
    for (int c = 0; c < HDIM; c += 64)
        s += Wq[(size_t)row * HDIM + c + l] * bk[c + l];
    #pragma unroll
    for (int off = 32; off > 0; off >>= 1) s += __shfl_down(s, off);
    if (l == 0) p[row] = s;
}

// ---- u[a] = sc2 * X[a,:] . p  (reads X fp32) ----
__global__ __launch_bounds__(256) void uvec_kernel(
    const float* __restrict__ X, const float* __restrict__ p,
    float* __restrict__ u, float sc2)
{
    const int row = blockIdx.x * 4 + (threadIdx.x >> 6);
    const int l = threadIdx.x & 63;
    float s = 0.f;
    #pragma unroll
    for (int c = 0; c < HDIM; c += 64)
        s += X[(size_t)row * HDIM + c + l] * p[c + l];
    #pragma unroll
    for (int off = 32; off > 0; off >>= 1) s += __shfl_down(s, off);
    if (l == 0) u[row] = s * sc2;
}

// ---- h1 = bf16( LN(diag*V8 + X) * g1 + b1 ), diag = exp(S_ll+u_l)/colsum ----
__global__ __launch_bounds__(256) void ln1_kernel(
    const unsigned char* __restrict__ V8, const float* __restrict__ X,
    const float* __restrict__ colsum, const float* __restrict__ diagval,
    const float* __restrict__ uvec,
    const float* __restrict__ g1, const float* __restrict__ b1,
    unsigned short* __restrict__ h1)
{
    const int row = blockIdx.x;
    const size_t base = (size_t)row * HDIM;
    const float dv = __expf(diagval[row] + uvec[row]) / colsum[row];
    const int h0 = threadIdx.x * 4;

    unsigned vv = *reinterpret_cast<const unsigned*>(&V8[base + h0]);
    float4 xx = *reinterpret_cast<const float4*>(&X[base + h0]);
    float y[4];
    y[0] = dv * fp8d((unsigned char)(vv      )) + xx.x;
    y[1] = dv * fp8d((unsigned char)(vv >>  8)) + xx.y;
    y[2] = dv * fp8d((unsigned char)(vv >> 16)) + xx.z;
    y[3] = dv * fp8d((unsigned char)(vv >> 24)) + xx.w;

    float s = y[0]+y[1]+y[2]+y[3];
    float s2 = y[0]*y[0]+y[1]*y[1]+y[2]*y[2]+y[3]*y[3];
    #pragma unroll
    for (int off = 32; off > 0; off >>= 1) {
        s  += __shfl_down(s,  off);
        s2 += __shfl_down(s2, off);
    }
    __shared__ float ws1[4], ws2[4];
    const int wid = threadIdx.x >> 6;
    if ((threadIdx.x & 63) == 0) { ws1[wid] = s; ws2[wid] = s2; }
    __syncthreads();
    const float S  = ws1[0]+ws1[1]+ws1[2]+ws1[3];
    const float S2 = ws2[0]+ws2[1]+ws2[2]+ws2[3];
    const float m   = S  * (1.0f / HDIM);
    const float var = S2 * (1.0f / HDIM) - m*m;
    const float inv = rsqrtf(var + LNEPS);

    float4 gg = *reinterpret_cast<const float4*>(&g1[h0]);
    float4 bb = *reinterpret_cast<const float4*>(&b1[h0]);
    ushort4v o;
    o[0] = f2bf((y[0]-m)*inv*gg.x + bb.x);
    o[1] = f2bf((y[1]-m)*inv*gg.y + bb.y);
    o[2] = f2bf((y[2]-m)*inv*gg.z + bb.z);
    o[3] = f2bf((y[3]-m)*inv*gg.w + bb.w);
    *reinterpret_cast<ushort4v*>(&h1[base + h0]) = o;
}

// ---- out = fp32( LN(G + h1) * g2 + b2 ) ----
__global__ __launch_bounds__(256) void ln2_kernel(
    const unsigned short* __restrict__ Gb, const unsigned short* __restrict__ h1b,
    const float* __restrict__ g2, const float* __restrict__ b2,
    float* __restrict__ out)
{
    const int row = blockIdx.x;
    const size_t base = (size_t)row * HDIM;
    const int h0 = threadIdx.x * 4;

    ushort4v gv = *reinterpret_cast<const ushort4v*>(&Gb[base + h0]);
    ushort4v hv = *reinterpret_cast<const ushort4v*>(&h1b[base + h0]);
    float y[4];
    y[0] = bf2f(gv[0]) + bf2f(hv[0]); y[1] = bf2f(gv[1]) + bf2f(hv[1]);
    y[2] = bf2f(gv[2]) + bf2f(hv[2]); y[3] = bf2f(gv[3]) + bf2f(hv[3]);

    float s = y[0]+y[1]+y[2]+y[3];
    float s2 = y[0]*y[0]+y[1]*y[1]+y[2]*y[2]+y[3]*y[3];
    #pragma unroll
    for (int off = 32; off > 0; off >>= 1) {
        s  += __shfl_down(s,  off);
        s2 += __shfl_down(s2, off);
    }
    __shared__ float ws1[4], ws2[4];
    const int wid = threadIdx.x >> 6;
    if ((threadIdx.x & 63) == 0) { ws1[wid] = s; ws2[wid] = s2; }
    __syncthreads();
    const float S  = ws1[0]+ws1[1]+ws1[2]+ws1[3];
    const float S2 = ws2[0]+ws2[1]+ws2[2]+ws2[3];
    const float m   = S  * (1.0f / HDIM);
    const float var = S2 * (1.0f / HDIM) - m*m;
    const float inv = rsqrtf(var + LNEPS);

    float4 gg = *reinterpret_cast<const float4*>(&g2[h0]);
    float4 bb = *reinterpret_cast<const float4*>(&b2[h0]);
    float4 o;
    o.x = (y[0]-m)*inv*gg.x + bb.x;
    o.y = (y[1]-m)*inv*gg.y + bb.y;
    o.z = (y[2]-m)*inv*gg.z + bb.z;
    o.w = (y[3]-m)*inv*gg.w + bb.w;
    *reinterpret_cast<float4*>(&out[base + h0]) = o;
}

extern "C" void kernel_launch(void* const* d_in, const int* in_sizes, int n_in,
                              void* d_out, int out_size, void* d_ws, size_t ws_size,
                              hipStream_t stream) {
    (void)in_sizes; (void)n_in; (void)out_size; (void)ws_size;
    const float* X  = (const float*)d_in[0];
    const float* Wq = (const float*)d_in[1];
    const float* bq = (const float*)d_in[2];   (void)bq; // cancels in diag/colsum ratio
    const float* Wk = (const float*)d_in[3];
    const float* bk = (const float*)d_in[4];
    const float* Wv = (const float*)d_in[5];
    const float* bv = (const float*)d_in[6];
    const float* Wf = (const float*)d_in[7];
    const float* bf = (const float*)d_in[8];
    const float* g1 = (const float*)d_in[9];
    const float* b1 = (const float*)d_in[10];
    const float* g2 = (const float*)d_in[11];
    const float* b2 = (const float*)d_in[12];
    float* out = (float*)d_out;

    const size_t MATE = (size_t)NB * LLEN * HDIM;   // 16,777,216 elements
    const size_t WE   = (size_t)HDIM * HDIM;

    // d_out (64 MiB) staging: three fp8 activations, all dead before ln2 writes out.
    unsigned char* Xb8 = (unsigned char*)d_out;     // 16 MiB
    unsigned char* Xq8 = Xb8 + MATE;                // 16 MiB
    unsigned char* V8  = Xq8 + MATE;                // 16 MiB

    unsigned short* h1b   = (unsigned short*)d_ws;  // 32 MiB
    unsigned short* Gb    = h1b + MATE;             // 32 MiB
    unsigned short* WqkT  = Gb + MATE;              // 2 MiB (bf16 intermediate)
    unsigned short* Wqb   = WqkT + WE;              // 2 MiB
    unsigned short* Wkb   = Wqb + WE;               // 2 MiB
    unsigned short* WfT   = Wkb + WE;               // 2 MiB
    unsigned char*  Wqk8T = (unsigned char*)(WfT + WE);  // 1 MiB; [Wqk8T|Wv8T] contiguous
    unsigned char*  Wv8T  = Wqk8T + WE;                  // 1 MiB
    float* colsum = (float*)(Wv8T + WE);            // 64 KiB
    float* diagv  = colsum + (size_t)NB * LLEN;     // 64 KiB
    float* pv     = diagv + (size_t)NB * LLEN;      // 4 KiB
    float* uv     = pv + HDIM;                      // 64 KiB
    float* zvec   = uv + (size_t)NB * LLEN;         // 4 KiB

    const int M = NB * LLEN;            // 16384
    const float sc2 = 1.0f / 1024.0f;   // (1/sqrt(H))^2

    hipMemsetAsync(colsum, 0, (size_t)NB * LLEN * sizeof(float), stream);
    hipMemsetAsync(zvec, 0, HDIM * sizeof(float), stream);

    cast_f32_fp8<<<(int)(MATE/8) / 256, 256, 0, stream>>>(X, Xb8, (int)(MATE/8));
    cast_f32_bf16<<<(int)(WE/8) / 256, 256, 0, stream>>>(Wq, Wqb, (int)(WE/8));
    cast_f32_bf16<<<(int)(WE/8) / 256, 256, 0, stream>>>(Wk, Wkb, (int)(WE/8));

    {
        dim3 tgrid(HDIM / 32, HDIM / 32);
        transpose_cast_bf16<<<tgrid, 256, 0, stream>>>(Wf, WfT);
        transpose_cast_fp8<<<tgrid, 256, 0, stream>>>(Wv, Wv8T, 16.0f);  // x2^4
    }

    // WqkT[h,i] = (sc2*2^16) * Wk[h,:].Wq[i,:]  (bf16, values ~0.8) -> fp8
    gemm_proj<<<16, NTHR, 0, stream>>>(Wkb, Wqb, zvec, zvec, zvec,
                                       WqkT, WqkT, WqkT, 64.0f, 64.0f, 64.0f, 4);
    cast_bf16_fp8<<<(int)(WE/8) / 256, 256, 0, stream>>>(WqkT, Wqk8T, (int)(WE/8));

    // u'[a] = sc2 * X[a,:].(Wq @ bk)
    pvec_kernel<<<HDIM / 4, 256, 0, stream>>>(Wq, bk, pv);
    uvec_kernel<<<M / 4, 256, 0, stream>>>(X, pv, uv, sc2);

    // fused fp8 proj: [Xq8 | V8] = Xb8 @ [Wqk8T | Wv8T]^T
    // mat0: scale 1.0*2^-16 (Wqk stored x2^16), epilogue x1024 -> Xq8 (qk undoes 2^-10)
    // mat1: scale 1.0*2^-4  (Wv  stored x2^4),  epilogue +bv    -> V8
    {
        const int gx = 2 * HDIM / BN;       // 8
        const int nwg = gx * (M / BM);      // 512
        gemm_proj_fp8<<<nwg, NTHR, 0, stream>>>(Xb8, Wqk8T, zvec, bv,
                                                Xq8, V8, 1024.0f, 1.0f,
                                                0x6F6F6F6Fu /*2^-16*/,
                                                0x7B7B7B7Bu /*2^-4*/, gx);
    }

    dim3 qgrid(LLEN / BN, LLEN / BM, NB);   // (8, 8, 8)
    qk_colsum_diag_fp8<<<qgrid, NTHR, 0, stream>>>(Xq8, Xb8, uv, colsum, diagv);

    ln1_kernel<<<M, 256, 0, stream>>>(V8, X, colsum, diagv, uv, g1, b1, h1b);

    // FF GEMM (bf16; accuracy matters at full scale through LN2)
    {
        const int gx = HDIM / BN;           // 4
        const int nwg = gx * (M / BM);      // 256
        gemm_proj<<<nwg, NTHR, 0, stream>>>(h1b, WfT, bf, bf, bf,
                                            Gb, Gb, Gb, 1.0f, 1.0f, 1.0f, gx);
    }

    ln2_kernel<<<M, 256, 0, stream>>>(Gb, h1b, g2, b2, out);
}

// Round 10
// 294.660 us; speedup vs baseline: 2.9239x; 2.9239x over previous
//
#include <hip/hip_runtime.h>
#include <math.h>

#define NB   8
#define LLEN 2048
#define HDIM 1024
#define LNEPS 1e-5f

#define BM 256
#define BN 256
#define BK 64
#define NT_K (HDIM / BK)    // 16 bf16 K-tiles
#define NT_K8 (HDIM / 128)  // 8 fp8 K-tiles
#define NTHR 512
#define SLOT (BM * BK)      // 32 KiB per bf16 operand slot
#define SLOT8 32768         // 32 KiB per fp8 operand slot (256 rows x 128 B)

typedef __attribute__((ext_vector_type(8))) short short8;
typedef __attribute__((ext_vector_type(4))) unsigned short ushort4v;
typedef __attribute__((ext_vector_type(4))) float f32x4;
typedef __attribute__((ext_vector_type(4))) int int4v;
typedef __attribute__((ext_vector_type(8))) int int8v;
typedef __attribute__((ext_vector_type(8))) unsigned char uchar8;

typedef __attribute__((address_space(3))) void lds_void;
typedef const __attribute__((address_space(1))) void glob_void;

__device__ __forceinline__ unsigned short f2bf(float f) {
    union { float f; unsigned u; } v; v.f = f;
    unsigned r = v.u + 0x7FFFu + ((v.u >> 16) & 1u);
    return (unsigned short)(r >> 16);
}
__device__ __forceinline__ float bf2f(unsigned short h) {
    union { unsigned u; float f; } v; v.u = ((unsigned)h) << 16;
    return v.f;
}

// OCP e4m3fn encode, RNE (HW-verified numerically in round 8).
__device__ __forceinline__ unsigned char f2fp8(float x) {
    union { float f; unsigned u; } v; v.f = x;
    unsigned s = (v.u >> 24) & 0x80u;
    float a = fabsf(x);
    if (!(a < 448.f)) return (unsigned char)(s | 0x7E);
    int e = (int)((v.u >> 23) & 0xFF) - 127;
    if (e < -6) e = -6;
    float q = rintf(ldexpf(a, 3 - e));
    if (q >= 16.f) { q *= 0.5f; e += 1; }
    int qi = (int)q;
    unsigned byte = (qi < 8) ? (unsigned)qi
                             : (((unsigned)(e + 7) << 3) | (unsigned)(qi - 8));
    return (unsigned char)(s | byte);
}

__device__ __forceinline__ void wg_barrier() {
    asm volatile("" ::: "memory");
    __builtin_amdgcn_s_barrier();
    asm volatile("" ::: "memory");
}

// ---------------- bf16 pipeline (round-7, proven) ----------------
__device__ __forceinline__ void stage_tile(
    const unsigned short* __restrict__ src, int R0, int kcol0,
    unsigned short* ldsDst, int w, int lane)
{
    const int rsub = lane >> 3;
    const int csw  = 8 * ((lane & 7) ^ rsub);
    #pragma unroll
    for (int s = 0; s < 4; ++s) {
        const int r = (s*8 + w)*8 + rsub;
        const unsigned short* g = src + (size_t)(R0 + r) * HDIM + kcol0 + csw;
        __builtin_amdgcn_global_load_lds(
            (glob_void*)g, (lds_void*)(ldsDst + (s*8 + w)*512), 16, 0, 0);
    }
}

__device__ __forceinline__ void run_pipeline(
    const unsigned short* __restrict__ srcA,
    const unsigned short* __restrict__ srcB,
    int rowBase, int colBase,
    unsigned short* lds, f32x4 (&acc)[8][4])
{
    const int t = threadIdx.x, w = t >> 6, l = t & 63;
    const int wr = w >> 2, wc = w & 3;
    const int lr = l & 15;
    const int sw = (l & 7) << 4;
    const int aRB = (wr*128 + lr) * 128;
    const int bRB = (wc*64  + lr) * 128;
    const int c0 = ((l >> 4) * 16) ^ sw;
    const int c1 = (64 + ((l >> 4) * 16)) ^ sw;

    unsigned short* sA[2] = { lds,            lds + 2*SLOT };
    unsigned short* sB[2] = { lds + SLOT,     lds + 3*SLOT };

    stage_tile(srcA, rowBase, 0,  sA[0], w, l);
    stage_tile(srcB, colBase, 0,  sB[0], w, l);
    stage_tile(srcA, rowBase, BK, sA[1], w, l);
    stage_tile(srcB, colBase, BK, sB[1], w, l);
    asm volatile("s_waitcnt vmcnt(8)" ::: "memory");
    wg_barrier();

    for (int kt = 0; kt < NT_K; ++kt) {
        const char* bufA = (const char*)sA[kt & 1];
        const char* bufB = (const char*)sB[kt & 1];
        #pragma unroll
        for (int kk = 0; kk < 2; ++kk) {
            const int cc = kk ? c1 : c0;
            short8 af[8], bfr[4];
            #pragma unroll
            for (int mi = 0; mi < 8; ++mi)
                af[mi] = *(const short8*)(bufA + aRB + mi*2048 + cc);
            #pragma unroll
            for (int ni = 0; ni < 4; ++ni)
                bfr[ni] = *(const short8*)(bufB + bRB + ni*2048 + cc);
            #pragma unroll
            for (int mi = 0; mi < 8; ++mi)
                #pragma unroll
                for (int ni = 0; ni < 4; ++ni)
                    acc[mi][ni] = __builtin_amdgcn_mfma_f32_16x16x32_bf16(
                        af[mi], bfr[ni], acc[mi][ni], 0, 0, 0);
        }
        if (kt == NT_K - 1) break;
        wg_barrier();
        if (kt + 2 < NT_K) {
            stage_tile(srcA, rowBase, (kt+2)*BK, sA[kt&1], w, l);
            stage_tile(srcB, colBase, (kt+2)*BK, sB[kt&1], w, l);
            asm volatile("s_waitcnt vmcnt(8)" ::: "memory");
        } else {
            asm volatile("s_waitcnt vmcnt(0)" ::: "memory");
        }
        wg_barrier();
    }
}

// ---------------- fp8 pipeline (qk only; shufflevector operand concat) ----------------
__device__ __forceinline__ void stage_tile8(
    const unsigned char* __restrict__ src, int R0, int kcol0,
    unsigned char* ldsDst, int w, int lane)
{
    const int rsub = lane >> 3;
    const int csw  = ((lane & 7) ^ rsub) << 4;
    #pragma unroll
    for (int s = 0; s < 4; ++s) {
        const int r = (s*8 + w)*8 + rsub;
        __builtin_amdgcn_global_load_lds(
            (glob_void*)(src + (size_t)(R0 + r) * HDIM + kcol0 + csw),
            (lds_void*)(ldsDst + (s*8 + w)*1024), 16, 0, 0);
    }
}

// A-scale 2^-10 (Xq stored x1024; e8m0 byte 0x75), B-scale 1.0 (0x7F).
// Operand concat via __builtin_shufflevector: single IR concat node so the
// two ds_read_b128 land directly in the 8-VGPR MFMA tuple (no v_mov chain —
// the round-8/9 element-wise inserts cost ~96 movs/K-tile and spilled).
__device__ __forceinline__ void run_pipeline_fp8(
    const unsigned char* __restrict__ srcA,
    const unsigned char* __restrict__ srcB,
    int rowBase, int colBase,
    unsigned char* lds, f32x4 (&acc)[8][4])
{
    const int t = threadIdx.x, w = t >> 6, l = t & 63;
    const int wr = w >> 2, wc = w & 3;
    const int lr = l & 15;
    const int sw = (l & 7) << 4;
    const int aRB = (wr*128 + lr) * 128;
    const int bRB = (wc*64  + lr) * 128;
    const int g0 = (l >> 4) * 32;
    const int cc0 = g0 ^ sw;
    const int cc1 = (g0 + 16) ^ sw;

    unsigned char* sA[2] = { lds,             lds + 2*SLOT8 };
    unsigned char* sB[2] = { lds + SLOT8,     lds + 3*SLOT8 };

    stage_tile8(srcA, rowBase, 0,   sA[0], w, l);
    stage_tile8(srcB, colBase, 0,   sB[0], w, l);
    stage_tile8(srcA, rowBase, 128, sA[1], w, l);
    stage_tile8(srcB, colBase, 128, sB[1], w, l);
    asm volatile("s_waitcnt vmcnt(8)" ::: "memory");
    wg_barrier();

    for (int kt = 0; kt < NT_K8; ++kt) {
        const char* bufA = (const char*)sA[kt & 1];
        const char* bufB = (const char*)sB[kt & 1];
        int8v b8[4];
        #pragma unroll
        for (int ni = 0; ni < 4; ++ni)
            b8[ni] = __builtin_shufflevector(
                *(const int4v*)(bufB + bRB + ni*2048 + cc0),
                *(const int4v*)(bufB + bRB + ni*2048 + cc1),
                0, 1, 2, 3, 4, 5, 6, 7);
        #pragma unroll
        for (int mi = 0; mi < 8; ++mi) {
            int8v a8 = __builtin_shufflevector(
                *(const int4v*)(bufA + aRB + mi*2048 + cc0),
                *(const int4v*)(bufA + aRB + mi*2048 + cc1),
                0, 1, 2, 3, 4, 5, 6, 7);
            #pragma unroll
            for (int ni = 0; ni < 4; ++ni)
                acc[mi][ni] = __builtin_amdgcn_mfma_scale_f32_16x16x128_f8f6f4(
                    a8, b8[ni], acc[mi][ni], 0, 0,
                    0, 0x75757575u, 0, 0x7F7F7F7Fu);
        }
        if (kt == NT_K8 - 1) break;
        wg_barrier();
        if (kt + 2 < NT_K8) {
            stage_tile8(srcA, rowBase, (kt+2)*128, sA[kt&1], w, l);
            stage_tile8(srcB, colBase, (kt+2)*128, sB[kt&1], w, l);
            asm volatile("s_waitcnt vmcnt(8)" ::: "memory");
        } else {
            asm volatile("s_waitcnt vmcnt(0)" ::: "memory");
        }
        wg_barrier();
    }
}

// ---- bf16 multi-output GEMM: C_mat = bf16(alpha_mat * (A @ Bt^T + bias_mat)) ----
__global__ __launch_bounds__(NTHR, 2) void gemm_proj(
    const unsigned short* __restrict__ A,
    const unsigned short* __restrict__ Bt,
    const float* __restrict__ bias0, const float* __restrict__ bias1,
    const float* __restrict__ bias2,
    unsigned short* __restrict__ C0, unsigned short* __restrict__ C1,
    unsigned short* __restrict__ C2,
    float al0, float al1, float al2, int gx)
{
    __shared__ __align__(16) unsigned short lds[4 * SLOT];
    const int nwg = gridDim.x, bid = blockIdx.x;
    const int swz = (bid & 7) * (nwg >> 3) + (bid >> 3);
    const int bx = swz % gx, by = swz / gx;
    const int rowBase = by * BM, colBase = bx * BN;

    f32x4 acc[8][4] = {};
    run_pipeline(A, Bt, rowBase, colBase, lds, acc);

    const int t = threadIdx.x, w = t >> 6, l = t & 63;
    const int wr = w >> 2, wc = w & 3;
    const int lr = l & 15;

    const int mat = colBase >> 10;
    unsigned short* Cm = (mat == 0) ? C0 : (mat == 1 ? C1 : C2);
    const float* bm    = (mat == 0) ? bias0 : (mat == 1 ? bias1 : bias2);
    const float am     = (mat == 0) ? al0 : (mat == 1 ? al1 : al2);
    const int lcb = colBase & (HDIM - 1);

    #pragma unroll
    for (int ni = 0; ni < 4; ++ni) {
        const int col = lcb + wc*64 + ni*16 + lr;
        const float bv = bm[col];
        #pragma unroll
        for (int mi = 0; mi < 8; ++mi) {
            const int row0 = rowBase + wr*128 + mi*16 + (l >> 4) * 4;
            #pragma unroll
            for (int j = 0; j < 4; ++j)
                Cm[(size_t)(row0 + j) * HDIM + col] = f2bf(am * (acc[mi][ni][j] + bv));
        }
    }
}

// ---- fp8 qk: S[a,b]=Xq8[a,:]·Xb8[b,:]*2^-10; colsum[b]+=sum_a exp(S+u[a]); diag=S ----
__global__ __launch_bounds__(NTHR, 2) void qk_colsum_diag_fp8(
    const unsigned char* __restrict__ Xq8,
    const unsigned char* __restrict__ Xb8,
    const float* __restrict__ uvec,
    float* __restrict__ colsum, float* __restrict__ diagv)
{
    __shared__ __align__(16) unsigned char lds8[4 * SLOT8];
    const int n = blockIdx.z;
    const unsigned char* An = Xq8 + (size_t)n * LLEN * HDIM;
    const unsigned char* Bn = Xb8 + (size_t)n * LLEN * HDIM;
    const int rowBase = blockIdx.y * BM;
    const int colBase = blockIdx.x * BN;

    f32x4 acc[8][4] = {};
    run_pipeline_fp8(An, Bn, rowBase, colBase, lds8, acc);

    const int t = threadIdx.x, w = t >> 6, l = t & 63;
    const int wr = w >> 2, wc = w & 3;
    const int lr = l & 15;

    float ur[8][4];
    #pragma unroll
    for (int mi = 0; mi < 8; ++mi)
        #pragma unroll
        for (int j = 0; j < 4; ++j)
            ur[mi][j] = uvec[(size_t)n * LLEN + rowBase + wr*128 + mi*16 + (l>>4)*4 + j];

    #pragma unroll
    for (int ni = 0; ni < 4; ++ni) {
        float s = 0.f;
        #pragma unroll
        for (int mi = 0; mi < 8; ++mi)
            #pragma unroll
            for (int j = 0; j < 4; ++j)
                s += __expf(acc[mi][ni][j] + ur[mi][j]);
        s += __shfl_xor(s, 16);
        s += __shfl_xor(s, 32);
        if (l < 16)
            atomicAdd(&colsum[(size_t)n * LLEN + colBase + wc*64 + ni*16 + l], s);
    }

    if (rowBase == colBase && (wc >> 1) == wr) {
        #pragma unroll
        for (int mi = 0; mi < 8; ++mi)
            #pragma unroll
            for (int ni = 0; ni < 4; ++ni)
                #pragma unroll
                for (int j = 0; j < 4; ++j) {
                    const int rr = wr*128 + mi*16 + (l >> 4)*4 + j;
                    const int cc = wc*64 + ni*16 + lr;
                    if (rr == cc)
                        diagv[(size_t)n * LLEN + rowBase + rr] = acc[mi][ni][j];
                }
    }
}

// ---- X f32 -> Xb bf16 + Xb8 fp8, single pass ----
__global__ __launch_bounds__(256) void cast_x_dual(
    const float* __restrict__ in, unsigned short* __restrict__ outb,
    unsigned char* __restrict__ out8, int n8)
{
    int i = blockIdx.x * 256 + threadIdx.x;
    if (i >= n8) return;
    const float4* p = reinterpret_cast<const float4*>(in) + (size_t)i * 2;
    float4 a = p[0], b = p[1];
    float f[8] = {a.x,a.y,a.z,a.w,b.x,b.y,b.z,b.w};
    short8 o; uchar8 o8;
    #pragma unroll
    for (int j = 0; j < 8; ++j) { o[j] = (short)f2bf(f[j]); o8[j] = f2fp8(f[j]); }
    *(reinterpret_cast<short8*>(outb) + i) = o;
    *(reinterpret_cast<uchar8*>(out8) + i) = o8;
}

// ---- bf16 -> fp8 (Xq0 -> Xq8) ----
__global__ __launch_bounds__(256) void cast_bf16_fp8(
    const unsigned short* __restrict__ in, unsigned char* __restrict__ outp, int n8)
{
    int i = blockIdx.x * 256 + threadIdx.x;
    if (i >= n8) return;
    short8 v = *(reinterpret_cast<const short8*>(in) + i);
    uchar8 o8;
    #pragma unroll
    for (int j = 0; j < 8; ++j) o8[j] = f2fp8(bf2f((unsigned short)v[j]));
    *(reinterpret_cast<uchar8*>(outp) + i) = o8;
}

// ---- fp32 -> bf16 ----
__global__ __launch_bounds__(256) void cast_f32_bf16(
    const float* __restrict__ in, unsigned short* __restrict__ outp, int n8)
{
    int i = blockIdx.x * 256 + threadIdx.x;
    if (i >= n8) return;
    const float4* p = reinterpret_cast<const float4*>(in) + (size_t)i * 2;
    float4 a = p[0], b = p[1];
    short8 o;
    o[0] = (short)f2bf(a.x); o[1] = (short)f2bf(a.y);
    o[2] = (short)f2bf(a.z); o[3] = (short)f2bf(a.w);
    o[4] = (short)f2bf(b.x); o[5] = (short)f2bf(b.y);
    o[6] = (short)f2bf(b.z); o[7] = (short)f2bf(b.w);
    *(reinterpret_cast<short8*>(outp) + i) = o;
}

// ---- Wv, Wf (K x N fp32) -> Wt (N x K bf16), z selects ----
__global__ __launch_bounds__(256) void transpose_cast2(
    const float* __restrict__ W0, const float* __restrict__ W1,
    unsigned short* __restrict__ Wt)
{
    const int z = blockIdx.z;
    const float* W = (z == 0) ? W0 : W1;
    unsigned short* dst = Wt + (size_t)z * HDIM * HDIM;
    __shared__ float tile[32][33];
    const int tx = threadIdx.x & 31, ty = threadIdx.x >> 5;
    const int c0 = blockIdx.x * 32, r0 = blockIdx.y * 32;
    #pragma unroll
    for (int r = 0; r < 4; ++r)
        tile[ty + r*8][tx] = W[(size_t)(r0 + ty + r*8) * HDIM + c0 + tx];
    __syncthreads();
    #pragma unroll
    for (int r = 0; r < 4; ++r)
        dst[(size_t)(c0 + ty + r*8) * HDIM + r0 + tx] = f2bf(tile[tx][ty + r*8]);
}

// ---- p[i] = Wq[i,:] . bk ----
__global__ __launch_bounds__(256) void pvec_kernel(
    const float* __restrict__ Wq, const float* __restrict__ bk,
    float* __restrict__ p)
{
    const int row = blockIdx.x * 4 + (threadIdx.x >> 6);
    const int l = threadIdx.x & 63;
    float s = 0.f;
    #pragma unroll
    for (int c = 0; c < HDIM; c += 64)
        s += Wq[(size_t)row * HDIM + c + l] * bk[c + l];
    #pragma unroll
    for (int off = 32; off > 0; off >>= 1) s += __shfl_down(s, off);
    if (l == 0) p[row] = s;
}

// ---- u[a] = sc2 * Xb[a,:] . p ----
__global__ __launch_bounds__(256) void uvec_kernel(
    const unsigned short* __restrict__ Xb, const float* __restrict__ p,
    float* __restrict__ u, float sc2)
{
    const int row = blockIdx.x * 4 + (threadIdx.x >> 6);
    const int l = threadIdx.x & 63;
    const unsigned short* xr = Xb + (size_t)row * HDIM + l * 16;
    float s = 0.f;
    #pragma unroll
    for (int k = 0; k < 2; ++k) {
        short8 v = *reinterpret_cast<const short8*>(xr + k*8);
        #pragma unroll
        for (int j = 0; j < 8; ++j)
            s += bf2f((unsigned short)v[j]) * p[l*16 + k*8 + j];
    }
    #pragma unroll
    for (int off = 32; off > 0; off >>= 1) s += __shfl_down(s, off);
    if (l == 0) u[row] = s * sc2;
}

// ---- h1 = bf16( LN(diag*V + X) * g1 + b1 ), diag = exp(S_ll+u_l)/colsum ----
__global__ __launch_bounds__(256) void ln1_kernel(
    const unsigned short* __restrict__ Vb, const float* __restrict__ X,
    const float* __restrict__ colsum, const float* __restrict__ diagval,
    const float* __restrict__ uvec,
    const float* __restrict__ g1, const float* __restrict__ b1,
    unsigned short* __restrict__ h1)
{
    const int row = blockIdx.x;
    const size_t base = (size_t)row * HDIM;
    const float dv = __expf(diagval[row] + uvec[row]) / colsum[row];
    const int h0 = threadIdx.x * 4;

    ushort4v vv = *reinterpret_cast<const ushort4v*>(&Vb[base + h0]);
    float4 xx = *reinterpret_cast<const float4*>(&X[base + h0]);
    float y[4];
    y[0] = dv * bf2f(vv[0]) + xx.x; y[1] = dv * bf2f(vv[1]) + xx.y;
    y[2] = dv * bf2f(vv[2]) + xx.z; y[3] = dv * bf2f(vv[3]) + xx.w;

    float s = y[0]+y[1]+y[2]+y[3];
    float s2 = y[0]*y[0]+y[1]*y[1]+y[2]*y[2]+y[3]*y[3];
    #pragma unroll
    for (int off = 32; off > 0; off >>= 1) {
        s  += __shfl_down(s,  off);
        s2 += __shfl_down(s2, off);
    }
    __shared__ float ws1[4], ws2[4];
    const int wid = threadIdx.x >> 6;
    if ((threadIdx.x & 63) == 0) { ws1[wid] = s; ws2[wid] = s2; }
    __syncthreads();
    const float S  = ws1[0]+ws1[1]+ws1[2]+ws1[3];
    const float S2 = ws2[0]+ws2[1]+ws2[2]+ws2[3];
    const float m   = S  * (1.0f / HDIM);
    const float var = S2 * (1.0f / HDIM) - m*m;
    const float inv = rsqrtf(var + LNEPS);

    float4 gg = *reinterpret_cast<const float4*>(&g1[h0]);
    float4 bb = *reinterpret_cast<const float4*>(&b1[h0]);
    ushort4v o;
    o[0] = f2bf((y[0]-m)*inv*gg.x + bb.x);
    o[1] = f2bf((y[1]-m)*inv*gg.y + bb.y);
    o[2] = f2bf((y[2]-m)*inv*gg.z + bb.z);
    o[3] = f2bf((y[3]-m)*inv*gg.w + bb.w);
    *reinterpret_cast<ushort4v*>(&h1[base + h0]) = o;
}

// ---- out = fp32( LN(G + h1) * g2 + b2 ) ----
__global__ __launch_bounds__(256) void ln2_kernel(
    const unsigned short* __restrict__ Gb, const unsigned short* __restrict__ h1b,
    const float* __restrict__ g2, const float* __restrict__ b2,
    float* __restrict__ out)
{
    const int row = blockIdx.x;
    const size_t base = (size_t)row * HDIM;
    const int h0 = threadIdx.x * 4;

    ushort4v gv = *reinterpret_cast<const ushort4v*>(&Gb[base + h0]);
    ushort4v hv = *reinterpret_cast<const ushort4v*>(&h1b[base + h0]);
    float y[4];
    y[0] = bf2f(gv[0]) + bf2f(hv[0]); y[1] = bf2f(gv[1]) + bf2f(hv[1]);
    y[2] = bf2f(gv[2]) + bf2f(hv[2]); y[3] = bf2f(gv[3]) + bf2f(hv[3]);

    float s = y[0]+y[1]+y[2]+y[3];
    float s2 = y[0]*y[0]+y[1]*y[1]+y[2]*y[2]+y[3]*y[3];
    #pragma unroll
    for (int off = 32; off > 0; off >>= 1) {
        s  += __shfl_down(s,  off);
        s2 += __shfl_down(s2, off);
    }
    __shared__ float ws1[4], ws2[4];
    const int wid = threadIdx.x >> 6;
    if ((threadIdx.x & 63) == 0) { ws1[wid] = s; ws2[wid] = s2; }
    __syncthreads();
    const float S  = ws1[0]+ws1[1]+ws1[2]+ws1[3];
    const float S2 = ws2[0]+ws2[1]+ws2[2]+ws2[3];
    const float m   = S  * (1.0f / HDIM);
    const float var = S2 * (1.0f / HDIM) - m*m;
    const float inv = rsqrtf(var + LNEPS);

    float4 gg = *reinterpret_cast<const float4*>(&g2[h0]);
    float4 bb = *reinterpret_cast<const float4*>(&b2[h0]);
    float4 o;
    o.x = (y[0]-m)*inv*gg.x + bb.x;
    o.y = (y[1]-m)*inv*gg.y + bb.y;
    o.z = (y[2]-m)*inv*gg.z + bb.z;
    o.w = (y[3]-m)*inv*gg.w + bb.w;
    *reinterpret_cast<float4*>(&out[base + h0]) = o;
}

extern "C" void kernel_launch(void* const* d_in, const int* in_sizes, int n_in,
                              void* d_out, int out_size, void* d_ws, size_t ws_size,
                              hipStream_t stream) {
    (void)in_sizes; (void)n_in; (void)out_size; (void)ws_size;
    const float* X  = (const float*)d_in[0];
    const float* Wq = (const float*)d_in[1];
    const float* bq = (const float*)d_in[2];   (void)bq; // cancels in diag/colsum ratio
    const float* Wk = (const float*)d_in[3];
    const float* bk = (const float*)d_in[4];
    const float* Wv = (const float*)d_in[5];
    const float* bv = (const float*)d_in[6];
    const float* Wf = (const float*)d_in[7];
    const float* bf = (const float*)d_in[8];
    const float* g1 = (const float*)d_in[9];
    const float* b1 = (const float*)d_in[10];
    const float* g2 = (const float*)d_in[11];
    const float* b2 = (const float*)d_in[12];
    float* out = (float*)d_out;

    const size_t MATE = (size_t)NB * LLEN * HDIM;   // 16,777,216 elements
    const size_t WE   = (size_t)HDIM * HDIM;

    // d_out doubles as staging: Xb bf16 [0,32MiB), Vb bf16 [32,64MiB).
    unsigned short* Xb  = (unsigned short*)d_out;
    unsigned short* Vb  = Xb + MATE;

    unsigned short* Xq0  = (unsigned short*)d_ws;   // 32 MiB (x1024-scaled; reused as h1b)
    unsigned short* Gb   = Xq0 + MATE;              // 32 MiB
    unsigned short* WqkT = Gb + MATE;               // [WqkT|WvT] contiguous
    unsigned short* WvT  = WqkT + WE;
    unsigned short* WfT  = WvT + WE;
    unsigned short* Wqb  = WfT + WE;
    unsigned short* Wkb  = Wqb + WE;
    float* colsum = (float*)(Wkb + WE);             // 64 KiB
    float* diagv  = colsum + (size_t)NB * LLEN;     // 64 KiB
    float* pv     = diagv + (size_t)NB * LLEN;      // 4 KiB
    float* uv     = pv + HDIM;                      // 64 KiB
    float* zvec   = uv + (size_t)NB * LLEN;         // 4 KiB
    unsigned char* Xq8 = (unsigned char*)(zvec + HDIM);  // 16 MiB
    unsigned char* Xb8 = Xq8 + MATE;                     // 16 MiB
    unsigned short* h1b = Xq0;                      // reuse after qk

    const int M = NB * LLEN;            // 16384
    const float sc2 = 1.0f / 1024.0f;   // (1/sqrt(H))^2

    hipMemsetAsync(colsum, 0, (size_t)NB * LLEN * sizeof(float), stream);
    hipMemsetAsync(zvec, 0, HDIM * sizeof(float), stream);

    cast_x_dual<<<(int)(MATE/8) / 256, 256, 0, stream>>>(X, Xb, Xb8, (int)(MATE/8));
    cast_f32_bf16<<<(int)(WE/8) / 256, 256, 0, stream>>>(Wq, Wqb, (int)(WE/8));
    cast_f32_bf16<<<(int)(WE/8) / 256, 256, 0, stream>>>(Wk, Wkb, (int)(WE/8));

    {
        dim3 tgrid(HDIM / 32, HDIM / 32, 2);
        transpose_cast2<<<tgrid, 256, 0, stream>>>(Wv, Wf, WvT);
    }

    // WqkT[j,i] = sc2 * Wk[j,:].Wq[i,:]
    gemm_proj<<<16, NTHR, 0, stream>>>(Wkb, Wqb, zvec, zvec, zvec,
                                       WqkT, WqkT, WqkT, sc2, sc2, sc2, 4);

    // u'[a] = sc2 * X[a,:].(Wq @ bk)
    pvec_kernel<<<HDIM / 4, 256, 0, stream>>>(Wq, bk, pv);
    uvec_kernel<<<M / 4, 256, 0, stream>>>(Xb, pv, uv, sc2);

    // fused [Xq0 | V] = Xb @ [WqkT | WvT]^T ; Xq0 pre-scaled x1024 for fp8 range
    {
        const int gx = 2 * HDIM / BN;       // 8
        const int nwg = gx * (M / BM);      // 512
        gemm_proj<<<nwg, NTHR, 0, stream>>>(Xb, WqkT, zvec, bv, zvec,
                                            Xq0, Vb, Vb, 1024.0f, 1.0f, 1.0f, gx);
    }

    cast_bf16_fp8<<<(int)(MATE/8) / 256, 256, 0, stream>>>(Xq0, Xq8, (int)(MATE/8));

    dim3 qgrid(LLEN / BN, LLEN / BM, NB);   // (8, 8, 8)
    qk_colsum_diag_fp8<<<qgrid, NTHR, 0, stream>>>(Xq8, Xb8, uv, colsum, diagv);

    ln1_kernel<<<M, 256, 0, stream>>>(Vb, X, colsum, diagv, uv, g1, b1, h1b);

    // FF GEMM (bf16)
    {
        const int gx = HDIM / BN;           // 4
        const int nwg = gx * (M / BM);      // 256
        gemm_proj<<<nwg, NTHR, 0, stream>>>(h1b, WfT, bf, bf, bf,
                                            Gb, Gb, Gb, 1.0f, 1.0f, 1.0f, gx);
    }

    ln2_kernel<<<M, 256, 0, stream>>>(Gb, h1b, g2, b2, out);
}

// Round 11
// 281.658 us; speedup vs baseline: 3.0589x; 1.0462x over previous
//
#include <hip/hip_runtime.h>
#include <math.h>

#define NB   8
#define LLEN 2048
#define HDIM 1024
#define LNEPS 1e-5f

#define BM 256
#define BN 256
#define BK 64
#define NT_K (HDIM / BK)    // 16 bf16 K-tiles
#define NT_K8 (HDIM / 128)  // 8 fp8 K-tiles
#define NTHR 512
#define SLOT (BM * BK)      // 32 KiB per bf16 operand slot
#define SLOT8 32768         // 32 KiB per fp8 operand slot (256 rows x 128 B)

typedef __attribute__((ext_vector_type(8))) short short8;
typedef __attribute__((ext_vector_type(4))) unsigned short ushort4v;
typedef __attribute__((ext_vector_type(4))) float f32x4;
typedef __attribute__((ext_vector_type(4))) int int4v;
typedef __attribute__((ext_vector_type(8))) int int8v;
typedef __attribute__((ext_vector_type(8))) unsigned char uchar8;

typedef __attribute__((address_space(3))) void lds_void;
typedef const __attribute__((address_space(1))) void glob_void;

__device__ __forceinline__ unsigned short f2bf(float f) {
    union { float f; unsigned u; } v; v.f = f;
    unsigned r = v.u + 0x7FFFu + ((v.u >> 16) & 1u);
    return (unsigned short)(r >> 16);
}
__device__ __forceinline__ float bf2f(unsigned short h) {
    union { unsigned u; float f; } v; v.u = ((unsigned)h) << 16;
    return v.f;
}

// OCP e4m3fn encode, RNE (HW-verified numerically in rounds 8/10).
__device__ __forceinline__ unsigned char f2fp8(float x) {
    union { float f; unsigned u; } v; v.f = x;
    unsigned s = (v.u >> 24) & 0x80u;
    float a = fabsf(x);
    if (!(a < 448.f)) return (unsigned char)(s | 0x7E);
    int e = (int)((v.u >> 23) & 0xFF) - 127;
    if (e < -6) e = -6;
    float q = rintf(ldexpf(a, 3 - e));
    if (q >= 16.f) { q *= 0.5f; e += 1; }
    int qi = (int)q;
    unsigned byte = (qi < 8) ? (unsigned)qi
                             : (((unsigned)(e + 7) << 3) | (unsigned)(qi - 8));
    return (unsigned char)(s | byte);
}

__device__ __forceinline__ void wg_barrier() {
    asm volatile("" ::: "memory");
    __builtin_amdgcn_s_barrier();
    asm volatile("" ::: "memory");
}

// ---------------- bf16 pipeline (round-7, proven) ----------------
__device__ __forceinline__ void stage_tile(
    const unsigned short* __restrict__ src, int R0, int kcol0,
    unsigned short* ldsDst, int w, int lane)
{
    const int rsub = lane >> 3;
    const int csw  = 8 * ((lane & 7) ^ rsub);
    #pragma unroll
    for (int s = 0; s < 4; ++s) {
        const int r = (s*8 + w)*8 + rsub;
        const unsigned short* g = src + (size_t)(R0 + r) * HDIM + kcol0 + csw;
        __builtin_amdgcn_global_load_lds(
            (glob_void*)g, (lds_void*)(ldsDst + (s*8 + w)*512), 16, 0, 0);
    }
}

__device__ __forceinline__ void run_pipeline(
    const unsigned short* __restrict__ srcA,
    const unsigned short* __restrict__ srcB,
    int rowBase, int colBase,
    unsigned short* lds, f32x4 (&acc)[8][4])
{
    const int t = threadIdx.x, w = t >> 6, l = t & 63;
    const int wr = w >> 2, wc = w & 3;
    const int lr = l & 15;
    const int sw = (l & 7) << 4;
    const int aRB = (wr*128 + lr) * 128;
    const int bRB = (wc*64  + lr) * 128;
    const int c0 = ((l >> 4) * 16) ^ sw;
    const int c1 = (64 + ((l >> 4) * 16)) ^ sw;

    unsigned short* sA[2] = { lds,            lds + 2*SLOT };
    unsigned short* sB[2] = { lds + SLOT,     lds + 3*SLOT };

    stage_tile(srcA, rowBase, 0,  sA[0], w, l);
    stage_tile(srcB, colBase, 0,  sB[0], w, l);
    stage_tile(srcA, rowBase, BK, sA[1], w, l);
    stage_tile(srcB, colBase, BK, sB[1], w, l);
    asm volatile("s_waitcnt vmcnt(8)" ::: "memory");
    wg_barrier();

    for (int kt = 0; kt < NT_K; ++kt) {
        const char* bufA = (const char*)sA[kt & 1];
        const char* bufB = (const char*)sB[kt & 1];
        #pragma unroll
        for (int kk = 0; kk < 2; ++kk) {
            const int cc = kk ? c1 : c0;
            short8 af[8], bfr[4];
            #pragma unroll
            for (int mi = 0; mi < 8; ++mi)
                af[mi] = *(const short8*)(bufA + aRB + mi*2048 + cc);
            #pragma unroll
            for (int ni = 0; ni < 4; ++ni)
                bfr[ni] = *(const short8*)(bufB + bRB + ni*2048 + cc);
            #pragma unroll
            for (int mi = 0; mi < 8; ++mi)
                #pragma unroll
                for (int ni = 0; ni < 4; ++ni)
                    acc[mi][ni] = __builtin_amdgcn_mfma_f32_16x16x32_bf16(
                        af[mi], bfr[ni], acc[mi][ni], 0, 0, 0);
        }
        if (kt == NT_K - 1) break;
        wg_barrier();
        if (kt + 2 < NT_K) {
            stage_tile(srcA, rowBase, (kt+2)*BK, sA[kt&1], w, l);
            stage_tile(srcB, colBase, (kt+2)*BK, sB[kt&1], w, l);
            asm volatile("s_waitcnt vmcnt(8)" ::: "memory");
        } else {
            asm volatile("s_waitcnt vmcnt(0)" ::: "memory");
        }
        wg_barrier();
    }
}

// ---------------- fp8 pipeline (qk only; shufflevector operand concat) ----------------
__device__ __forceinline__ void stage_tile8(
    const unsigned char* __restrict__ src, int R0, int kcol0,
    unsigned char* ldsDst, int w, int lane)
{
    const int rsub = lane >> 3;
    const int csw  = ((lane & 7) ^ rsub) << 4;
    #pragma unroll
    for (int s = 0; s < 4; ++s) {
        const int r = (s*8 + w)*8 + rsub;
        __builtin_amdgcn_global_load_lds(
            (glob_void*)(src + (size_t)(R0 + r) * HDIM + kcol0 + csw),
            (lds_void*)(ldsDst + (s*8 + w)*1024), 16, 0, 0);
    }
}

// A-scale 2^-10 (Xq stored x1024; e8m0 0x75), B-scale 1.0 (0x7F).
__device__ __forceinline__ void run_pipeline_fp8(
    const unsigned char* __restrict__ srcA,
    const unsigned char* __restrict__ srcB,
    int rowBase, int colBase,
    unsigned char* lds, f32x4 (&acc)[8][4])
{
    const int t = threadIdx.x, w = t >> 6, l = t & 63;
    const int wr = w >> 2, wc = w & 3;
    const int lr = l & 15;
    const int sw = (l & 7) << 4;
    const int aRB = (wr*128 + lr) * 128;
    const int bRB = (wc*64  + lr) * 128;
    const int g0 = (l >> 4) * 32;
    const int cc0 = g0 ^ sw;
    const int cc1 = (g0 + 16) ^ sw;

    unsigned char* sA[2] = { lds,             lds + 2*SLOT8 };
    unsigned char* sB[2] = { lds + SLOT8,     lds + 3*SLOT8 };

    stage_tile8(srcA, rowBase, 0,   sA[0], w, l);
    stage_tile8(srcB, colBase, 0,   sB[0], w, l);
    stage_tile8(srcA, rowBase, 128, sA[1], w, l);
    stage_tile8(srcB, colBase, 128, sB[1], w, l);
    asm volatile("s_waitcnt vmcnt(8)" ::: "memory");
    wg_barrier();

    for (int kt = 0; kt < NT_K8; ++kt) {
        const char* bufA = (const char*)sA[kt & 1];
        const char* bufB = (const char*)sB[kt & 1];
        int8v b8[4];
        #pragma unroll
        for (int ni = 0; ni < 4; ++ni)
            b8[ni] = __builtin_shufflevector(
                *(const int4v*)(bufB + bRB + ni*2048 + cc0),
                *(const int4v*)(bufB + bRB + ni*2048 + cc1),
                0, 1, 2, 3, 4, 5, 6, 7);
        #pragma unroll
        for (int mi = 0; mi < 8; ++mi) {
            int8v a8 = __builtin_shufflevector(
                *(const int4v*)(bufA + aRB + mi*2048 + cc0),
                *(const int4v*)(bufA + aRB + mi*2048 + cc1),
                0, 1, 2, 3, 4, 5, 6, 7);
            #pragma unroll
            for (int ni = 0; ni < 4; ++ni)
                acc[mi][ni] = __builtin_amdgcn_mfma_scale_f32_16x16x128_f8f6f4(
                    a8, b8[ni], acc[mi][ni], 0, 0,
                    0, 0x75757575u, 0, 0x7F7F7F7Fu);
        }
        if (kt == NT_K8 - 1) break;
        wg_barrier();
        if (kt + 2 < NT_K8) {
            stage_tile8(srcA, rowBase, (kt+2)*128, sA[kt&1], w, l);
            stage_tile8(srcB, colBase, (kt+2)*128, sB[kt&1], w, l);
            asm volatile("s_waitcnt vmcnt(8)" ::: "memory");
        } else {
            asm volatile("s_waitcnt vmcnt(0)" ::: "memory");
        }
        wg_barrier();
    }
}

// ---- bf16 multi-output GEMM; mat==0 may write fp8 directly (C8 != null) ----
__global__ __launch_bounds__(NTHR, 2) void gemm_proj(
    const unsigned short* __restrict__ A,
    const unsigned short* __restrict__ Bt,
    const float* __restrict__ bias0, const float* __restrict__ bias1,
    const float* __restrict__ bias2,
    unsigned short* __restrict__ C0, unsigned short* __restrict__ C1,
    unsigned short* __restrict__ C2,
    unsigned char* __restrict__ C8,
    float al0, float al1, float al2, int gx)
{
    __shared__ __align__(16) unsigned short lds[4 * SLOT];
    const int nwg = gridDim.x, bid = blockIdx.x;
    const int swz = (bid & 7) * (nwg >> 3) + (bid >> 3);
    const int bx = swz % gx, by = swz / gx;
    const int rowBase = by * BM, colBase = bx * BN;

    f32x4 acc[8][4] = {};
    run_pipeline(A, Bt, rowBase, colBase, lds, acc);

    const int t = threadIdx.x, w = t >> 6, l = t & 63;
    const int wr = w >> 2, wc = w & 3;
    const int lr = l & 15;

    const int mat = colBase >> 10;
    unsigned short* Cm = (mat == 0) ? C0 : (mat == 1 ? C1 : C2);
    const float* bm    = (mat == 0) ? bias0 : (mat == 1 ? bias1 : bias2);
    const float am     = (mat == 0) ? al0 : (mat == 1 ? al1 : al2);
    const int lcb = colBase & (HDIM - 1);

    if (mat == 0 && C8) {
        // fp8 output path (Xq8 direct; kills the separate cast pass)
        #pragma unroll
        for (int ni = 0; ni < 4; ++ni) {
            const int col = lcb + wc*64 + ni*16 + lr;
            const float bv = bm[col];
            #pragma unroll
            for (int mi = 0; mi < 8; ++mi) {
                const int row0 = rowBase + wr*128 + mi*16 + (l >> 4) * 4;
                #pragma unroll
                for (int j = 0; j < 4; ++j)
                    C8[(size_t)(row0 + j) * HDIM + col] = f2fp8(am * (acc[mi][ni][j] + bv));
            }
        }
        return;
    }

    #pragma unroll
    for (int ni = 0; ni < 4; ++ni) {
        const int col = lcb + wc*64 + ni*16 + lr;
        const float bv = bm[col];
        #pragma unroll
        for (int mi = 0; mi < 8; ++mi) {
            const int row0 = rowBase + wr*128 + mi*16 + (l >> 4) * 4;
            #pragma unroll
            for (int j = 0; j < 4; ++j)
                Cm[(size_t)(row0 + j) * HDIM + col] = f2bf(am * (acc[mi][ni][j] + bv));
        }
    }
}

// ---- fp8 qk, batch-per-XCD grid: bid&7 = batch (round-robin XCD heuristic) ----
// Per batch: Q+K panels = 4 MiB fp8 -> fits one XCD's 4 MiB L2.
__global__ __launch_bounds__(NTHR, 2) void qk_colsum_diag_fp8(
    const unsigned char* __restrict__ Xq8,
    const unsigned char* __restrict__ Xb8,
    const float* __restrict__ uvec,
    float* __restrict__ colsum, float* __restrict__ diagv)
{
    __shared__ __align__(16) unsigned char lds8[4 * SLOT8];
    const int bid = blockIdx.x;          // 512
    const int n = bid & 7;
    const int rem = bid >> 3;            // 0..63
    const int rowBase = (rem & 7) * BM;
    const int colBase = (rem >> 3) * BN;
    const unsigned char* An = Xq8 + (size_t)n * LLEN * HDIM;
    const unsigned char* Bn = Xb8 + (size_t)n * LLEN * HDIM;

    f32x4 acc[8][4] = {};
    run_pipeline_fp8(An, Bn, rowBase, colBase, lds8, acc);

    const int t = threadIdx.x, w = t >> 6, l = t & 63;
    const int wr = w >> 2, wc = w & 3;
    const int lr = l & 15;

    float ur[8][4];
    #pragma unroll
    for (int mi = 0; mi < 8; ++mi)
        #pragma unroll
        for (int j = 0; j < 4; ++j)
            ur[mi][j] = uvec[(size_t)n * LLEN + rowBase + wr*128 + mi*16 + (l>>4)*4 + j];

    #pragma unroll
    for (int ni = 0; ni < 4; ++ni) {
        float s = 0.f;
        #pragma unroll
        for (int mi = 0; mi < 8; ++mi)
            #pragma unroll
            for (int j = 0; j < 4; ++j)
                s += __expf(acc[mi][ni][j] + ur[mi][j]);
        s += __shfl_xor(s, 16);
        s += __shfl_xor(s, 32);
        if (l < 16)
            atomicAdd(&colsum[(size_t)n * LLEN + colBase + wc*64 + ni*16 + l], s);
    }

    if (rowBase == colBase && (wc >> 1) == wr) {
        #pragma unroll
        for (int mi = 0; mi < 8; ++mi)
            #pragma unroll
            for (int ni = 0; ni < 4; ++ni)
                #pragma unroll
                for (int j = 0; j < 4; ++j) {
                    const int rr = wr*128 + mi*16 + (l >> 4)*4 + j;
                    const int cc = wc*64 + ni*16 + lr;
                    if (rr == cc)
                        diagv[(size_t)n * LLEN + rowBase + rr] = acc[mi][ni][j];
                }
    }
}

// ---- X f32 -> Xb bf16 + Xb8 fp8, single pass ----
__global__ __launch_bounds__(256) void cast_x_dual(
    const float* __restrict__ in, unsigned short* __restrict__ outb,
    unsigned char* __restrict__ out8, int n8)
{
    int i = blockIdx.x * 256 + threadIdx.x;
    if (i >= n8) return;
    const float4* p = reinterpret_cast<const float4*>(in) + (size_t)i * 2;
    float4 a = p[0], b = p[1];
    float f[8] = {a.x,a.y,a.z,a.w,b.x,b.y,b.z,b.w};
    short8 o; uchar8 o8;
    #pragma unroll
    for (int j = 0; j < 8; ++j) { o[j] = (short)f2bf(f[j]); o8[j] = f2fp8(f[j]); }
    *(reinterpret_cast<short8*>(outb) + i) = o;
    *(reinterpret_cast<uchar8*>(out8) + i) = o8;
}

// ---- fp32 -> bf16 ----
__global__ __launch_bounds__(256) void cast_f32_bf16(
    const float* __restrict__ in, unsigned short* __restrict__ outp, int n8)
{
    int i = blockIdx.x * 256 + threadIdx.x;
    if (i >= n8) return;
    const float4* p = reinterpret_cast<const float4*>(in) + (size_t)i * 2;
    float4 a = p[0], b = p[1];
    short8 o;
    o[0] = (short)f2bf(a.x); o[1] = (short)f2bf(a.y);
    o[2] = (short)f2bf(a.z); o[3] = (short)f2bf(a.w);
    o[4] = (short)f2bf(b.x); o[5] = (short)f2bf(b.y);
    o[6] = (short)f2bf(b.z); o[7] = (short)f2bf(b.w);
    *(reinterpret_cast<short8*>(outp) + i) = o;
}

// ---- Wv, Wf (K x N fp32) -> Wt (N x K bf16), z selects ----
__global__ __launch_bounds__(256) void transpose_cast2(
    const float* __restrict__ W0, const float* __restrict__ W1,
    unsigned short* __restrict__ Wt)
{
    const int z = blockIdx.z;
    const float* W = (z == 0) ? W0 : W1;
    unsigned short* dst = Wt + (size_t)z * HDIM * HDIM;
    __shared__ float tile[32][33];
    const int tx = threadIdx.x & 31, ty = threadIdx.x >> 5;
    const int c0 = blockIdx.x * 32, r0 = blockIdx.y * 32;
    #pragma unroll
    for (int r = 0; r < 4; ++r)
        tile[ty + r*8][tx] = W[(size_t)(r0 + ty + r*8) * HDIM + c0 + tx];
    __syncthreads();
    #pragma unroll
    for (int r = 0; r < 4; ++r)
        dst[(size_t)(c0 + ty + r*8) * HDIM + r0 + tx] = f2bf(tile[tx][ty + r*8]);
}

// ---- p[i] = Wq[i,:] . bk ----
__global__ __launch_bounds__(256) void pvec_kernel(
    const float* __restrict__ Wq, const float* __restrict__ bk,
    float* __restrict__ p)
{
    const int row = blockIdx.x * 4 + (threadIdx.x >> 6);
    const int l = threadIdx.x & 63;
    float s = 0.f;
    #pragma unroll
    for (int c = 0; c < HDIM; c += 64)
        s += Wq[(size_t)row * HDIM + c + l] * bk[c + l];
    #pragma unroll
    for (int off = 32; off > 0; off >>= 1) s += __shfl_down(s, off);
    if (l == 0) p[row] = s;
}

// ---- u[a] = sc2 * Xb[a,:] . p ----
__global__ __launch_bounds__(256) void uvec_kernel(
    const unsigned short* __restrict__ Xb, const float* __restrict__ p,
    float* __restrict__ u, float sc2)
{
    const int row = blockIdx.x * 4 + (threadIdx.x >> 6);
    const int l = threadIdx.x & 63;
    const unsigned short* xr = Xb + (size_t)row * HDIM + l * 16;
    float s = 0.f;
    #pragma unroll
    for (int k = 0; k < 2; ++k) {
        short8 v = *reinterpret_cast<const short8*>(xr + k*8);
        #pragma unroll
        for (int j = 0; j < 8; ++j)
            s += bf2f((unsigned short)v[j]) * p[l*16 + k*8 + j];
    }
    #pragma unroll
    for (int off = 32; off > 0; off >>= 1) s += __shfl_down(s, off);
    if (l == 0) u[row] = s * sc2;
}

// ---- h1 = bf16( LN(diag*V + Xb) * g1 + b1 ), X residual read as bf16 ----
__global__ __launch_bounds__(256) void ln1_kernel(
    const unsigned short* __restrict__ Vb, const unsigned short* __restrict__ Xbp,
    const float* __restrict__ colsum, const float* __restrict__ diagval,
    const float* __restrict__ uvec,
    const float* __restrict__ g1, const float* __restrict__ b1,
    unsigned short* __restrict__ h1)
{
    const int row = blockIdx.x;
    const size_t base = (size_t)row * HDIM;
    const float dv = __expf(diagval[row] + uvec[row]) / colsum[row];
    const int h0 = threadIdx.x * 4;

    ushort4v vv = *reinterpret_cast<const ushort4v*>(&Vb[base + h0]);
    ushort4v xx = *reinterpret_cast<const ushort4v*>(&Xbp[base + h0]);
    float y[4];
    y[0] = dv * bf2f(vv[0]) + bf2f(xx[0]); y[1] = dv * bf2f(vv[1]) + bf2f(xx[1]);
    y[2] = dv * bf2f(vv[2]) + bf2f(xx[2]); y[3] = dv * bf2f(vv[3]) + bf2f(xx[3]);

    float s = y[0]+y[1]+y[2]+y[3];
    float s2 = y[0]*y[0]+y[1]*y[1]+y[2]*y[2]+y[3]*y[3];
    #pragma unroll
    for (int off = 32; off > 0; off >>= 1) {
        s  += __shfl_down(s,  off);
        s2 += __shfl_down(s2, off);
    }
    __shared__ float ws1[4], ws2[4];
    const int wid = threadIdx.x >> 6;
    if ((threadIdx.x & 63) == 0) { ws1[wid] = s; ws2[wid] = s2; }
    __syncthreads();
    const float S  = ws1[0]+ws1[1]+ws1[2]+ws1[3];
    const float S2 = ws2[0]+ws2[1]+ws2[2]+ws2[3];
    const float m   = S  * (1.0f / HDIM);
    const float var = S2 * (1.0f / HDIM) - m*m;
    const float inv = rsqrtf(var + LNEPS);

    float4 gg = *reinterpret_cast<const float4*>(&g1[h0]);
    float4 bb = *reinterpret_cast<const float4*>(&b1[h0]);
    ushort4v o;
    o[0] = f2bf((y[0]-m)*inv*gg.x + bb.x);
    o[1] = f2bf((y[1]-m)*inv*gg.y + bb.y);
    o[2] = f2bf((y[2]-m)*inv*gg.z + bb.z);
    o[3] = f2bf((y[3]-m)*inv*gg.w + bb.w);
    *reinterpret_cast<ushort4v*>(&h1[base + h0]) = o;
}

// ---- out = fp32( LN(G + h1) * g2 + b2 ) ----
__global__ __launch_bounds__(256) void ln2_kernel(
    const unsigned short* __restrict__ Gb, const unsigned short* __restrict__ h1b,
    const float* __restrict__ g2, const float* __restrict__ b2,
    float* __restrict__ out)
{
    const int row = blockIdx.x;
    const size_t base = (size_t)row * HDIM;
    const int h0 = threadIdx.x * 4;

    ushort4v gv = *reinterpret_cast<const ushort4v*>(&Gb[base + h0]);
    ushort4v hv = *reinterpret_cast<const ushort4v*>(&h1b[base + h0]);
    float y[4];
    y[0] = bf2f(gv[0]) + bf2f(hv[0]); y[1] = bf2f(gv[1]) + bf2f(hv[1]);
    y[2] = bf2f(gv[2]) + bf2f(hv[2]); y[3] = bf2f(gv[3]) + bf2f(hv[3]);

    float s = y[0]+y[1]+y[2]+y[3];
    float s2 = y[0]*y[0]+y[1]*y[1]+y[2]*y[2]+y[3]*y[3];
    #pragma unroll
    for (int off = 32; off > 0; off >>= 1) {
        s  += __shfl_down(s,  off);
        s2 += __shfl_down(s2, off);
    }
    __shared__ float ws1[4], ws2[4];
    const int wid = threadIdx.x >> 6;
    if ((threadIdx.x & 63) == 0) { ws1[wid] = s; ws2[wid] = s2; }
    __syncthreads();
    const float S  = ws1[0]+ws1[1]+ws1[2]+ws1[3];
    const float S2 = ws2[0]+ws2[1]+ws2[2]+ws2[3];
    const float m   = S  * (1.0f / HDIM);
    const float var = S2 * (1.0f / HDIM) - m*m;
    const float inv = rsqrtf(var + LNEPS);

    float4 gg = *reinterpret_cast<const float4*>(&g2[h0]);
    float4 bb = *reinterpret_cast<const float4*>(&b2[h0]);
    float4 o;
    o.x = (y[0]-m)*inv*gg.x + bb.x;
    o.y = (y[1]-m)*inv*gg.y + bb.y;
    o.z = (y[2]-m)*inv*gg.z + bb.z;
    o.w = (y[3]-m)*inv*gg.w + bb.w;
    *reinterpret_cast<float4*>(&out[base + h0]) = o;
}

extern "C" void kernel_launch(void* const* d_in, const int* in_sizes, int n_in,
                              void* d_out, int out_size, void* d_ws, size_t ws_size,
                              hipStream_t stream) {
    (void)in_sizes; (void)n_in; (void)out_size; (void)ws_size;
    const float* X  = (const float*)d_in[0];
    const float* Wq = (const float*)d_in[1];
    const float* bq = (const float*)d_in[2];   (void)bq; // cancels in diag/colsum ratio
    const float* Wk = (const float*)d_in[3];
    const float* bk = (const float*)d_in[4];
    const float* Wv = (const float*)d_in[5];
    const float* bv = (const float*)d_in[6];
    const float* Wf = (const float*)d_in[7];
    const float* bf = (const float*)d_in[8];
    const float* g1 = (const float*)d_in[9];
    const float* b1 = (const float*)d_in[10];
    const float* g2 = (const float*)d_in[11];
    const float* b2 = (const float*)d_in[12];
    float* out = (float*)d_out;

    const size_t MATE = (size_t)NB * LLEN * HDIM;   // 16,777,216 elements
    const size_t WE   = (size_t)HDIM * HDIM;

    // d_out doubles as staging: Xb bf16 [0,32MiB), Vb bf16 [32,64MiB).
    unsigned short* Xb  = (unsigned short*)d_out;
    unsigned short* Vb  = Xb + MATE;

    unsigned short* h1b  = (unsigned short*)d_ws;   // 32 MiB
    unsigned short* Gb   = h1b + MATE;              // 32 MiB
    unsigned short* WqkT = Gb + MATE;               // [WqkT|WvT] contiguous
    unsigned short* WvT  = WqkT + WE;
    unsigned short* WfT  = WvT + WE;
    unsigned short* Wqb  = WfT + WE;
    unsigned short* Wkb  = Wqb + WE;
    float* colsum = (float*)(Wkb + WE);             // 64 KiB
    float* diagv  = colsum + (size_t)NB * LLEN;     // 64 KiB
    float* pv     = diagv + (size_t)NB * LLEN;      // 4 KiB
    float* uv     = pv + HDIM;                      // 64 KiB
    float* zvec   = uv + (size_t)NB * LLEN;         // 4 KiB
    unsigned char* Xq8 = (unsigned char*)(zvec + HDIM);  // 16 MiB
    unsigned char* Xb8 = Xq8 + MATE;                     // 16 MiB

    const int M = NB * LLEN;            // 16384
    const float sc2 = 1.0f / 1024.0f;   // (1/sqrt(H))^2

    hipMemsetAsync(colsum, 0, (size_t)NB * LLEN * sizeof(float), stream);
    hipMemsetAsync(zvec, 0, HDIM * sizeof(float), stream);

    cast_x_dual<<<(int)(MATE/8) / 256, 256, 0, stream>>>(X, Xb, Xb8, (int)(MATE/8));
    cast_f32_bf16<<<(int)(WE/8) / 256, 256, 0, stream>>>(Wq, Wqb, (int)(WE/8));
    cast_f32_bf16<<<(int)(WE/8) / 256, 256, 0, stream>>>(Wk, Wkb, (int)(WE/8));

    {
        dim3 tgrid(HDIM / 32, HDIM / 32, 2);
        transpose_cast2<<<tgrid, 256, 0, stream>>>(Wv, Wf, WvT);
    }

    // WqkT[j,i] = sc2 * Wk[j,:].Wq[i,:]
    gemm_proj<<<16, NTHR, 0, stream>>>(Wkb, Wqb, zvec, zvec, zvec,
                                       WqkT, WqkT, WqkT, (unsigned char*)nullptr,
                                       sc2, sc2, sc2, 4);

    // u'[a] = sc2 * X[a,:].(Wq @ bk)
    pvec_kernel<<<HDIM / 4, 256, 0, stream>>>(Wq, bk, pv);
    uvec_kernel<<<M / 4, 256, 0, stream>>>(Xb, pv, uv, sc2);

    // fused [Xq8 | V] = Xb @ [WqkT | WvT]^T
    // mat0 writes fp8 directly (x1024 scale; qk's A-scale 2^-10 undoes it)
    {
        const int gx = 2 * HDIM / BN;       // 8
        const int nwg = gx * (M / BM);      // 512
        gemm_proj<<<nwg, NTHR, 0, stream>>>(Xb, WqkT, zvec, bv, zvec,
                                            nullptr, Vb, Vb, Xq8,
                                            1024.0f, 1.0f, 1.0f, gx);
    }

    // qk: 1D grid, bid&7 = batch -> per-XCD L2 residency of Q/K panels
    qk_colsum_diag_fp8<<<512, NTHR, 0, stream>>>(Xq8, Xb8, uv, colsum, diagv);

    ln1_kernel<<<M, 256, 0, stream>>>(Vb, Xb, colsum, diagv, uv, g1, b1, h1b);

    // FF GEMM (bf16)
    {
        const int gx = HDIM / BN;           // 4
        const int nwg = gx * (M / BM);      // 256
        gemm_proj<<<nwg, NTHR, 0, stream>>>(h1b, WfT, bf, bf, bf,
                                            Gb, Gb, Gb, (unsigned char*)nullptr,
                                            1.0f, 1.0f, 1.0f, gx);
    }

    ln2_kernel<<<M, 256, 0, stream>>>(Gb, h1b, g2, b2, out);
}

// Round 12
// 247.797 us; speedup vs baseline: 3.4769x; 1.1366x over previous
//
#include <hip/hip_runtime.h>
#include <math.h>

#define NB   8
#define LLEN 2048
#define HDIM 1024
#define LNEPS 1e-5f

#define BM 256
#define BN 256
#define BK 64
#define NT_K (HDIM / BK)    // 16 bf16 K-tiles
#define NT_K8 (HDIM / 128)  // 8 fp8 K-tiles
#define NTHR 512
#define SLOT (BM * BK)      // 32 KiB per bf16 operand slot
#define SLOT8 32768         // 32 KiB per fp8 operand slot (256 rows x 128 B)

typedef __attribute__((ext_vector_type(8))) short short8;
typedef __attribute__((ext_vector_type(4))) unsigned short ushort4v;
typedef __attribute__((ext_vector_type(4))) float f32x4;
typedef __attribute__((ext_vector_type(4))) int int4v;
typedef __attribute__((ext_vector_type(8))) int int8v;
typedef __attribute__((ext_vector_type(8))) unsigned char uchar8;

typedef __attribute__((address_space(3))) void lds_void;
typedef const __attribute__((address_space(1))) void glob_void;

__device__ __forceinline__ unsigned short f2bf(float f) {
    union { float f; unsigned u; } v; v.f = f;
    unsigned r = v.u + 0x7FFFu + ((v.u >> 16) & 1u);
    return (unsigned short)(r >> 16);
}
__device__ __forceinline__ float bf2f(unsigned short h) {
    union { unsigned u; float f; } v; v.u = ((unsigned)h) << 16;
    return v.f;
}

// OCP e4m3fn encode, RNE (HW-verified numerically rounds 8-11). Fallback path.
__device__ __forceinline__ unsigned char f2fp8(float x) {
    union { float f; unsigned u; } v; v.f = x;
    unsigned s = (v.u >> 24) & 0x80u;
    float a = fabsf(x);
    if (!(a < 448.f)) return (unsigned char)(s | 0x7E);
    int e = (int)((v.u >> 23) & 0xFF) - 127;
    if (e < -6) e = -6;
    float q = rintf(ldexpf(a, 3 - e));
    if (q >= 16.f) { q *= 0.5f; e += 1; }
    int qi = (int)q;
    unsigned byte = (qi < 8) ? (unsigned)qi
                             : (((unsigned)(e + 7) << 3) | (unsigned)(qi - 8));
    return (unsigned char)(s | byte);
}
// e4m3fn decode (software; cold path, 4/thread in ln1)
__device__ __forceinline__ float fp8d(unsigned char b) {
    int e = (b >> 3) & 15, m = b & 7;
    float v = e ? ldexpf((float)(8 + m), e - 10) : ldexpf((float)m, -9);
    return (b & 0x80) ? -v : v;
}

// Pack 4 f32 -> 4 fp8 bytes. HW v_cvt_pk_fp8_f32 when available (2 inst),
// else software (guarded: compile-safe either way).
__device__ __forceinline__ unsigned pack4_fp8(float a, float b, float c, float d) {
#if __has_builtin(__builtin_amdgcn_cvt_pk_fp8_f32)
    int r = __builtin_amdgcn_cvt_pk_fp8_f32(a, b, 0, false);
    r = __builtin_amdgcn_cvt_pk_fp8_f32(c, d, r, true);
    return (unsigned)r;
#else
    return (unsigned)f2fp8(a) | ((unsigned)f2fp8(b) << 8)
         | ((unsigned)f2fp8(c) << 16) | ((unsigned)f2fp8(d) << 24);
#endif
}

__device__ __forceinline__ void wg_barrier() {
    asm volatile("" ::: "memory");
    __builtin_amdgcn_s_barrier();
    asm volatile("" ::: "memory");
}

// ---------------- bf16 pipeline (round-7, proven) ----------------
__device__ __forceinline__ void stage_tile(
    const unsigned short* __restrict__ src, int R0, int kcol0,
    unsigned short* ldsDst, int w, int lane)
{
    const int rsub = lane >> 3;
    const int csw  = 8 * ((lane & 7) ^ rsub);
    #pragma unroll
    for (int s = 0; s < 4; ++s) {
        const int r = (s*8 + w)*8 + rsub;
        const unsigned short* g = src + (size_t)(R0 + r) * HDIM + kcol0 + csw;
        __builtin_amdgcn_global_load_lds(
            (glob_void*)g, (lds_void*)(ldsDst + (s*8 + w)*512), 16, 0, 0);
    }
}

__device__ __forceinline__ void run_pipeline(
    const unsigned short* __restrict__ srcA,
    const unsigned short* __restrict__ srcB,
    int rowBase, int colBase,
    unsigned short* lds, f32x4 (&acc)[8][4])
{
    const int t = threadIdx.x, w = t >> 6, l = t & 63;
    const int wr = w >> 2, wc = w & 3;
    const int lr = l & 15;
    const int sw = (l & 7) << 4;
    const int aRB = (wr*128 + lr) * 128;
    const int bRB = (wc*64  + lr) * 128;
    const int c0 = ((l >> 4) * 16) ^ sw;
    const int c1 = (64 + ((l >> 4) * 16)) ^ sw;

    unsigned short* sA[2] = { lds,            lds + 2*SLOT };
    unsigned short* sB[2] = { lds + SLOT,     lds + 3*SLOT };

    stage_tile(srcA, rowBase, 0,  sA[0], w, l);
    stage_tile(srcB, colBase, 0,  sB[0], w, l);
    stage_tile(srcA, rowBase, BK, sA[1], w, l);
    stage_tile(srcB, colBase, BK, sB[1], w, l);
    asm volatile("s_waitcnt vmcnt(8)" ::: "memory");
    wg_barrier();

    for (int kt = 0; kt < NT_K; ++kt) {
        const char* bufA = (const char*)sA[kt & 1];
        const char* bufB = (const char*)sB[kt & 1];
        #pragma unroll
        for (int kk = 0; kk < 2; ++kk) {
            const int cc = kk ? c1 : c0;
            short8 af[8], bfr[4];
            #pragma unroll
            for (int mi = 0; mi < 8; ++mi)
                af[mi] = *(const short8*)(bufA + aRB + mi*2048 + cc);
            #pragma unroll
            for (int ni = 0; ni < 4; ++ni)
                bfr[ni] = *(const short8*)(bufB + bRB + ni*2048 + cc);
            #pragma unroll
            for (int mi = 0; mi < 8; ++mi)
                #pragma unroll
                for (int ni = 0; ni < 4; ++ni)
                    acc[mi][ni] = __builtin_amdgcn_mfma_f32_16x16x32_bf16(
                        af[mi], bfr[ni], acc[mi][ni], 0, 0, 0);
        }
        if (kt == NT_K - 1) break;
        wg_barrier();
        if (kt + 2 < NT_K) {
            stage_tile(srcA, rowBase, (kt+2)*BK, sA[kt&1], w, l);
            stage_tile(srcB, colBase, (kt+2)*BK, sB[kt&1], w, l);
            asm volatile("s_waitcnt vmcnt(8)" ::: "memory");
        } else {
            asm volatile("s_waitcnt vmcnt(0)" ::: "memory");
        }
        wg_barrier();
    }
}

// ---------------- fp8 pipeline (shufflevector concat; rounds 9-11 verified) ----------------
__device__ __forceinline__ void stage_tile8(
    const unsigned char* __restrict__ src, int R0, int kcol0,
    unsigned char* ldsDst, int w, int lane)
{
    const int rsub = lane >> 3;
    const int csw  = ((lane & 7) ^ rsub) << 4;
    #pragma unroll
    for (int s = 0; s < 4; ++s) {
        const int r = (s*8 + w)*8 + rsub;
        __builtin_amdgcn_global_load_lds(
            (glob_void*)(src + (size_t)(R0 + r) * HDIM + kcol0 + csw),
            (lds_void*)(ldsDst + (s*8 + w)*1024), 16, 0, 0);
    }
}

// Only the PRODUCT of sa/sb matters (uniform e8m0 scales commute with the dot).
__device__ __forceinline__ void run_pipeline_fp8(
    const unsigned char* __restrict__ srcA,
    const unsigned char* __restrict__ srcB,
    int rowBase, int colBase,
    unsigned char* lds, f32x4 (&acc)[8][4],
    unsigned sa, unsigned sb)
{
    const int t = threadIdx.x, w = t >> 6, l = t & 63;
    const int wr = w >> 2, wc = w & 3;
    const int lr = l & 15;
    const int sw = (l & 7) << 4;
    const int aRB = (wr*128 + lr) * 128;
    const int bRB = (wc*64  + lr) * 128;
    const int g0 = (l >> 4) * 32;
    const int cc0 = g0 ^ sw;
    const int cc1 = (g0 + 16) ^ sw;

    unsigned char* sA[2] = { lds,             lds + 2*SLOT8 };
    unsigned char* sB[2] = { lds + SLOT8,     lds + 3*SLOT8 };

    stage_tile8(srcA, rowBase, 0,   sA[0], w, l);
    stage_tile8(srcB, colBase, 0,   sB[0], w, l);
    stage_tile8(srcA, rowBase, 128, sA[1], w, l);
    stage_tile8(srcB, colBase, 128, sB[1], w, l);
    asm volatile("s_waitcnt vmcnt(8)" ::: "memory");
    wg_barrier();

    for (int kt = 0; kt < NT_K8; ++kt) {
        const char* bufA = (const char*)sA[kt & 1];
        const char* bufB = (const char*)sB[kt & 1];
        int8v b8[4];
        #pragma unroll
        for (int ni = 0; ni < 4; ++ni)
            b8[ni] = __builtin_shufflevector(
                *(const int4v*)(bufB + bRB + ni*2048 + cc0),
                *(const int4v*)(bufB + bRB + ni*2048 + cc1),
                0, 1, 2, 3, 4, 5, 6, 7);
        #pragma unroll
        for (int mi = 0; mi < 8; ++mi) {
            int8v a8 = __builtin_shufflevector(
                *(const int4v*)(bufA + aRB + mi*2048 + cc0),
                *(const int4v*)(bufA + aRB + mi*2048 + cc1),
                0, 1, 2, 3, 4, 5, 6, 7);
            #pragma unroll
            for (int ni = 0; ni < 4; ++ni)
                acc[mi][ni] = __builtin_amdgcn_mfma_scale_f32_16x16x128_f8f6f4(
                    a8, b8[ni], acc[mi][ni], 0, 0, 0, sa, 0, sb);
        }
        if (kt == NT_K8 - 1) break;
        wg_barrier();
        if (kt + 2 < NT_K8) {
            stage_tile8(srcA, rowBase, (kt+2)*128, sA[kt&1], w, l);
            stage_tile8(srcB, colBase, (kt+2)*128, sB[kt&1], w, l);
            asm volatile("s_waitcnt vmcnt(8)" ::: "memory");
        } else {
            asm volatile("s_waitcnt vmcnt(0)" ::: "memory");
        }
        wg_barrier();
    }
}

// ---- bf16 multi-output GEMM; mat==0 may write fp8 directly (C8 != null) ----
__global__ __launch_bounds__(NTHR, 2) void gemm_proj(
    const unsigned short* __restrict__ A,
    const unsigned short* __restrict__ Bt,
    const float* __restrict__ bias0, const float* __restrict__ bias1,
    const float* __restrict__ bias2,
    unsigned short* __restrict__ C0, unsigned short* __restrict__ C1,
    unsigned short* __restrict__ C2,
    unsigned char* __restrict__ C8,
    float al0, float al1, float al2, int gx)
{
    __shared__ __align__(16) unsigned short lds[4 * SLOT];
    const int nwg = gridDim.x, bid = blockIdx.x;
    const int swz = (bid & 7) * (nwg >> 3) + (bid >> 3);
    const int bx = swz % gx, by = swz / gx;
    const int rowBase = by * BM, colBase = bx * BN;

    f32x4 acc[8][4] = {};
    run_pipeline(A, Bt, rowBase, colBase, lds, acc);

    const int t = threadIdx.x, w = t >> 6, l = t & 63;
    const int wr = w >> 2, wc = w & 3;
    const int lr = l & 15;

    const int mat = colBase >> 10;
    unsigned short* Cm = (mat == 0) ? C0 : (mat == 1 ? C1 : C2);
    const float* bm    = (mat == 0) ? bias0 : (mat == 1 ? bias1 : bias2);
    const float am     = (mat == 0) ? al0 : (mat == 1 ? al1 : al2);
    const int lcb = colBase & (HDIM - 1);

    if (mat == 0 && C8) {
        #pragma unroll
        for (int ni = 0; ni < 4; ++ni) {
            const int col = lcb + wc*64 + ni*16 + lr;
            const float bv = bm[col];
            #pragma unroll
            for (int mi = 0; mi < 8; ++mi) {
                const int row0 = rowBase + wr*128 + mi*16 + (l >> 4) * 4;
                const unsigned wd = pack4_fp8(
                    am * (acc[mi][ni][0] + bv), am * (acc[mi][ni][1] + bv),
                    am * (acc[mi][ni][2] + bv), am * (acc[mi][ni][3] + bv));
                #pragma unroll
                for (int j = 0; j < 4; ++j)
                    C8[(size_t)(row0 + j) * HDIM + col] = (unsigned char)(wd >> (8*j));
            }
        }
        return;
    }

    #pragma unroll
    for (int ni = 0; ni < 4; ++ni) {
        const int col = lcb + wc*64 + ni*16 + lr;
        const float bv = bm[col];
        #pragma unroll
        for (int mi = 0; mi < 8; ++mi) {
            const int row0 = rowBase + wr*128 + mi*16 + (l >> 4) * 4;
            #pragma unroll
            for (int j = 0; j < 4; ++j)
                Cm[(size_t)(row0 + j) * HDIM + col] = f2bf(am * (acc[mi][ni][j] + bv));
        }
    }
}

// ---- fp8 fused proj: [Xq8 | V8] = fp8( al_mat * (Xb8 @ W8^T + bias_mat) ) ----
__global__ __launch_bounds__(NTHR, 2) void gemm_proj_fp8(
    const unsigned char* __restrict__ A,
    const unsigned char* __restrict__ Bt,
    const float* __restrict__ bias0, const float* __restrict__ bias1,
    unsigned char* __restrict__ C0, unsigned char* __restrict__ C1,
    float al0, float al1, unsigned sb0, unsigned sb1, int gx)
{
    __shared__ __align__(16) unsigned char lds8[4 * SLOT8];
    const int nwg = gridDim.x, bid = blockIdx.x;
    const int swz = (bid & 7) * (nwg >> 3) + (bid >> 3);
    const int bx = swz % gx, by = swz / gx;
    const int rowBase = by * BM, colBase = bx * BN;

    const int mat = colBase >> 10;

    f32x4 acc[8][4] = {};
    run_pipeline_fp8(A, Bt, rowBase, colBase, lds8, acc,
                     0x7F7F7F7Fu, mat ? sb1 : sb0);

    const int t = threadIdx.x, w = t >> 6, l = t & 63;
    const int wr = w >> 2, wc = w & 3;
    const int lr = l & 15;

    unsigned char* Cm  = mat ? C1 : C0;
    const float* bm    = mat ? bias1 : bias0;
    const float am     = mat ? al1 : al0;
    const int lcb = colBase & (HDIM - 1);

    #pragma unroll
    for (int ni = 0; ni < 4; ++ni) {
        const int col = lcb + wc*64 + ni*16 + lr;
        const float bv = bm[col];
        #pragma unroll
        for (int mi = 0; mi < 8; ++mi) {
            const int row0 = rowBase + wr*128 + mi*16 + (l >> 4) * 4;
            const unsigned wd = pack4_fp8(
                am * (acc[mi][ni][0] + bv), am * (acc[mi][ni][1] + bv),
                am * (acc[mi][ni][2] + bv), am * (acc[mi][ni][3] + bv));
            #pragma unroll
            for (int j = 0; j < 4; ++j)
                Cm[(size_t)(row0 + j) * HDIM + col] = (unsigned char)(wd >> (8*j));
        }
    }
}

// ---- fp8 qk, batch-per-XCD grid: bid&7 = batch ----
__global__ __launch_bounds__(NTHR, 2) void qk_colsum_diag_fp8(
    const unsigned char* __restrict__ Xq8,
    const unsigned char* __restrict__ Xb8,
    const float* __restrict__ uvec,
    float* __restrict__ colsum, float* __restrict__ diagv)
{
    __shared__ __align__(16) unsigned char lds8[4 * SLOT8];
    const int bid = blockIdx.x;          // 512
    const int n = bid & 7;
    const int rem = bid >> 3;            // 0..63
    const int rowBase = (rem & 7) * BM;
    const int colBase = (rem >> 3) * BN;
    const unsigned char* An = Xq8 + (size_t)n * LLEN * HDIM;
    const unsigned char* Bn = Xb8 + (size_t)n * LLEN * HDIM;

    f32x4 acc[8][4] = {};
    run_pipeline_fp8(An, Bn, rowBase, colBase, lds8, acc,
                     0x75757575u, 0x7F7F7F7Fu);

    const int t = threadIdx.x, w = t >> 6, l = t & 63;
    const int wr = w >> 2, wc = w & 3;
    const int lr = l & 15;

    float ur[8][4];
    #pragma unroll
    for (int mi = 0; mi < 8; ++mi)
        #pragma unroll
        for (int j = 0; j < 4; ++j)
            ur[mi][j] = uvec[(size_t)n * LLEN + rowBase + wr*128 + mi*16 + (l>>4)*4 + j];

    #pragma unroll
    for (int ni = 0; ni < 4; ++ni) {
        float s = 0.f;
        #pragma unroll
        for (int mi = 0; mi < 8; ++mi)
            #pragma unroll
            for (int j = 0; j < 4; ++j)
                s += __expf(acc[mi][ni][j] + ur[mi][j]);
        s += __shfl_xor(s, 16);
        s += __shfl_xor(s, 32);
        if (l < 16)
            atomicAdd(&colsum[(size_t)n * LLEN + colBase + wc*64 + ni*16 + l], s);
    }

    if (rowBase == colBase && (wc >> 1) == wr) {
        #pragma unroll
        for (int mi = 0; mi < 8; ++mi)
            #pragma unroll
            for (int ni = 0; ni < 4; ++ni)
                #pragma unroll
                for (int j = 0; j < 4; ++j) {
                    const int rr = wr*128 + mi*16 + (l >> 4)*4 + j;
                    const int cc = wc*64 + ni*16 + lr;
                    if (rr == cc)
                        diagv[(size_t)n * LLEN + rowBase + rr] = acc[mi][ni][j];
                }
    }
}

// ---- X f32 -> Xb bf16 + Xb8 fp8, single pass ----
__global__ __launch_bounds__(256) void cast_x_dual(
    const float* __restrict__ in, unsigned short* __restrict__ outb,
    unsigned char* __restrict__ out8, int n8)
{
    int i = blockIdx.x * 256 + threadIdx.x;
    if (i >= n8) return;
    const float4* p = reinterpret_cast<const float4*>(in) + (size_t)i * 2;
    float4 a = p[0], b = p[1];
    short8 o;
    o[0] = (short)f2bf(a.x); o[1] = (short)f2bf(a.y);
    o[2] = (short)f2bf(a.z); o[3] = (short)f2bf(a.w);
    o[4] = (short)f2bf(b.x); o[5] = (short)f2bf(b.y);
    o[6] = (short)f2bf(b.z); o[7] = (short)f2bf(b.w);
    unsigned w0 = pack4_fp8(a.x, a.y, a.z, a.w);
    unsigned w1 = pack4_fp8(b.x, b.y, b.z, b.w);
    *(reinterpret_cast<short8*>(outb) + i) = o;
    uint2 pk; pk.x = w0; pk.y = w1;
    *(reinterpret_cast<uint2*>(out8) + i) = pk;
}

// ---- fp32 -> bf16 ----
__global__ __launch_bounds__(256) void cast_f32_bf16(
    const float* __restrict__ in, unsigned short* __restrict__ outp, int n8)
{
    int i = blockIdx.x * 256 + threadIdx.x;
    if (i >= n8) return;
    const float4* p = reinterpret_cast<const float4*>(in) + (size_t)i * 2;
    float4 a = p[0], b = p[1];
    short8 o;
    o[0] = (short)f2bf(a.x); o[1] = (short)f2bf(a.y);
    o[2] = (short)f2bf(a.z); o[3] = (short)f2bf(a.w);
    o[4] = (short)f2bf(b.x); o[5] = (short)f2bf(b.y);
    o[6] = (short)f2bf(b.z); o[7] = (short)f2bf(b.w);
    *(reinterpret_cast<short8*>(outp) + i) = o;
}

// ---- W (K x N fp32) -> bf16 N x K ----
__global__ __launch_bounds__(256) void transpose_cast_bf16(
    const float* __restrict__ W, unsigned short* __restrict__ Wt)
{
    __shared__ float tile[32][33];
    const int tx = threadIdx.x & 31, ty = threadIdx.x >> 5;
    const int c0 = blockIdx.x * 32, r0 = blockIdx.y * 32;
    #pragma unroll
    for (int r = 0; r < 4; ++r)
        tile[ty + r*8][tx] = W[(size_t)(r0 + ty + r*8) * HDIM + c0 + tx];
    __syncthreads();
    #pragma unroll
    for (int r = 0; r < 4; ++r)
        Wt[(size_t)(c0 + ty + r*8) * HDIM + r0 + tx] = f2bf(tile[tx][ty + r*8]);
}

// ---- W (K x N fp32) -> fp8 N x K, value scaled by `scale` ----
__global__ __launch_bounds__(256) void transpose_cast_fp8(
    const float* __restrict__ W, unsigned char* __restrict__ Wt, float scale)
{
    __shared__ float tile[32][33];
    const int tx = threadIdx.x & 31, ty = threadIdx.x >> 5;
    const int c0 = blockIdx.x * 32, r0 = blockIdx.y * 32;
    #pragma unroll
    for (int r = 0; r < 4; ++r)
        tile[ty + r*8][tx] = W[(size_t)(r0 + ty + r*8) * HDIM + c0 + tx];
    __syncthreads();
    #pragma unroll
    for (int r = 0; r < 4; ++r)
        Wt[(size_t)(c0 + ty + r*8) * HDIM + r0 + tx] = f2fp8(tile[tx][ty + r*8] * scale);
}

// ---- p[i] = Wq[i,:] . bk ----
__global__ __launch_bounds__(256) void pvec_kernel(
    const float* __restrict__ Wq, const float* __restrict__ bk,
    float* __restrict__ p)
{
    const int row = blockIdx.x * 4 + (threadIdx.x >> 6);
    const int l = threadIdx.x & 63;
    float s = 0.f;
    #pragma unroll
    for (int c = 0; c < HDIM; c += 64)
        s += Wq[(size_t)row * HDIM + c + l] * bk[c + l];
    #pragma unroll
    for (int off = 32; off > 0; off >>= 1) s += __shfl_down(s, off);
    if (l == 0) p[row] = s;
}

// ---- u[a] = sc2 * Xb[a,:] . p ----
__global__ __launch_bounds__(256) void uvec_kernel(
    const unsigned short* __restrict__ Xb, const float* __restrict__ p,
    float* __restrict__ u, float sc2)
{
    const int row = blockIdx.x * 4 + (threadIdx.x >> 6);
    const int l = threadIdx.x & 63;
    const unsigned short* xr = Xb + (size_t)row * HDIM + l * 16;
    float s = 0.f;
    #pragma unroll
    for (int k = 0; k < 2; ++k) {
        short8 v = *reinterpret_cast<const short8*>(xr + k*8);
        #pragma unroll
        for (int j = 0; j < 8; ++j)
            s += bf2f((unsigned short)v[j]) * p[l*16 + k*8 + j];
    }
    #pragma unroll
    for (int off = 32; off > 0; off >>= 1) s += __shfl_down(s, off);
    if (l == 0) u[row] = s * sc2;
}

// ---- h1 = bf16( LN(diag*V8 + Xb) * g1 + b1 ) ----
__global__ __launch_bounds__(256) void ln1_kernel(
    const unsigned char* __restrict__ V8, const unsigned short* __restrict__ Xbp,
    const float* __restrict__ colsum, const float* __restrict__ diagval,
    const float* __restrict__ uvec,
    const float* __restrict__ g1, const float* __restrict__ b1,
    unsigned short* __restrict__ h1)
{
    const int row = blockIdx.x;
    const size_t base = (size_t)row * HDIM;
    const float dv = __expf(diagval[row] + uvec[row]) / colsum[row];
    const int h0 = threadIdx.x * 4;

    unsigned vv = *reinterpret_cast<const unsigned*>(&V8[base + h0]);
    ushort4v xx = *reinterpret_cast<const ushort4v*>(&Xbp[base + h0]);
    float y[4];
    y[0] = dv * fp8d((unsigned char)(vv      )) + bf2f(xx[0]);
    y[1] = dv * fp8d((unsigned char)(vv >>  8)) + bf2f(xx[1]);
    y[2] = dv * fp8d((unsigned char)(vv >> 16)) + bf2f(xx[2]);
    y[3] = dv * fp8d((unsigned char)(vv >> 24)) + bf2f(xx[3]);

    float s = y[0]+y[1]+y[2]+y[3];
    float s2 = y[0]*y[0]+y[1]*y[1]+y[2]*y[2]+y[3]*y[3];
    #pragma unroll
    for (int off = 32; off > 0; off >>= 1) {
        s  += __shfl_down(s,  off);
        s2 += __shfl_down(s2, off);
    }
    __shared__ float ws1[4], ws2[4];
    const int wid = threadIdx.x >> 6;
    if ((threadIdx.x & 63) == 0) { ws1[wid] = s; ws2[wid] = s2; }
    __syncthreads();
    const float S  = ws1[0]+ws1[1]+ws1[2]+ws1[3];
    const float S2 = ws2[0]+ws2[1]+ws2[2]+ws2[3];
    const float m   = S  * (1.0f / HDIM);
    const float var = S2 * (1.0f / HDIM) - m*m;
    const float inv = rsqrtf(var + LNEPS);

    float4 gg = *reinterpret_cast<const float4*>(&g1[h0]);
    float4 bb = *reinterpret_cast<const float4*>(&b1[h0]);
    ushort4v o;
    o[0] = f2bf((y[0]-m)*inv*gg.x + bb.x);
    o[1] = f2bf((y[1]-m)*inv*gg.y + bb.y);
    o[2] = f2bf((y[2]-m)*inv*gg.z + bb.z);
    o[3] = f2bf((y[3]-m)*inv*gg.w + bb.w);
    *reinterpret_cast<ushort4v*>(&h1[base + h0]) = o;
}

// ---- out = fp32( LN(G + h1) * g2 + b2 ) ----
__global__ __launch_bounds__(256) void ln2_kernel(
    const unsigned short* __restrict__ Gb, const unsigned short* __restrict__ h1b,
    const float* __restrict__ g2, const float* __restrict__ b2,
    float* __restrict__ out)
{
    const int row = blockIdx.x;
    const size_t base = (size_t)row * HDIM;
    const int h0 = threadIdx.x * 4;

    ushort4v gv = *reinterpret_cast<const ushort4v*>(&Gb[base + h0]);
    ushort4v hv = *reinterpret_cast<const ushort4v*>(&h1b[base + h0]);
    float y[4];
    y[0] = bf2f(gv[0]) + bf2f(hv[0]); y[1] = bf2f(gv[1]) + bf2f(hv[1]);
    y[2] = bf2f(gv[2]) + bf2f(hv[2]); y[3] = bf2f(gv[3]) + bf2f(hv[3]);

    float s = y[0]+y[1]+y[2]+y[3];
    float s2 = y[0]*y[0]+y[1]*y[1]+y[2]*y[2]+y[3]*y[3];
    #pragma unroll
    for (int off = 32; off > 0; off >>= 1) {
        s  += __shfl_down(s,  off);
        s2 += __shfl_down(s2, off);
    }
    __shared__ float ws1[4], ws2[4];
    const int wid = threadIdx.x >> 6;
    if ((threadIdx.x & 63) == 0) { ws1[wid] = s; ws2[wid] = s2; }
    __syncthreads();
    const float S  = ws1[0]+ws1[1]+ws1[2]+ws1[3];
    const float S2 = ws2[0]+ws2[1]+ws2[2]+ws2[3];
    const float m   = S  * (1.0f / HDIM);
    const float var = S2 * (1.0f / HDIM) - m*m;
    const float inv = rsqrtf(var + LNEPS);

    float4 gg = *reinterpret_cast<const float4*>(&g2[h0]);
    float4 bb = *reinterpret_cast<const float4*>(&b2[h0]);
    float4 o;
    o.x = (y[0]-m)*inv*gg.x + bb.x;
    o.y = (y[1]-m)*inv*gg.y + bb.y;
    o.z = (y[2]-m)*inv*gg.z + bb.z;
    o.w = (y[3]-m)*inv*gg.w + bb.w;
    *reinterpret_cast<float4*>(&out[base + h0]) = o;
}

extern "C" void kernel_launch(void* const* d_in, const int* in_sizes, int n_in,
                              void* d_out, int out_size, void* d_ws, size_t ws_size,
                              hipStream_t stream) {
    (void)in_sizes; (void)n_in; (void)out_size; (void)ws_size;
    const float* X  = (const float*)d_in[0];
    const float* Wq = (const float*)d_in[1];
    const float* bq = (const float*)d_in[2];   (void)bq; // cancels in diag/colsum ratio
    const float* Wk = (const float*)d_in[3];
    const float* bk = (const float*)d_in[4];
    const float* Wv = (const float*)d_in[5];
    const float* bv = (const float*)d_in[6];
    const float* Wf = (const float*)d_in[7];
    const float* bf = (const float*)d_in[8];
    const float* g1 = (const float*)d_in[9];
    const float* b1 = (const float*)d_in[10];
    const float* g2 = (const float*)d_in[11];
    const float* b2 = (const float*)d_in[12];
    float* out = (float*)d_out;

    const size_t MATE = (size_t)NB * LLEN * HDIM;   // 16,777,216 elements
    const size_t WE   = (size_t)HDIM * HDIM;

    // d_out staging: Xb bf16 [0,32MiB), V8 fp8 [32,48MiB). Dead before ln2 writes out.
    unsigned short* Xb  = (unsigned short*)d_out;
    unsigned char*  V8  = (unsigned char*)(Xb + MATE);

    unsigned short* h1b   = (unsigned short*)d_ws;  // 32 MiB
    unsigned short* Gb    = h1b + MATE;             // 32 MiB
    unsigned short* WfT   = Gb + MATE;              // 2 MiB
    unsigned short* Wqb   = WfT + WE;               // 2 MiB
    unsigned short* Wkb   = Wqb + WE;               // 2 MiB
    unsigned char*  Wqk8T = (unsigned char*)(Wkb + WE); // 1 MiB; [Wqk8T|Wv8T] contiguous
    unsigned char*  Wv8T  = Wqk8T + WE;                 // 1 MiB
    float* colsum = (float*)(Wv8T + WE);            // 64 KiB
    float* diagv  = colsum + (size_t)NB * LLEN;     // 64 KiB
    float* pv     = diagv + (size_t)NB * LLEN;      // 4 KiB
    float* uv     = pv + HDIM;                      // 64 KiB
    float* zvec   = uv + (size_t)NB * LLEN;         // 4 KiB
    unsigned char* Xq8 = (unsigned char*)(zvec + HDIM);  // 16 MiB
    unsigned char* Xb8 = Xq8 + MATE;                     // 16 MiB

    const int M = NB * LLEN;            // 16384
    const float sc2 = 1.0f / 1024.0f;   // (1/sqrt(H))^2

    hipMemsetAsync(colsum, 0, (size_t)NB * LLEN * sizeof(float), stream);
    hipMemsetAsync(zvec, 0, HDIM * sizeof(float), stream);

    cast_x_dual<<<(int)(MATE/8) / 256, 256, 0, stream>>>(X, Xb, Xb8, (int)(MATE/8));
    cast_f32_bf16<<<(int)(WE/8) / 256, 256, 0, stream>>>(Wq, Wqb, (int)(WE/8));
    cast_f32_bf16<<<(int)(WE/8) / 256, 256, 0, stream>>>(Wk, Wkb, (int)(WE/8));

    {
        dim3 tgrid(HDIM / 32, HDIM / 32);
        transpose_cast_bf16<<<tgrid, 256, 0, stream>>>(Wf, WfT);
        transpose_cast_fp8<<<tgrid, 256, 0, stream>>>(Wv, Wv8T, 16.0f);   // x2^4
    }

    // Wqk8T[j,i] = fp8( 64 * Wk[j,:].Wq[i,:] )   (64 = sc2 * 2^16; ~0.8 range)
    gemm_proj<<<16, NTHR, 0, stream>>>(Wkb, Wqb, zvec, zvec, zvec,
                                       nullptr, nullptr, nullptr, Wqk8T,
                                       64.0f, 64.0f, 64.0f, 4);

    // u'[a] = sc2 * X[a,:].(Wq @ bk)
    pvec_kernel<<<HDIM / 4, 256, 0, stream>>>(Wq, bk, pv);
    uvec_kernel<<<M / 4, 256, 0, stream>>>(Xb, pv, uv, sc2);

    // fp8 fused proj: [Xq8 | V8] = Xb8 @ [Wqk8T | Wv8T]^T
    // mat0: sb=2^-16 (Wqk x2^16), epilogue x1024 -> Xq8 (qk's sa=2^-10 undoes it)
    // mat1: sb=2^-4  (Wv  x2^4),  epilogue +bv    -> V8
    {
        const int gx = 2 * HDIM / BN;       // 8
        const int nwg = gx * (M / BM);      // 512 (%8==0)
        gemm_proj_fp8<<<nwg, NTHR, 0, stream>>>(Xb8, Wqk8T, zvec, bv,
                                                Xq8, V8, 1024.0f, 1.0f,
                                                0x6F6F6F6Fu /*2^-16*/,
                                                0x7B7B7B7Bu /*2^-4*/, gx);
    }

    // qk: 1D grid, bid&7 = batch -> per-XCD L2 residency of Q/K panels
    qk_colsum_diag_fp8<<<512, NTHR, 0, stream>>>(Xq8, Xb8, uv, colsum, diagv);

    ln1_kernel<<<M, 256, 0, stream>>>(V8, Xb, colsum, diagv, uv, g1, b1, h1b);

    // FF GEMM (bf16; full-scale numerics through LN2)
    {
        const int gx = HDIM / BN;           // 4
        const int nwg = gx * (M / BM);      // 256
        gemm_proj<<<nwg, NTHR, 0, stream>>>(h1b, WfT, bf, bf, bf,
                                            Gb, Gb, Gb, (unsigned char*)nullptr,
                                            1.0f, 1.0f, 1.0f, gx);
    }

    ln2_kernel<<<M, 256, 0, stream>>>(Gb, h1b, g2, b2, out);
}

// Round 14
// 232.627 us; speedup vs baseline: 3.7037x; 1.0652x over previous
//
#include <hip/hip_runtime.h>
#include <math.h>

#define NB   8
#define LLEN 2048
#define HDIM 1024
#define LNEPS 1e-5f

#define BM 256
#define BN 256
#define BK 64
#define NT_K (HDIM / BK)    // 16 bf16 K-tiles
#define NT_K8 (HDIM / 128)  // 8 fp8 K-tiles
#define NTHR 512
#define SLOT (BM * BK)      // 32 KiB per bf16 operand slot
#define SLOT8 32768         // 32 KiB per fp8 operand slot (256 rows x 128 B)

typedef __attribute__((ext_vector_type(8))) short short8;
typedef __attribute__((ext_vector_type(4))) unsigned short ushort4v;
typedef __attribute__((ext_vector_type(4))) float f32x4;
typedef __attribute__((ext_vector_type(4))) int int4v;
typedef __attribute__((ext_vector_type(8))) int int8v;
typedef __attribute__((ext_vector_type(8))) unsigned char uchar8;

typedef __attribute__((address_space(3))) void lds_void;
typedef const __attribute__((address_space(1))) void glob_void;

__device__ __forceinline__ unsigned short f2bf(float f) {
    union { float f; unsigned u; } v; v.f = f;
    unsigned r = v.u + 0x7FFFu + ((v.u >> 16) & 1u);
    return (unsigned short)(r >> 16);
}
__device__ __forceinline__ float bf2f(unsigned short h) {
    union { unsigned u; float f; } v; v.u = ((unsigned)h) << 16;
    return v.f;
}

// OCP e4m3fn encode, RNE (HW-verified rounds 8-12). Fallback path.
__device__ __forceinline__ unsigned char f2fp8(float x) {
    union { float f; unsigned u; } v; v.f = x;
    unsigned s = (v.u >> 24) & 0x80u;
    float a = fabsf(x);
    if (!(a < 448.f)) return (unsigned char)(s | 0x7E);
    int e = (int)((v.u >> 23) & 0xFF) - 127;
    if (e < -6) e = -6;
    float q = rintf(ldexpf(a, 3 - e));
    if (q >= 16.f) { q *= 0.5f; e += 1; }
    int qi = (int)q;
    unsigned byte = (qi < 8) ? (unsigned)qi
                             : (((unsigned)(e + 7) << 3) | (unsigned)(qi - 8));
    return (unsigned char)(s | byte);
}
// e4m3fn decode (cold path, 4/thread in ln1)
__device__ __forceinline__ float fp8d(unsigned char b) {
    int e = (b >> 3) & 15, m = b & 7;
    float v = e ? ldexpf((float)(8 + m), e - 10) : ldexpf((float)m, -9);
    return (b & 0x80) ? -v : v;
}

// Pack 4 f32 -> 4 fp8 bytes (HW v_cvt_pk_fp8_f32 when available).
__device__ __forceinline__ unsigned pack4_fp8(float a, float b, float c, float d) {
#if __has_builtin(__builtin_amdgcn_cvt_pk_fp8_f32)
    int r = __builtin_amdgcn_cvt_pk_fp8_f32(a, b, 0, false);
    r = __builtin_amdgcn_cvt_pk_fp8_f32(c, d, r, true);
    return (unsigned)r;
#else
    return (unsigned)f2fp8(a) | ((unsigned)f2fp8(b) << 8)
         | ((unsigned)f2fp8(c) << 16) | ((unsigned)f2fp8(d) << 24);
#endif
}

__device__ __forceinline__ void wg_barrier() {
    asm volatile("" ::: "memory");
    __builtin_amdgcn_s_barrier();
    asm volatile("" ::: "memory");
}

// ---------------- bf16 pipeline (round-7 proven; K-range parametrized) ----------------
__device__ __forceinline__ void stage_tile(
    const unsigned short* __restrict__ src, int R0, int kcol0,
    unsigned short* ldsDst, int w, int lane)
{
    const int rsub = lane >> 3;
    const int csw  = 8 * ((lane & 7) ^ rsub);
    #pragma unroll
    for (int s = 0; s < 4; ++s) {
        const int r = (s*8 + w)*8 + rsub;
        const unsigned short* g = src + (size_t)(R0 + r) * HDIM + kcol0 + csw;
        __builtin_amdgcn_global_load_lds(
            (glob_void*)g, (lds_void*)(ldsDst + (s*8 + w)*512), 16, 0, 0);
    }
}

// K-loop over nt tiles of BK starting at element k0. (0, NT_K) == old behavior.
__device__ __forceinline__ void run_pipeline(
    const unsigned short* __restrict__ srcA,
    const unsigned short* __restrict__ srcB,
    int rowBase, int colBase, int k0, int nt,
    unsigned short* lds, f32x4 (&acc)[8][4])
{
    const int t = threadIdx.x, w = t >> 6, l = t & 63;
    const int wr = w >> 2, wc = w & 3;
    const int lr = l & 15;
    const int sw = (l & 7) << 4;
    const int aRB = (wr*128 + lr) * 128;
    const int bRB = (wc*64  + lr) * 128;
    const int c0 = ((l >> 4) * 16) ^ sw;
    const int c1 = (64 + ((l >> 4) * 16)) ^ sw;

    unsigned short* sA[2] = { lds,            lds + 2*SLOT };
    unsigned short* sB[2] = { lds + SLOT,     lds + 3*SLOT };

    stage_tile(srcA, rowBase, k0,      sA[0], w, l);
    stage_tile(srcB, colBase, k0,      sB[0], w, l);
    stage_tile(srcA, rowBase, k0 + BK, sA[1], w, l);
    stage_tile(srcB, colBase, k0 + BK, sB[1], w, l);
    asm volatile("s_waitcnt vmcnt(8)" ::: "memory");
    wg_barrier();

    for (int kt = 0; kt < nt; ++kt) {
        const char* bufA = (const char*)sA[kt & 1];
        const char* bufB = (const char*)sB[kt & 1];
        #pragma unroll
        for (int kk = 0; kk < 2; ++kk) {
            const int cc = kk ? c1 : c0;
            short8 af[8], bfr[4];
            #pragma unroll
            for (int mi = 0; mi < 8; ++mi)
                af[mi] = *(const short8*)(bufA + aRB + mi*2048 + cc);
            #pragma unroll
            for (int ni = 0; ni < 4; ++ni)
                bfr[ni] = *(const short8*)(bufB + bRB + ni*2048 + cc);
            #pragma unroll
            for (int mi = 0; mi < 8; ++mi)
                #pragma unroll
                for (int ni = 0; ni < 4; ++ni)
                    acc[mi][ni] = __builtin_amdgcn_mfma_f32_16x16x32_bf16(
                        af[mi], bfr[ni], acc[mi][ni], 0, 0, 0);
        }
        if (kt == nt - 1) break;
        wg_barrier();
        if (kt + 2 < nt) {
            stage_tile(srcA, rowBase, k0 + (kt+2)*BK, sA[kt&1], w, l);
            stage_tile(srcB, colBase, k0 + (kt+2)*BK, sB[kt&1], w, l);
            asm volatile("s_waitcnt vmcnt(8)" ::: "memory");
        } else {
            asm volatile("s_waitcnt vmcnt(0)" ::: "memory");
        }
        wg_barrier();
    }
}

// ---------------- fp8 pipeline (rounds 9-12 verified) ----------------
__device__ __forceinline__ void stage_tile8(
    const unsigned char* __restrict__ src, int R0, int kcol0,
    unsigned char* ldsDst, int w, int lane)
{
    const int rsub = lane >> 3;
    const int csw  = ((lane & 7) ^ rsub) << 4;
    #pragma unroll
    for (int s = 0; s < 4; ++s) {
        const int r = (s*8 + w)*8 + rsub;
        __builtin_amdgcn_global_load_lds(
            (glob_void*)(src + (size_t)(R0 + r) * HDIM + kcol0 + csw),
            (lds_void*)(ldsDst + (s*8 + w)*1024), 16, 0, 0);
    }
}

__device__ __forceinline__ void run_pipeline_fp8(
    const unsigned char* __restrict__ srcA,
    const unsigned char* __restrict__ srcB,
    int rowBase, int colBase,
    unsigned char* lds, f32x4 (&acc)[8][4],
    unsigned sa, unsigned sb)
{
    const int t = threadIdx.x, w = t >> 6, l = t & 63;
    const int wr = w >> 2, wc = w & 3;
    const int lr = l & 15;
    const int sw = (l & 7) << 4;
    const int aRB = (wr*128 + lr) * 128;
    const int bRB = (wc*64  + lr) * 128;
    const int g0 = (l >> 4) * 32;
    const int cc0 = g0 ^ sw;
    const int cc1 = (g0 + 16) ^ sw;

    unsigned char* sA[2] = { lds,             lds + 2*SLOT8 };
    unsigned char* sB[2] = { lds + SLOT8,     lds + 3*SLOT8 };

    stage_tile8(srcA, rowBase, 0,   sA[0], w, l);
    stage_tile8(srcB, colBase, 0,   sB[0], w, l);
    stage_tile8(srcA, rowBase, 128, sA[1], w, l);
    stage_tile8(srcB, colBase, 128, sB[1], w, l);
    asm volatile("s_waitcnt vmcnt(8)" ::: "memory");
    wg_barrier();

    for (int kt = 0; kt < NT_K8; ++kt) {
        const char* bufA = (const char*)sA[kt & 1];
        const char* bufB = (const char*)sB[kt & 1];
        int8v b8[4];
        #pragma unroll
        for (int ni = 0; ni < 4; ++ni)
            b8[ni] = __builtin_shufflevector(
                *(const int4v*)(bufB + bRB + ni*2048 + cc0),
                *(const int4v*)(bufB + bRB + ni*2048 + cc1),
                0, 1, 2, 3, 4, 5, 6, 7);
        #pragma unroll
        for (int mi = 0; mi < 8; ++mi) {
            int8v a8 = __builtin_shufflevector(
                *(const int4v*)(bufA + aRB + mi*2048 + cc0),
                *(const int4v*)(bufA + aRB + mi*2048 + cc1),
                0, 1, 2, 3, 4, 5, 6, 7);
            #pragma unroll
            for (int ni = 0; ni < 4; ++ni)
                acc[mi][ni] = __builtin_amdgcn_mfma_scale_f32_16x16x128_f8f6f4(
                    a8, b8[ni], acc[mi][ni], 0, 0, 0, sa, 0, sb);
        }
        if (kt == NT_K8 - 1) break;
        wg_barrier();
        if (kt + 2 < NT_K8) {
            stage_tile8(srcA, rowBase, (kt+2)*128, sA[kt&1], w, l);
            stage_tile8(srcB, colBase, (kt+2)*128, sB[kt&1], w, l);
            asm volatile("s_waitcnt vmcnt(8)" ::: "memory");
        } else {
            asm volatile("s_waitcnt vmcnt(0)" ::: "memory");
        }
        wg_barrier();
    }
}

// ---- bf16 GEMM (FF): C = bf16(alpha * (A @ Bt^T + bias)) ----
__global__ __launch_bounds__(NTHR, 2) void gemm_proj(
    const unsigned short* __restrict__ A,
    const unsigned short* __restrict__ Bt,
    const float* __restrict__ bias,
    unsigned short* __restrict__ C,
    float alpha, int gx)
{
    __shared__ __align__(16) unsigned short lds[4 * SLOT];
    const int nwg = gridDim.x, bid = blockIdx.x;
    const int swz = (bid & 7) * (nwg >> 3) + (bid >> 3);
    const int bx = swz % gx, by = swz / gx;
    const int rowBase = by * BM, colBase = bx * BN;

    f32x4 acc[8][4] = {};
    run_pipeline(A, Bt, rowBase, colBase, 0, NT_K, lds, acc);

    const int t = threadIdx.x, w = t >> 6, l = t & 63;
    const int wr = w >> 2, wc = w & 3;
    const int lr = l & 15;

    #pragma unroll
    for (int ni = 0; ni < 4; ++ni) {
        const int col = colBase + wc*64 + ni*16 + lr;
        const float bv = bias[col];
        #pragma unroll
        for (int mi = 0; mi < 8; ++mi) {
            const int row0 = rowBase + wr*128 + mi*16 + (l >> 4) * 4;
            #pragma unroll
            for (int j = 0; j < 4; ++j)
                C[(size_t)(row0 + j) * HDIM + col] = f2bf(alpha * (acc[mi][ni][j] + bv));
        }
    }
}

// ---- Wqk split-K: 16 tiles x 4 K-slices; slab[kz] gets f32 partials ----
__global__ __launch_bounds__(NTHR, 2) void gemm_wqk_splitk(
    const unsigned short* __restrict__ Wkb,
    const unsigned short* __restrict__ Wqb,
    float* __restrict__ slabs)   // 4 x 1024x1024 f32
{
    __shared__ __align__(16) unsigned short lds[4 * SLOT];
    const int bid = blockIdx.x;      // 64
    const int kz = bid & 3, tile = bid >> 2;
    const int rowBase = (tile >> 2) * BM, colBase = (tile & 3) * BN;

    f32x4 acc[8][4] = {};
    run_pipeline(Wkb, Wqb, rowBase, colBase, kz * (HDIM/4), NT_K/4, lds, acc);

    float* out = slabs + (size_t)kz * HDIM * HDIM;
    const int t = threadIdx.x, w = t >> 6, l = t & 63;
    const int wr = w >> 2, wc = w & 3;
    const int lr = l & 15;

    #pragma unroll
    for (int ni = 0; ni < 4; ++ni) {
        const int col = colBase + wc*64 + ni*16 + lr;
        #pragma unroll
        for (int mi = 0; mi < 8; ++mi) {
            const int row0 = rowBase + wr*128 + mi*16 + (l >> 4) * 4;
            #pragma unroll
            for (int j = 0; j < 4; ++j)
                out[(size_t)(row0 + j) * HDIM + col] = acc[mi][ni][j];
        }
    }
}

// ---- sum 4 slabs, scale x64, write fp8 (4 elems/thread) ----
__global__ __launch_bounds__(256) void wqk_reduce_cast(
    const float* __restrict__ slabs, unsigned char* __restrict__ out8)
{
    const size_t WEl = (size_t)HDIM * HDIM;
    const size_t i = ((size_t)blockIdx.x * 256 + threadIdx.x) * 4;
    float4 a = *reinterpret_cast<const float4*>(slabs + i);
    float4 b = *reinterpret_cast<const float4*>(slabs + WEl + i);
    float4 c = *reinterpret_cast<const float4*>(slabs + 2*WEl + i);
    float4 d = *reinterpret_cast<const float4*>(slabs + 3*WEl + i);
    unsigned wd = pack4_fp8(64.f*(a.x+b.x+c.x+d.x), 64.f*(a.y+b.y+c.y+d.y),
                            64.f*(a.z+b.z+c.z+d.z), 64.f*(a.w+b.w+c.w+d.w));
    *reinterpret_cast<unsigned*>(out8 + i) = wd;
}

// ---- fp8 fused proj: [Xq8 | V8] = fp8( al_mat * (Xb8 @ W8^T + bias_mat) ) ----
__global__ __launch_bounds__(NTHR, 2) void gemm_proj_fp8(
    const unsigned char* __restrict__ A,
    const unsigned char* __restrict__ Bt,
    const float* __restrict__ bias0, const float* __restrict__ bias1,
    unsigned char* __restrict__ C0, unsigned char* __restrict__ C1,
    float al0, float al1, unsigned sb0, unsigned sb1, int gx)
{
    __shared__ __align__(16) unsigned char lds8[4 * SLOT8];
    const int nwg = gridDim.x, bid = blockIdx.x;
    const int swz = (bid & 7) * (nwg >> 3) + (bid >> 3);
    const int bx = swz % gx, by = swz / gx;
    const int rowBase = by * BM, colBase = bx * BN;

    const int mat = colBase >> 10;

    f32x4 acc[8][4] = {};
    run_pipeline_fp8(A, Bt, rowBase, colBase, lds8, acc,
                     0x7F7F7F7Fu, mat ? sb1 : sb0);

    const int t = threadIdx.x, w = t >> 6, l = t & 63;
    const int wr = w >> 2, wc = w & 3;
    const int lr = l & 15;

    unsigned char* Cm  = mat ? C1 : C0;
    const float* bm    = mat ? bias1 : bias0;
    const float am     = mat ? al1 : al0;
    const int lcb = colBase & (HDIM - 1);

    #pragma unroll
    for (int ni = 0; ni < 4; ++ni) {
        const int col = lcb + wc*64 + ni*16 + lr;
        const float bv = bm[col];
        #pragma unroll
        for (int mi = 0; mi < 8; ++mi) {
            const int row0 = rowBase + wr*128 + mi*16 + (l >> 4) * 4;
            const unsigned wd = pack4_fp8(
                am * (acc[mi][ni][0] + bv), am * (acc[mi][ni][1] + bv),
                am * (acc[mi][ni][2] + bv), am * (acc[mi][ni][3] + bv));
            #pragma unroll
            for (int j = 0; j < 4; ++j)
                Cm[(size_t)(row0 + j) * HDIM + col] = (unsigned char)(wd >> (8*j));
        }
    }
}

// ---- fp8 qk, batch-per-XCD grid: bid&7 = batch ----
__global__ __launch_bounds__(NTHR, 2) void qk_colsum_diag_fp8(
    const unsigned char* __restrict__ Xq8,
    const unsigned char* __restrict__ Xb8,
    const float* __restrict__ uvec,
    float* __restrict__ colsum, float* __restrict__ diagv)
{
    __shared__ __align__(16) unsigned char lds8[4 * SLOT8];
    const int bid = blockIdx.x;          // 512
    const int n = bid & 7;
    const int rem = bid >> 3;            // 0..63
    const int rowBase = (rem & 7) * BM;
    const int colBase = (rem >> 3) * BN;
    const unsigned char* An = Xq8 + (size_t)n * LLEN * HDIM;
    const unsigned char* Bn = Xb8 + (size_t)n * LLEN * HDIM;

    f32x4 acc[8][4] = {};
    run_pipeline_fp8(An, Bn, rowBase, colBase, lds8, acc,
                     0x75757575u, 0x7F7F7F7Fu);

    const int t = threadIdx.x, w = t >> 6, l = t & 63;
    const int wr = w >> 2, wc = w & 3;
    const int lr = l & 15;

    float ur[8][4];
    #pragma unroll
    for (int mi = 0; mi < 8; ++mi)
        #pragma unroll
        for (int j = 0; j < 4; ++j)
            ur[mi][j] = uvec[(size_t)n * LLEN + rowBase + wr*128 + mi*16 + (l>>4)*4 + j];

    #pragma unroll
    for (int ni = 0; ni < 4; ++ni) {
        float s = 0.f;
        #pragma unroll
        for (int mi = 0; mi < 8; ++mi)
            #pragma unroll
            for (int j = 0; j < 4; ++j)
                s += __expf(acc[mi][ni][j] + ur[mi][j]);
        s += __shfl_xor(s, 16);
        s += __shfl_xor(s, 32);
        if (l < 16)
            atomicAdd(&colsum[(size_t)n * LLEN + colBase + wc*64 + ni*16 + l], s);
    }

    if (rowBase == colBase && (wc >> 1) == wr) {
        #pragma unroll
        for (int mi = 0; mi < 8; ++mi)
            #pragma unroll
            for (int ni = 0; ni < 4; ++ni)
                #pragma unroll
                for (int j = 0; j < 4; ++j) {
                    const int rr = wr*128 + mi*16 + (l >> 4)*4 + j;
                    const int cc = wc*64 + ni*16 + lr;
                    if (rr == cc)
                        diagv[(size_t)n * LLEN + rowBase + rr] = acc[mi][ni][j];
                }
    }
}

// ---- X f32 -> Xb bf16 + Xb8 fp8, single pass ----
__global__ __launch_bounds__(256) void cast_x_dual(
    const float* __restrict__ in, unsigned short* __restrict__ outb,
    unsigned char* __restrict__ out8, int n8)
{
    int i = blockIdx.x * 256 + threadIdx.x;
    if (i >= n8) return;
    const float4* p = reinterpret_cast<const float4*>(in) + (size_t)i * 2;
    float4 a = p[0], b = p[1];
    short8 o;
    o[0] = (short)f2bf(a.x); o[1] = (short)f2bf(a.y);
    o[2] = (short)f2bf(a.z); o[3] = (short)f2bf(a.w);
    o[4] = (short)f2bf(b.x); o[5] = (short)f2bf(b.y);
    o[6] = (short)f2bf(b.z); o[7] = (short)f2bf(b.w);
    unsigned w0 = pack4_fp8(a.x, a.y, a.z, a.w);
    unsigned w1 = pack4_fp8(b.x, b.y, b.z, b.w);
    *(reinterpret_cast<short8*>(outb) + i) = o;
    uint2 pk; pk.x = w0; pk.y = w1;
    *(reinterpret_cast<uint2*>(out8) + i) = pk;
}

// ---- Wq,Wk f32 -> bf16 (blockIdx.y selects) ----
__global__ __launch_bounds__(256) void cast_w2(
    const float* __restrict__ W0, const float* __restrict__ W1,
    unsigned short* __restrict__ out0, unsigned short* __restrict__ out1, int n8)
{
    int i = blockIdx.x * 256 + threadIdx.x;
    if (i >= n8) return;
    const float* in = blockIdx.y ? W1 : W0;
    unsigned short* outp = blockIdx.y ? out1 : out0;
    const float4* p = reinterpret_cast<const float4*>(in) + (size_t)i * 2;
    float4 a = p[0], b = p[1];
    short8 o;
    o[0] = (short)f2bf(a.x); o[1] = (short)f2bf(a.y);
    o[2] = (short)f2bf(a.z); o[3] = (short)f2bf(a.w);
    o[4] = (short)f2bf(b.x); o[5] = (short)f2bf(b.y);
    o[6] = (short)f2bf(b.z); o[7] = (short)f2bf(b.w);
    *(reinterpret_cast<short8*>(outp) + i) = o;
}

// ---- W (K x N fp32) -> bf16 N x K ----
__global__ __launch_bounds__(256) void transpose_cast_bf16(
    const float* __restrict__ W, unsigned short* __restrict__ Wt)
{
    __shared__ float tile[32][33];
    const int tx = threadIdx.x & 31, ty = threadIdx.x >> 5;
    const int c0 = blockIdx.x * 32, r0 = blockIdx.y * 32;
    #pragma unroll
    for (int r = 0; r < 4; ++r)
        tile[ty + r*8][tx] = W[(size_t)(r0 + ty + r*8) * HDIM + c0 + tx];
    __syncthreads();
    #pragma unroll
    for (int r = 0; r < 4; ++r)
        Wt[(size_t)(c0 + ty + r*8) * HDIM + r0 + tx] = f2bf(tile[tx][ty + r*8]);
}

// ---- W (K x N fp32) -> fp8 N x K, value scaled ----
__global__ __launch_bounds__(256) void transpose_cast_fp8(
    const float* __restrict__ W, unsigned char* __restrict__ Wt, float scale)
{
    __shared__ float tile[32][33];
    const int tx = threadIdx.x & 31, ty = threadIdx.x >> 5;
    const int c0 = blockIdx.x * 32, r0 = blockIdx.y * 32;
    #pragma unroll
    for (int r = 0; r < 4; ++r)
        tile[ty + r*8][tx] = W[(size_t)(r0 + ty + r*8) * HDIM + c0 + tx];
    __syncthreads();
    #pragma unroll
    for (int r = 0; r < 4; ++r)
        Wt[(size_t)(c0 + ty + r*8) * HDIM + r0 + tx] = f2fp8(tile[tx][ty + r*8] * scale);
}

// ---- p[i] = Wq[i,:] . bk ----
__global__ __launch_bounds__(256) void pvec_kernel(
    const float* __restrict__ Wq, const float* __restrict__ bk,
    float* __restrict__ p)
{
    const int row = blockIdx.x * 4 + (threadIdx.x >> 6);
    const int l = threadIdx.x & 63;
    float s = 0.f;
    #pragma unroll
    for (int c = 0; c < HDIM; c += 64)
        s += Wq[(size_t)row * HDIM + c + l] * bk[c + l];
    #pragma unroll
    for (int off = 32; off > 0; off >>= 1) s += __shfl_down(s, off);
    if (l == 0) p[row] = s;
}

// ---- u[a] = sc2 * Xb[a,:] . p ----
__global__ __launch_bounds__(256) void uvec_kernel(
    const unsigned short* __restrict__ Xb, const float* __restrict__ p,
    float* __restrict__ u, float sc2)
{
    const int row = blockIdx.x * 4 + (threadIdx.x >> 6);
    const int l = threadIdx.x & 63;
    const unsigned short* xr = Xb + (size_t)row * HDIM + l * 16;
    float s = 0.f;
    #pragma unroll
    for (int k = 0; k < 2; ++k) {
        short8 v = *reinterpret_cast<const short8*>(xr + k*8);
        #pragma unroll
        for (int j = 0; j < 8; ++j)
            s += bf2f((unsigned short)v[j]) * p[l*16 + k*8 + j];
    }
    #pragma unroll
    for (int off = 32; off > 0; off >>= 1) s += __shfl_down(s, off);
    if (l == 0) u[row] = s * sc2;
}

// ---- h1 = bf16( LN(diag*V8 + Xb) * g1 + b1 ) ----
__global__ __launch_bounds__(256) void ln1_kernel(
    const unsigned char* __restrict__ V8, const unsigned short* __restrict__ Xbp,
    const float* __restrict__ colsum, const float* __restrict__ diagval,
    const float* __restrict__ uvec,
    const float* __restrict__ g1, const float* __restrict__ b1,
    unsigned short* __restrict__ h1)
{
    const int row = blockIdx.x;
    const size_t base = (size_t)row * HDIM;
    const float dv = __expf(diagval[row] + uvec[row]) / colsum[row];
    const int h0 = threadIdx.x * 4;

    unsigned vv = *reinterpret_cast<const unsigned*>(&V8[base + h0]);
    ushort4v xx = *reinterpret_cast<const ushort4v*>(&Xbp[base + h0]);
    float y[4];
    y[0] = dv * fp8d((unsigned char)(vv      )) + bf2f(xx[0]);
    y[1] = dv * fp8d((unsigned char)(vv >>  8)) + bf2f(xx[1]);
    y[2] = dv * fp8d((unsigned char)(vv >> 16)) + bf2f(xx[2]);
    y[3] = dv * fp8d((unsigned char)(vv >> 24)) + bf2f(xx[3]);

    float s = y[0]+y[1]+y[2]+y[3];
    float s2 = y[0]*y[0]+y[1]*y[1]+y[2]*y[2]+y[3]*y[3];
    #pragma unroll
    for (int off = 32; off > 0; off >>= 1) {
        s  += __shfl_down(s,  off);
        s2 += __shfl_down(s2, off);
    }
    __shared__ float ws1[4], ws2[4];
    const int wid = threadIdx.x >> 6;
    if ((threadIdx.x & 63) == 0) { ws1[wid] = s; ws2[wid] = s2; }
    __syncthreads();
    const float S  = ws1[0]+ws1[1]+ws1[2]+ws1[3];
    const float S2 = ws2[0]+ws2[1]+ws2[2]+ws2[3];
    const float m   = S  * (1.0f / HDIM);
    const float var = S2 * (1.0f / HDIM) - m*m;
    const float inv = rsqrtf(var + LNEPS);

    float4 gg = *reinterpret_cast<const float4*>(&g1[h0]);
    float4 bb = *reinterpret_cast<const float4*>(&b1[h0]);
    ushort4v o;
    o[0] = f2bf((y[0]-m)*inv*gg.x + bb.x);
    o[1] = f2bf((y[1]-m)*inv*gg.y + bb.y);
    o[2] = f2bf((y[2]-m)*inv*gg.z + bb.z);
    o[3] = f2bf((y[3]-m)*inv*gg.w + bb.w);
    *reinterpret_cast<ushort4v*>(&h1[base + h0]) = o;
}

// ---- out = fp32( LN(G + h1) * g2 + b2 ) ----
__global__ __launch_bounds__(256) void ln2_kernel(
    const unsigned short* __restrict__ Gb, const unsigned short* __restrict__ h1b,
    const float* __restrict__ g2, const float* __restrict__ b2,
    float* __restrict__ out)
{
    const int row = blockIdx.x;
    const size_t base = (size_t)row * HDIM;
    const int h0 = threadIdx.x * 4;

    ushort4v gv = *reinterpret_cast<const ushort4v*>(&Gb[base + h0]);
    ushort4v hv = *reinterpret_cast<const ushort4v*>(&h1b[base + h0]);
    float y[4];
    y[0] = bf2f(gv[0]) + bf2f(hv[0]); y[1] = bf2f(gv[1]) + bf2f(hv[1]);
    y[2] = bf2f(gv[2]) + bf2f(hv[2]); y[3] = bf2f(gv[3]) + bf2f(hv[3]);

    float s = y[0]+y[1]+y[2]+y[3];
    float s2 = y[0]*y[0]+y[1]*y[1]+y[2]*y[2]+y[3]*y[3];
    #pragma unroll
    for (int off = 32; off > 0; off >>= 1) {
        s  += __shfl_down(s,  off);
        s2 += __shfl_down(s2, off);
    }
    __shared__ float ws1[4], ws2[4];
    const int wid = threadIdx.x >> 6;
    if ((threadIdx.x & 63) == 0) { ws1[wid] = s; ws2[wid] = s2; }
    __syncthreads();
    const float S  = ws1[0]+ws1[1]+ws1[2]+ws1[3];
    const float S2 = ws2[0]+ws2[1]+ws2[2]+ws2[3];
    const float m   = S  * (1.0f / HDIM);
    const float var = S2 * (1.0f / HDIM) - m*m;
    const float inv = rsqrtf(var + LNEPS);

    float4 gg = *reinterpret_cast<const float4*>(&g2[h0]);
    float4 bb = *reinterpret_cast<const float4*>(&b2[h0]);
    float4 o;
    o.x = (y[0]-m)*inv*gg.x + bb.x;
    o.y = (y[1]-m)*inv*gg.y + bb.y;
    o.z = (y[2]-m)*inv*gg.z + bb.z;
    o.w = (y[3]-m)*inv*gg.w + bb.w;
    *reinterpret_cast<float4*>(&out[base + h0]) = o;
}

extern "C" void kernel_launch(void* const* d_in, const int* in_sizes, int n_in,
                              void* d_out, int out_size, void* d_ws, size_t ws_size,
                              hipStream_t stream) {
    (void)in_sizes; (void)n_in; (void)out_size; (void)ws_size;
    const float* X  = (const float*)d_in[0];
    const float* Wq = (const float*)d_in[1];
    const float* bq = (const float*)d_in[2];   (void)bq; // cancels in diag/colsum ratio
    const float* Wk = (const float*)d_in[3];
    const float* bk = (const float*)d_in[4];
    const float* Wv = (const float*)d_in[5];
    const float* bv = (const float*)d_in[6];
    const float* Wf = (const float*)d_in[7];
    const float* bf = (const float*)d_in[8];
    const float* g1 = (const float*)d_in[9];
    const float* b1 = (const float*)d_in[10];
    const float* g2 = (const float*)d_in[11];
    const float* b2 = (const float*)d_in[12];
    float* out = (float*)d_out;

    const size_t MATE = (size_t)NB * LLEN * HDIM;   // 16,777,216 elements
    const size_t WE   = (size_t)HDIM * HDIM;

    // d_out staging: Xb bf16 [0,32MiB), V8 fp8 [32,48MiB). Dead before ln2 writes out.
    unsigned short* Xb  = (unsigned short*)d_out;
    unsigned char*  V8  = (unsigned char*)(Xb + MATE);

    unsigned short* h1b   = (unsigned short*)d_ws;      // 32 MiB
    unsigned short* Gb    = h1b + MATE;                 // 32 MiB
    unsigned short* WfT   = Gb + MATE;                  // 2 MiB
    unsigned short* Wqb   = WfT + WE;                   // 2 MiB
    unsigned short* Wkb   = Wqb + WE;                   // 2 MiB
    unsigned char*  Wqk8T = (unsigned char*)(Wkb + WE); // 1 MiB; [Wqk8T|Wv8T] contiguous
    unsigned char*  Wv8T  = Wqk8T + WE;                 // 1 MiB
    // colsum..zvec: one contiguous memset region (diagv/pv/uv fully overwritten later)
    float* colsum = (float*)(Wv8T + WE);                // 64 KiB
    float* diagv  = colsum + (size_t)NB * LLEN;         // 64 KiB
    float* pv     = diagv + (size_t)NB * LLEN;          // 4 KiB
    float* uv     = pv + HDIM;                          // 64 KiB
    float* zvec   = uv + (size_t)NB * LLEN;             // 4 KiB
    unsigned char* Xq8 = (unsigned char*)(zvec + HDIM); // 16 MiB
    unsigned char* Xb8 = Xq8 + MATE;                    // 16 MiB
    float* wqkSlabs = (float*)(Xb8 + MATE);             // 16 MiB (4 x f32 1024^2)

    const int M = NB * LLEN;            // 16384
    const float sc2 = 1.0f / 1024.0f;   // (1/sqrt(H))^2

    const size_t mset = (3*(size_t)NB*LLEN + 2*HDIM) * sizeof(float);
    hipMemsetAsync(colsum, 0, mset, stream);

    cast_x_dual<<<(int)(MATE/8) / 256, 256, 0, stream>>>(X, Xb, Xb8, (int)(MATE/8));
    {
        dim3 cg((int)(WE/8) / 256, 2);
        cast_w2<<<cg, 256, 0, stream>>>(Wq, Wk, Wqb, Wkb, (int)(WE/8));
    }
    {
        dim3 tgrid(HDIM / 32, HDIM / 32);
        transpose_cast_bf16<<<tgrid, 256, 0, stream>>>(Wf, WfT);
        transpose_cast_fp8<<<tgrid, 256, 0, stream>>>(Wv, Wv8T, 16.0f);   // x2^4
    }

    // Wqk split-K: 64 blocks (16 tiles x 4 K-slices) -> f32 slabs -> x64 fp8.
    // (Replaces the 16-block full-K GEMM: ~45us serial bubble with 240 CUs idle.)
    gemm_wqk_splitk<<<64, NTHR, 0, stream>>>(Wkb, Wqb, wqkSlabs);
    wqk_reduce_cast<<<(int)(WE/4) / 256, 256, 0, stream>>>(wqkSlabs, Wqk8T);

    // u'[a] = sc2 * X[a,:].(Wq @ bk)
    pvec_kernel<<<HDIM / 4, 256, 0, stream>>>(Wq, bk, pv);
    uvec_kernel<<<M / 4, 256, 0, stream>>>(Xb, pv, uv, sc2);

    // fp8 fused proj: [Xq8 | V8] = Xb8 @ [Wqk8T | Wv8T]^T
    // mat0: sb=2^-16 (Wqk x2^16 = x64/sc2), epilogue x1024 -> Xq8 (qk sa=2^-10 undoes)
    // mat1: sb=2^-4  (Wv  x2^4),            epilogue +bv   -> V8
    {
        const int gx = 2 * HDIM / BN;       // 8
        const int nwg = gx * (M / BM);      // 512 (%8==0)
        gemm_proj_fp8<<<nwg, NTHR, 0, stream>>>(Xb8, Wqk8T, zvec, bv,
                                                Xq8, V8, 1024.0f, 1.0f,
                                                0x6F6F6F6Fu /*2^-16*/,
                                                0x7B7B7B7Bu /*2^-4*/, gx);
    }

    // qk: 1D grid, bid&7 = batch -> per-XCD L2 residency of Q/K panels
    qk_colsum_diag_fp8<<<512, NTHR, 0, stream>>>(Xq8, Xb8, uv, colsum, diagv);

    ln1_kernel<<<M, 256, 0, stream>>>(V8, Xb, colsum, diagv, uv, g1, b1, h1b);

    // FF GEMM (bf16; full-scale numerics through LN2)
    {
        const int gx = HDIM / BN;           // 4
        const int nwg = gx * (M / BM);      // 256
        gemm_proj<<<nwg, NTHR, 0, stream>>>(h1b, WfT, bf, Gb, 1.0f, gx);
    }

    ln2_kernel<<<M, 256, 0, stream>>>(Gb, h1b, g2, b2, out);
}

// Round 15
// 228.468 us; speedup vs baseline: 3.7711x; 1.0182x over previous
//
#include <hip/hip_runtime.h>
#include <math.h>

#define NB   8
#define LLEN 2048
#define HDIM 1024
#define LNEPS 1e-5f

#define BM 128               // 128^2 tiles: 64 KiB LDS -> 2 blocks/CU (m97 structure)
#define BK 64                // bf16 K-tile (elems); fp8 K-tile = 128 (bytes)
#define NT_K (HDIM / BK)     // 16 bf16 K-tiles
#define NT_K8 (HDIM / 128)   // 8 fp8 K-tiles
#define NTHR 256             // 4 waves
#define TB 16384             // tile bytes: 128 rows x 128 B (both dtypes)

typedef __attribute__((ext_vector_type(8))) short short8;
typedef __attribute__((ext_vector_type(4))) unsigned short ushort4v;
typedef __attribute__((ext_vector_type(4))) float f32x4;
typedef __attribute__((ext_vector_type(4))) int int4v;
typedef __attribute__((ext_vector_type(8))) int int8v;
typedef __attribute__((ext_vector_type(8))) unsigned char uchar8;

typedef __attribute__((address_space(3))) void lds_void;
typedef const __attribute__((address_space(1))) void glob_void;

__device__ __forceinline__ unsigned short f2bf(float f) {
    union { float f; unsigned u; } v; v.f = f;
    unsigned r = v.u + 0x7FFFu + ((v.u >> 16) & 1u);
    return (unsigned short)(r >> 16);
}
__device__ __forceinline__ float bf2f(unsigned short h) {
    union { unsigned u; float f; } v; v.u = ((unsigned)h) << 16;
    return v.f;
}

// OCP e4m3fn encode, RNE (HW-verified rounds 8-14). Fallback path.
__device__ __forceinline__ unsigned char f2fp8(float x) {
    union { float f; unsigned u; } v; v.f = x;
    unsigned s = (v.u >> 24) & 0x80u;
    float a = fabsf(x);
    if (!(a < 448.f)) return (unsigned char)(s | 0x7E);
    int e = (int)((v.u >> 23) & 0xFF) - 127;
    if (e < -6) e = -6;
    float q = rintf(ldexpf(a, 3 - e));
    if (q >= 16.f) { q *= 0.5f; e += 1; }
    int qi = (int)q;
    unsigned byte = (qi < 8) ? (unsigned)qi
                             : (((unsigned)(e + 7) << 3) | (unsigned)(qi - 8));
    return (unsigned char)(s | byte);
}
// e4m3fn decode (cold path, 4/thread in ln1)
__device__ __forceinline__ float fp8d(unsigned char b) {
    int e = (b >> 3) & 15, m = b & 7;
    float v = e ? ldexpf((float)(8 + m), e - 10) : ldexpf((float)m, -9);
    return (b & 0x80) ? -v : v;
}

// Pack 4 f32 -> 4 fp8 bytes (HW v_cvt_pk_fp8_f32 when available).
__device__ __forceinline__ unsigned pack4_fp8(float a, float b, float c, float d) {
#if __has_builtin(__builtin_amdgcn_cvt_pk_fp8_f32)
    int r = __builtin_amdgcn_cvt_pk_fp8_f32(a, b, 0, false);
    r = __builtin_amdgcn_cvt_pk_fp8_f32(c, d, r, true);
    return (unsigned)r;
#else
    return (unsigned)f2fp8(a) | ((unsigned)f2fp8(b) << 8)
         | ((unsigned)f2fp8(c) << 16) | ((unsigned)f2fp8(d) << 24);
#endif
}

__device__ __forceinline__ void wg_barrier() {
    asm volatile("" ::: "memory");
    __builtin_amdgcn_s_barrier();
    asm volatile("" ::: "memory");
}

// ---------------- 128^2 staging (both dtypes have 128-byte rows) ----------------
// XOR swizzle byte(r,cb) = r*128 + (cb ^ ((r&7)<<4)); swizzle pre-applied to the
// per-lane GLOBAL source (rule 21), LDS dest stays linear. 4 rounds of 32 rows;
// per wave: rows s*32 + w*8 + (l>>3), chunk l&7.
__device__ __forceinline__ void stage128_bf16(
    const unsigned short* __restrict__ src, int R0, int kcol0,
    unsigned short* ldsDst, int w, int l)
{
    const int rsub = l >> 3;
    const int ce = 8 * ((l & 7) ^ rsub);      // element offset (bf16)
    #pragma unroll
    for (int s = 0; s < 4; ++s) {
        const int r = s*32 + w*8 + rsub;
        __builtin_amdgcn_global_load_lds(
            (glob_void*)(src + (size_t)(R0 + r) * HDIM + kcol0 + ce),
            (lds_void*)(ldsDst + s*2048 + w*512), 16, 0, 0);
    }
}

__device__ __forceinline__ void stage128_fp8(
    const unsigned char* __restrict__ src, int R0, int kcol0,
    unsigned char* ldsDst, int w, int l)
{
    const int rsub = l >> 3;
    const int cb = ((l & 7) ^ rsub) << 4;     // byte offset (fp8)
    #pragma unroll
    for (int s = 0; s < 4; ++s) {
        const int r = s*32 + w*8 + rsub;
        __builtin_amdgcn_global_load_lds(
            (glob_void*)(src + (size_t)(R0 + r) * HDIM + kcol0 + cb),
            (lds_void*)(ldsDst + s*4096 + w*1024), 16, 0, 0);
    }
}

// ---- bf16 128^2 pipeline, depth-2, counted vmcnt(8); K-range (k0, nt) ----
__device__ __forceinline__ void pipe128_bf16(
    const unsigned short* __restrict__ srcA,
    const unsigned short* __restrict__ srcB,
    int rowBase, int colBase, int k0, int nt,
    unsigned short* lds, f32x4 (&acc)[4][4])
{
    const int t = threadIdx.x, w = t >> 6, l = t & 63;
    const int wr = w >> 1, wc = w & 1;
    const int lr = l & 15;
    const int sw = (l & 7) << 4;
    const int aRB = (wr*64 + lr) * 128;
    const int bRB = (wc*64 + lr) * 128;
    const int c0 = ((l >> 4) * 16) ^ sw;
    const int c1 = (64 + ((l >> 4) * 16)) ^ sw;

    unsigned short* sA[2] = { lds,          lds + 2*(TB/2) };
    unsigned short* sB[2] = { lds + TB/2,   lds + 3*(TB/2) };

    stage128_bf16(srcA, rowBase, k0,      sA[0], w, l);
    stage128_bf16(srcB, colBase, k0,      sB[0], w, l);
    stage128_bf16(srcA, rowBase, k0 + BK, sA[1], w, l);
    stage128_bf16(srcB, colBase, k0 + BK, sB[1], w, l);
    asm volatile("s_waitcnt vmcnt(8)" ::: "memory");
    wg_barrier();

    for (int kt = 0; kt < nt; ++kt) {
        const char* bufA = (const char*)sA[kt & 1];
        const char* bufB = (const char*)sB[kt & 1];
        #pragma unroll
        for (int kk = 0; kk < 2; ++kk) {
            const int cc = kk ? c1 : c0;
            short8 af[4], bfr[4];
            #pragma unroll
            for (int mi = 0; mi < 4; ++mi)
                af[mi] = *(const short8*)(bufA + aRB + mi*2048 + cc);
            #pragma unroll
            for (int ni = 0; ni < 4; ++ni)
                bfr[ni] = *(const short8*)(bufB + bRB + ni*2048 + cc);
            #pragma unroll
            for (int mi = 0; mi < 4; ++mi)
                #pragma unroll
                for (int ni = 0; ni < 4; ++ni)
                    acc[mi][ni] = __builtin_amdgcn_mfma_f32_16x16x32_bf16(
                        af[mi], bfr[ni], acc[mi][ni], 0, 0, 0);
        }
        if (kt == nt - 1) break;
        wg_barrier();
        if (kt + 2 < nt) {
            stage128_bf16(srcA, rowBase, k0 + (kt+2)*BK, sA[kt&1], w, l);
            stage128_bf16(srcB, colBase, k0 + (kt+2)*BK, sB[kt&1], w, l);
            asm volatile("s_waitcnt vmcnt(8)" ::: "memory");
        } else {
            asm volatile("s_waitcnt vmcnt(0)" ::: "memory");
        }
        wg_barrier();
    }
}

// ---- fp8 128^2 pipeline (shufflevector concat; scale algebra rounds 8-14) ----
__device__ __forceinline__ void pipe128_fp8(
    const unsigned char* __restrict__ srcA,
    const unsigned char* __restrict__ srcB,
    int rowBase, int colBase,
    unsigned char* lds, f32x4 (&acc)[4][4],
    unsigned sa, unsigned sb)
{
    const int t = threadIdx.x, w = t >> 6, l = t & 63;
    const int wr = w >> 1, wc = w & 1;
    const int lr = l & 15;
    const int sw = (l & 7) << 4;
    const int aRB = (wr*64 + lr) * 128;
    const int bRB = (wc*64 + lr) * 128;
    const int g0 = (l >> 4) * 32;
    const int cc0 = g0 ^ sw;
    const int cc1 = (g0 + 16) ^ sw;

    unsigned char* sA[2] = { lds,        lds + 2*TB };
    unsigned char* sB[2] = { lds + TB,   lds + 3*TB };

    stage128_fp8(srcA, rowBase, 0,   sA[0], w, l);
    stage128_fp8(srcB, colBase, 0,   sB[0], w, l);
    stage128_fp8(srcA, rowBase, 128, sA[1], w, l);
    stage128_fp8(srcB, colBase, 128, sB[1], w, l);
    asm volatile("s_waitcnt vmcnt(8)" ::: "memory");
    wg_barrier();

    for (int kt = 0; kt < NT_K8; ++kt) {
        const char* bufA = (const char*)sA[kt & 1];
        const char* bufB = (const char*)sB[kt & 1];
        int8v b8[4];
        #pragma unroll
        for (int ni = 0; ni < 4; ++ni)
            b8[ni] = __builtin_shufflevector(
                *(const int4v*)(bufB + bRB + ni*2048 + cc0),
                *(const int4v*)(bufB + bRB + ni*2048 + cc1),
                0, 1, 2, 3, 4, 5, 6, 7);
        #pragma unroll
        for (int mi = 0; mi < 4; ++mi) {
            int8v a8 = __builtin_shufflevector(
                *(const int4v*)(bufA + aRB + mi*2048 + cc0),
                *(const int4v*)(bufA + aRB + mi*2048 + cc1),
                0, 1, 2, 3, 4, 5, 6, 7);
            #pragma unroll
            for (int ni = 0; ni < 4; ++ni)
                acc[mi][ni] = __builtin_amdgcn_mfma_scale_f32_16x16x128_f8f6f4(
                    a8, b8[ni], acc[mi][ni], 0, 0, 0, sa, 0, sb);
        }
        if (kt == NT_K8 - 1) break;
        wg_barrier();
        if (kt + 2 < NT_K8) {
            stage128_fp8(srcA, rowBase, (kt+2)*128, sA[kt&1], w, l);
            stage128_fp8(srcB, colBase, (kt+2)*128, sB[kt&1], w, l);
            asm volatile("s_waitcnt vmcnt(8)" ::: "memory");
        } else {
            asm volatile("s_waitcnt vmcnt(0)" ::: "memory");
        }
        wg_barrier();
    }
}

// ---- bf16 GEMM (FF): C = bf16(alpha * (A @ Bt^T + bias)); 128^2 ----
__global__ __launch_bounds__(NTHR) void gemm_proj(
    const unsigned short* __restrict__ A,
    const unsigned short* __restrict__ Bt,
    const float* __restrict__ bias,
    unsigned short* __restrict__ C,
    float alpha, int gx)
{
    __shared__ __align__(16) unsigned short lds[2 * TB];   // 64 KiB
    const int nwg = gridDim.x, bid = blockIdx.x;
    const int swz = (bid & 7) * (nwg >> 3) + (bid >> 3);
    const int bx = swz % gx, by = swz / gx;
    const int rowBase = by * BM, colBase = bx * BM;

    f32x4 acc[4][4] = {};
    pipe128_bf16(A, Bt, rowBase, colBase, 0, NT_K, lds, acc);

    const int t = threadIdx.x, w = t >> 6, l = t & 63;
    const int wr = w >> 1, wc = w & 1;
    const int lr = l & 15;

    #pragma unroll
    for (int ni = 0; ni < 4; ++ni) {
        const int col = colBase + wc*64 + ni*16 + lr;
        const float bv = bias[col];
        #pragma unroll
        for (int mi = 0; mi < 4; ++mi) {
            const int row0 = rowBase + wr*64 + mi*16 + (l >> 4) * 4;
            #pragma unroll
            for (int j = 0; j < 4; ++j)
                C[(size_t)(row0 + j) * HDIM + col] = f2bf(alpha * (acc[mi][ni][j] + bv));
        }
    }
}

// ---- Wqk split-K: 64 tiles x 4 K-slices (256 blocks); f32 partial slabs ----
__global__ __launch_bounds__(NTHR) void gemm_wqk_splitk(
    const unsigned short* __restrict__ Wkb,
    const unsigned short* __restrict__ Wqb,
    float* __restrict__ slabs)   // 4 x 1024x1024 f32
{
    __shared__ __align__(16) unsigned short lds[2 * TB];
    const int bid = blockIdx.x;      // 256
    const int kz = bid & 3, tile = bid >> 2;
    const int rowBase = (tile >> 3) * BM, colBase = (tile & 7) * BM;

    f32x4 acc[4][4] = {};
    pipe128_bf16(Wkb, Wqb, rowBase, colBase, kz * (HDIM/4), NT_K/4, lds, acc);

    float* out = slabs + (size_t)kz * HDIM * HDIM;
    const int t = threadIdx.x, w = t >> 6, l = t & 63;
    const int wr = w >> 1, wc = w & 1;
    const int lr = l & 15;

    #pragma unroll
    for (int ni = 0; ni < 4; ++ni) {
        const int col = colBase + wc*64 + ni*16 + lr;
        #pragma unroll
        for (int mi = 0; mi < 4; ++mi) {
            const int row0 = rowBase + wr*64 + mi*16 + (l >> 4) * 4;
            #pragma unroll
            for (int j = 0; j < 4; ++j)
                out[(size_t)(row0 + j) * HDIM + col] = acc[mi][ni][j];
        }
    }
}

// ---- sum 4 slabs, scale x64, write fp8 ----
__global__ __launch_bounds__(256) void wqk_reduce_cast(
    const float* __restrict__ slabs, unsigned char* __restrict__ out8)
{
    const size_t WEl = (size_t)HDIM * HDIM;
    const size_t i = ((size_t)blockIdx.x * 256 + threadIdx.x) * 4;
    float4 a = *reinterpret_cast<const float4*>(slabs + i);
    float4 b = *reinterpret_cast<const float4*>(slabs + WEl + i);
    float4 c = *reinterpret_cast<const float4*>(slabs + 2*WEl + i);
    float4 d = *reinterpret_cast<const float4*>(slabs + 3*WEl + i);
    unsigned wd = pack4_fp8(64.f*(a.x+b.x+c.x+d.x), 64.f*(a.y+b.y+c.y+d.y),
                            64.f*(a.z+b.z+c.z+d.z), 64.f*(a.w+b.w+c.w+d.w));
    *reinterpret_cast<unsigned*>(out8 + i) = wd;
}

// ---- fp8 fused proj: [Xq8 | V8] = fp8( al_mat * (Xb8 @ W8^T + bias_mat) ); 128^2 ----
__global__ __launch_bounds__(NTHR) void gemm_proj_fp8(
    const unsigned char* __restrict__ A,
    const unsigned char* __restrict__ Bt,
    const float* __restrict__ bias0, const float* __restrict__ bias1,
    unsigned char* __restrict__ C0, unsigned char* __restrict__ C1,
    float al0, float al1, unsigned sb0, unsigned sb1, int gx)
{
    __shared__ __align__(16) unsigned char lds8[4 * TB];   // 64 KiB
    const int nwg = gridDim.x, bid = blockIdx.x;
    const int swz = (bid & 7) * (nwg >> 3) + (bid >> 3);
    const int bx = swz % gx, by = swz / gx;
    const int rowBase = by * BM, colBase = bx * BM;

    const int mat = colBase >> 10;

    f32x4 acc[4][4] = {};
    pipe128_fp8(A, Bt, rowBase, colBase, lds8, acc,
                0x7F7F7F7Fu, mat ? sb1 : sb0);

    const int t = threadIdx.x, w = t >> 6, l = t & 63;
    const int wr = w >> 1, wc = w & 1;
    const int lr = l & 15;

    unsigned char* Cm  = mat ? C1 : C0;
    const float* bm    = mat ? bias1 : bias0;
    const float am     = mat ? al1 : al0;
    const int lcb = colBase & (HDIM - 1);

    #pragma unroll
    for (int ni = 0; ni < 4; ++ni) {
        const int col = lcb + wc*64 + ni*16 + lr;
        const float bv = bm[col];
        #pragma unroll
        for (int mi = 0; mi < 4; ++mi) {
            const int row0 = rowBase + wr*64 + mi*16 + (l >> 4) * 4;
            const unsigned wd = pack4_fp8(
                am * (acc[mi][ni][0] + bv), am * (acc[mi][ni][1] + bv),
                am * (acc[mi][ni][2] + bv), am * (acc[mi][ni][3] + bv));
            #pragma unroll
            for (int j = 0; j < 4; ++j)
                Cm[(size_t)(row0 + j) * HDIM + col] = (unsigned char)(wd >> (8*j));
        }
    }
}

// ---- fp8 qk, 128^2, batch-per-XCD grid: bid&7 = batch ----
__global__ __launch_bounds__(NTHR) void qk_colsum_diag_fp8(
    const unsigned char* __restrict__ Xq8,
    const unsigned char* __restrict__ Xb8,
    const float* __restrict__ uvec,
    float* __restrict__ colsum, float* __restrict__ diagv)
{
    __shared__ __align__(16) unsigned char lds8[4 * TB];
    const int bid = blockIdx.x;          // 2048
    const int n = bid & 7;
    const int rem = bid >> 3;            // 0..255
    const int rowBase = (rem & 15) * BM;
    const int colBase = (rem >> 4) * BM;
    const unsigned char* An = Xq8 + (size_t)n * LLEN * HDIM;
    const unsigned char* Bn = Xb8 + (size_t)n * LLEN * HDIM;

    f32x4 acc[4][4] = {};
    pipe128_fp8(An, Bn, rowBase, colBase, lds8, acc,
                0x75757575u, 0x7F7F7F7Fu);

    const int t = threadIdx.x, w = t >> 6, l = t & 63;
    const int wr = w >> 1, wc = w & 1;
    const int lr = l & 15;

    float ur[4][4];
    #pragma unroll
    for (int mi = 0; mi < 4; ++mi)
        #pragma unroll
        for (int j = 0; j < 4; ++j)
            ur[mi][j] = uvec[(size_t)n * LLEN + rowBase + wr*64 + mi*16 + (l>>4)*4 + j];

    #pragma unroll
    for (int ni = 0; ni < 4; ++ni) {
        float s = 0.f;
        #pragma unroll
        for (int mi = 0; mi < 4; ++mi)
            #pragma unroll
            for (int j = 0; j < 4; ++j)
                s += __expf(acc[mi][ni][j] + ur[mi][j]);
        s += __shfl_xor(s, 16);
        s += __shfl_xor(s, 32);
        if (l < 16)
            atomicAdd(&colsum[(size_t)n * LLEN + colBase + wc*64 + ni*16 + l], s);
    }

    if (rowBase == colBase && wr == wc) {
        #pragma unroll
        for (int mi = 0; mi < 4; ++mi)
            #pragma unroll
            for (int ni = 0; ni < 4; ++ni)
                #pragma unroll
                for (int j = 0; j < 4; ++j) {
                    const int rr = wr*64 + mi*16 + (l >> 4)*4 + j;
                    const int cc = wc*64 + ni*16 + lr;
                    if (rr == cc)
                        diagv[(size_t)n * LLEN + rowBase + rr] = acc[mi][ni][j];
                }
    }
}

// ---- X f32 -> Xb bf16 + Xb8 fp8, single pass ----
__global__ __launch_bounds__(256) void cast_x_dual(
    const float* __restrict__ in, unsigned short* __restrict__ outb,
    unsigned char* __restrict__ out8, int n8)
{
    int i = blockIdx.x * 256 + threadIdx.x;
    if (i >= n8) return;
    const float4* p = reinterpret_cast<const float4*>(in) + (size_t)i * 2;
    float4 a = p[0], b = p[1];
    short8 o;
    o[0] = (short)f2bf(a.x); o[1] = (short)f2bf(a.y);
    o[2] = (short)f2bf(a.z); o[3] = (short)f2bf(a.w);
    o[4] = (short)f2bf(b.x); o[5] = (short)f2bf(b.y);
    o[6] = (short)f2bf(b.z); o[7] = (short)f2bf(b.w);
    unsigned w0 = pack4_fp8(a.x, a.y, a.z, a.w);
    unsigned w1 = pack4_fp8(b.x, b.y, b.z, b.w);
    *(reinterpret_cast<short8*>(outb) + i) = o;
    uint2 pk; pk.x = w0; pk.y = w1;
    *(reinterpret_cast<uint2*>(out8) + i) = pk;
}

// ---- Wq,Wk f32 -> bf16 (blockIdx.y selects) ----
__global__ __launch_bounds__(256) void cast_w2(
    const float* __restrict__ W0, const float* __restrict__ W1,
    unsigned short* __restrict__ out0, unsigned short* __restrict__ out1, int n8)
{
    int i = blockIdx.x * 256 + threadIdx.x;
    if (i >= n8) return;
    const float* in = blockIdx.y ? W1 : W0;
    unsigned short* outp = blockIdx.y ? out1 : out0;
    const float4* p = reinterpret_cast<const float4*>(in) + (size_t)i * 2;
    float4 a = p[0], b = p[1];
    short8 o;
    o[0] = (short)f2bf(a.x); o[1] = (short)f2bf(a.y);
    o[2] = (short)f2bf(a.z); o[3] = (short)f2bf(a.w);
    o[4] = (short)f2bf(b.x); o[5] = (short)f2bf(b.y);
    o[6] = (short)f2bf(b.z); o[7] = (short)f2bf(b.w);
    *(reinterpret_cast<short8*>(outp) + i) = o;
}

// ---- W (K x N fp32) -> bf16 N x K ----
__global__ __launch_bounds__(256) void transpose_cast_bf16(
    const float* __restrict__ W, unsigned short* __restrict__ Wt)
{
    __shared__ float tile[32][33];
    const int tx = threadIdx.x & 31, ty = threadIdx.x >> 5;
    const int c0 = blockIdx.x * 32, r0 = blockIdx.y * 32;
    #pragma unroll
    for (int r = 0; r < 4; ++r)
        tile[ty + r*8][tx] = W[(size_t)(r0 + ty + r*8) * HDIM + c0 + tx];
    __syncthreads();
    #pragma unroll
    for (int r = 0; r < 4; ++r)
        Wt[(size_t)(c0 + ty + r*8) * HDIM + r0 + tx] = f2bf(tile[tx][ty + r*8]);
}

// ---- W (K x N fp32) -> fp8 N x K, value scaled ----
__global__ __launch_bounds__(256) void transpose_cast_fp8(
    const float* __restrict__ W, unsigned char* __restrict__ Wt, float scale)
{
    __shared__ float tile[32][33];
    const int tx = threadIdx.x & 31, ty = threadIdx.x >> 5;
    const int c0 = blockIdx.x * 32, r0 = blockIdx.y * 32;
    #pragma unroll
    for (int r = 0; r < 4; ++r)
        tile[ty + r*8][tx] = W[(size_t)(r0 + ty + r*8) * HDIM + c0 + tx];
    __syncthreads();
    #pragma unroll
    for (int r = 0; r < 4; ++r)
        Wt[(size_t)(c0 + ty + r*8) * HDIM + r0 + tx] = f2fp8(tile[tx][ty + r*8] * scale);
}

// ---- p[i] = Wq[i,:] . bk ----
__global__ __launch_bounds__(256) void pvec_kernel(
    const float* __restrict__ Wq, const float* __restrict__ bk,
    float* __restrict__ p)
{
    const int row = blockIdx.x * 4 + (threadIdx.x >> 6);
    const int l = threadIdx.x & 63;
    float s = 0.f;
    #pragma unroll
    for (int c = 0; c < HDIM; c += 64)
        s += Wq[(size_t)row * HDIM + c + l] * bk[c + l];
    #pragma unroll
    for (int off = 32; off > 0; off >>= 1) s += __shfl_down(s, off);
    if (l == 0) p[row] = s;
}

// ---- u[a] = sc2 * Xb[a,:] . p ----
__global__ __launch_bounds__(256) void uvec_kernel(
    const unsigned short* __restrict__ Xb, const float* __restrict__ p,
    float* __restrict__ u, float sc2)
{
    const int row = blockIdx.x * 4 + (threadIdx.x >> 6);
    const int l = threadIdx.x & 63;
    const unsigned short* xr = Xb + (size_t)row * HDIM + l * 16;
    float s = 0.f;
    #pragma unroll
    for (int k = 0; k < 2; ++k) {
        short8 v = *reinterpret_cast<const short8*>(xr + k*8);
        #pragma unroll
        for (int j = 0; j < 8; ++j)
            s += bf2f((unsigned short)v[j]) * p[l*16 + k*8 + j];
    }
    #pragma unroll
    for (int off = 32; off > 0; off >>= 1) s += __shfl_down(s, off);
    if (l == 0) u[row] = s * sc2;
}

// ---- h1 = bf16( LN(diag*V8 + Xb) * g1 + b1 ) ----
__global__ __launch_bounds__(256) void ln1_kernel(
    const unsigned char* __restrict__ V8, const unsigned short* __restrict__ Xbp,
    const float* __restrict__ colsum, const float* __restrict__ diagval,
    const float* __restrict__ uvec,
    const float* __restrict__ g1, const float* __restrict__ b1,
    unsigned short* __restrict__ h1)
{
    const int row = blockIdx.x;
    const size_t base = (size_t)row * HDIM;
    const float dv = __expf(diagval[row] + uvec[row]) / colsum[row];
    const int h0 = threadIdx.x * 4;

    unsigned vv = *reinterpret_cast<const unsigned*>(&V8[base + h0]);
    ushort4v xx = *reinterpret_cast<const ushort4v*>(&Xbp[base + h0]);
    float y[4];
    y[0] = dv * fp8d((unsigned char)(vv      )) + bf2f(xx[0]);
    y[1] = dv * fp8d((unsigned char)(vv >>  8)) + bf2f(xx[1]);
    y[2] = dv * fp8d((unsigned char)(vv >> 16)) + bf2f(xx[2]);
    y[3] = dv * fp8d((unsigned char)(vv >> 24)) + bf2f(xx[3]);

    float s = y[0]+y[1]+y[2]+y[3];
    float s2 = y[0]*y[0]+y[1]*y[1]+y[2]*y[2]+y[3]*y[3];
    #pragma unroll
    for (int off = 32; off > 0; off >>= 1) {
        s  += __shfl_down(s,  off);
        s2 += __shfl_down(s2, off);
    }
    __shared__ float ws1[4], ws2[4];
    const int wid = threadIdx.x >> 6;
    if ((threadIdx.x & 63) == 0) { ws1[wid] = s; ws2[wid] = s2; }
    __syncthreads();
    const float S  = ws1[0]+ws1[1]+ws1[2]+ws1[3];
    const float S2 = ws2[0]+ws2[1]+ws2[2]+ws2[3];
    const float m   = S  * (1.0f / HDIM);
    const float var = S2 * (1.0f / HDIM) - m*m;
    const float inv = rsqrtf(var + LNEPS);

    float4 gg = *reinterpret_cast<const float4*>(&g1[h0]);
    float4 bb = *reinterpret_cast<const float4*>(&b1[h0]);
    ushort4v o;
    o[0] = f2bf((y[0]-m)*inv*gg.x + bb.x);
    o[1] = f2bf((y[1]-m)*inv*gg.y + bb.y);
    o[2] = f2bf((y[2]-m)*inv*gg.z + bb.z);
    o[3] = f2bf((y[3]-m)*inv*gg.w + bb.w);
    *reinterpret_cast<ushort4v*>(&h1[base + h0]) = o;
}

// ---- out = fp32( LN(G + h1) * g2 + b2 ) ----
__global__ __launch_bounds__(256) void ln2_kernel(
    const unsigned short* __restrict__ Gb, const unsigned short* __restrict__ h1b,
    const float* __restrict__ g2, const float* __restrict__ b2,
    float* __restrict__ out)
{
    const int row = blockIdx.x;
    const size_t base = (size_t)row * HDIM;
    const int h0 = threadIdx.x * 4;

    ushort4v gv = *reinterpret_cast<const ushort4v*>(&Gb[base + h0]);
    ushort4v hv = *reinterpret_cast<const ushort4v*>(&h1b[base + h0]);
    float y[4];
    y[0] = bf2f(gv[0]) + bf2f(hv[0]); y[1] = bf2f(gv[1]) + bf2f(hv[1]);
    y[2] = bf2f(gv[2]) + bf2f(hv[2]); y[3] = bf2f(gv[3]) + bf2f(hv[3]);

    float s = y[0]+y[1]+y[2]+y[3];
    float s2 = y[0]*y[0]+y[1]*y[1]+y[2]*y[2]+y[3]*y[3];
    #pragma unroll
    for (int off = 32; off > 0; off >>= 1) {
        s  += __shfl_down(s,  off);
        s2 += __shfl_down(s2, off);
    }
    __shared__ float ws1[4], ws2[4];
    const int wid = threadIdx.x >> 6;
    if ((threadIdx.x & 63) == 0) { ws1[wid] = s; ws2[wid] = s2; }
    __syncthreads();
    const float S  = ws1[0]+ws1[1]+ws1[2]+ws1[3];
    const float S2 = ws2[0]+ws2[1]+ws2[2]+ws2[3];
    const float m   = S  * (1.0f / HDIM);
    const float var = S2 * (1.0f / HDIM) - m*m;
    const float inv = rsqrtf(var + LNEPS);

    float4 gg = *reinterpret_cast<const float4*>(&g2[h0]);
    float4 bb = *reinterpret_cast<const float4*>(&b2[h0]);
    float4 o;
    o.x = (y[0]-m)*inv*gg.x + bb.x;
    o.y = (y[1]-m)*inv*gg.y + bb.y;
    o.z = (y[2]-m)*inv*gg.z + bb.z;
    o.w = (y[3]-m)*inv*gg.w + bb.w;
    *reinterpret_cast<float4*>(&out[base + h0]) = o;
}

extern "C" void kernel_launch(void* const* d_in, const int* in_sizes, int n_in,
                              void* d_out, int out_size, void* d_ws, size_t ws_size,
                              hipStream_t stream) {
    (void)in_sizes; (void)n_in; (void)out_size; (void)ws_size;
    const float* X  = (const float*)d_in[0];
    const float* Wq = (const float*)d_in[1];
    const float* bq = (const float*)d_in[2];   (void)bq; // cancels in diag/colsum ratio
    const float* Wk = (const float*)d_in[3];
    const float* bk = (const float*)d_in[4];
    const float* Wv = (const float*)d_in[5];
    const float* bv = (const float*)d_in[6];
    const float* Wf = (const float*)d_in[7];
    const float* bf = (const float*)d_in[8];
    const float* g1 = (const float*)d_in[9];
    const float* b1 = (const float*)d_in[10];
    const float* g2 = (const float*)d_in[11];
    const float* b2 = (const float*)d_in[12];
    float* out = (float*)d_out;

    const size_t MATE = (size_t)NB * LLEN * HDIM;   // 16,777,216 elements
    const size_t WE   = (size_t)HDIM * HDIM;

    // d_out staging: Xb bf16 [0,32MiB), V8 fp8 [32,48MiB). Dead before ln2 writes out.
    unsigned short* Xb  = (unsigned short*)d_out;
    unsigned char*  V8  = (unsigned char*)(Xb + MATE);

    unsigned short* h1b   = (unsigned short*)d_ws;      // 32 MiB
    unsigned short* Gb    = h1b + MATE;                 // 32 MiB
    unsigned short* WfT   = Gb + MATE;                  // 2 MiB
    unsigned short* Wqb   = WfT + WE;                   // 2 MiB
    unsigned short* Wkb   = Wqb + WE;                   // 2 MiB
    unsigned char*  Wqk8T = (unsigned char*)(Wkb + WE); // 1 MiB; [Wqk8T|Wv8T] contiguous
    unsigned char*  Wv8T  = Wqk8T + WE;                 // 1 MiB
    // colsum..zvec: one contiguous memset region (diagv/pv/uv fully overwritten later)
    float* colsum = (float*)(Wv8T + WE);                // 64 KiB
    float* diagv  = colsum + (size_t)NB * LLEN;         // 64 KiB
    float* pv     = diagv + (size_t)NB * LLEN;          // 4 KiB
    float* uv     = pv + HDIM;                          // 64 KiB
    float* zvec   = uv + (size_t)NB * LLEN;             // 4 KiB
    unsigned char* Xq8 = (unsigned char*)(zvec + HDIM); // 16 MiB
    unsigned char* Xb8 = Xq8 + MATE;                    // 16 MiB
    float* wqkSlabs = (float*)(Xb8 + MATE);             // 16 MiB (4 x f32 1024^2)

    const int M = NB * LLEN;            // 16384
    const float sc2 = 1.0f / 1024.0f;   // (1/sqrt(H))^2

    const size_t mset = (3*(size_t)NB*LLEN + 2*HDIM) * sizeof(float);
    hipMemsetAsync(colsum, 0, mset, stream);

    cast_x_dual<<<(int)(MATE/8) / 256, 256, 0, stream>>>(X, Xb, Xb8, (int)(MATE/8));
    {
        dim3 cg((int)(WE/8) / 256, 2);
        cast_w2<<<cg, 256, 0, stream>>>(Wq, Wk, Wqb, Wkb, (int)(WE/8));
    }
    {
        dim3 tgrid(HDIM / 32, HDIM / 32);
        transpose_cast_bf16<<<tgrid, 256, 0, stream>>>(Wf, WfT);
        transpose_cast_fp8<<<tgrid, 256, 0, stream>>>(Wv, Wv8T, 16.0f);   // x2^4
    }

    // Wqk split-K: 256 blocks (64 tiles x 4 K-slices) -> f32 slabs -> x64 fp8
    gemm_wqk_splitk<<<256, NTHR, 0, stream>>>(Wkb, Wqb, wqkSlabs);
    wqk_reduce_cast<<<(int)(WE/4) / 256, 256, 0, stream>>>(wqkSlabs, Wqk8T);

    // u'[a] = sc2 * X[a,:].(Wq @ bk)
    pvec_kernel<<<HDIM / 4, 256, 0, stream>>>(Wq, bk, pv);
    uvec_kernel<<<M / 4, 256, 0, stream>>>(Xb, pv, uv, sc2);

    // fp8 fused proj: [Xq8 | V8] = Xb8 @ [Wqk8T | Wv8T]^T  (128^2 tiles)
    // mat0: sb=2^-16 (Wqk x2^16 = x64/sc2), epilogue x1024 -> Xq8 (qk sa=2^-10 undoes)
    // mat1: sb=2^-4  (Wv  x2^4),            epilogue +bv   -> V8
    {
        const int gx = 2 * HDIM / BM;       // 16
        const int nwg = gx * (M / BM);      // 2048 (%8==0)
        gemm_proj_fp8<<<nwg, NTHR, 0, stream>>>(Xb8, Wqk8T, zvec, bv,
                                                Xq8, V8, 1024.0f, 1.0f,
                                                0x6F6F6F6Fu /*2^-16*/,
                                                0x7B7B7B7Bu /*2^-4*/, gx);
    }

    // qk: 1D grid 2048, bid&7 = batch -> per-XCD L2 residency of Q/K panels
    qk_colsum_diag_fp8<<<2048, NTHR, 0, stream>>>(Xq8, Xb8, uv, colsum, diagv);

    ln1_kernel<<<M, 256, 0, stream>>>(V8, Xb, colsum, diagv, uv, g1, b1, h1b);

    // FF GEMM (bf16, 128^2)
    {
        const int gx = HDIM / BM;           // 8
        const int nwg = gx * (M / BM);      // 1024
        gemm_proj<<<nwg, NTHR, 0, stream>>>(h1b, WfT, bf, Gb, 1.0f, gx);
    }

    ln2_kernel<<<M, 256, 0, stream>>>(Gb, h1b, g2, b2, out);
}

// Round 16
// 209.706 us; speedup vs baseline: 4.1085x; 1.0895x over previous
//
#include <hip/hip_runtime.h>
#include <math.h>

#define NB   8
#define LLEN 2048
#define HDIM 1024
#define LNEPS 1e-5f

#define BM 128               // 128^2 tiles for fp8 kernels (2 blocks/CU)
#define BK 64                // bf16 K-tile (elems); fp8 K-tile = 128 (bytes)
#define NT_K (HDIM / BK)     // 16 bf16 K-tiles
#define NT_K8 (HDIM / 128)   // 8 fp8 K-tiles
#define NTHR 256             // 4 waves (128^2 kernels)
#define TB 16384             // 128^2 tile bytes: 128 rows x 128 B

#define BM2 256              // 256^2 tile for bf16 FF (1 block/CU, 8 waves)
#define NTHR2 512
#define SLOT2 (BM2 * BK)     // 16384 shorts = 32 KiB per 256^2 operand slot

typedef __attribute__((ext_vector_type(8))) short short8;
typedef __attribute__((ext_vector_type(4))) unsigned short ushort4v;
typedef __attribute__((ext_vector_type(4))) float f32x4;
typedef __attribute__((ext_vector_type(4))) int int4v;
typedef __attribute__((ext_vector_type(8))) int int8v;
typedef __attribute__((ext_vector_type(8))) unsigned char uchar8;

typedef __attribute__((address_space(3))) void lds_void;
typedef const __attribute__((address_space(1))) void glob_void;

__device__ __forceinline__ unsigned short f2bf(float f) {
    union { float f; unsigned u; } v; v.f = f;
    unsigned r = v.u + 0x7FFFu + ((v.u >> 16) & 1u);
    return (unsigned short)(r >> 16);
}
__device__ __forceinline__ float bf2f(unsigned short h) {
    union { unsigned u; float f; } v; v.u = ((unsigned)h) << 16;
    return v.f;
}

// OCP e4m3fn encode, RNE (HW-verified rounds 8-15). Fallback path.
__device__ __forceinline__ unsigned char f2fp8(float x) {
    union { float f; unsigned u; } v; v.f = x;
    unsigned s = (v.u >> 24) & 0x80u;
    float a = fabsf(x);
    if (!(a < 448.f)) return (unsigned char)(s | 0x7E);
    int e = (int)((v.u >> 23) & 0xFF) - 127;
    if (e < -6) e = -6;
    float q = rintf(ldexpf(a, 3 - e));
    if (q >= 16.f) { q *= 0.5f; e += 1; }
    int qi = (int)q;
    unsigned byte = (qi < 8) ? (unsigned)qi
                             : (((unsigned)(e + 7) << 3) | (unsigned)(qi - 8));
    return (unsigned char)(s | byte);
}
// e4m3fn decode (cold path, 4/thread in ln1)
__device__ __forceinline__ float fp8d(unsigned char b) {
    int e = (b >> 3) & 15, m = b & 7;
    float v = e ? ldexpf((float)(8 + m), e - 10) : ldexpf((float)m, -9);
    return (b & 0x80) ? -v : v;
}

// Pack 4 f32 -> 4 fp8 bytes (HW v_cvt_pk_fp8_f32 when available).
__device__ __forceinline__ unsigned pack4_fp8(float a, float b, float c, float d) {
#if __has_builtin(__builtin_amdgcn_cvt_pk_fp8_f32)
    int r = __builtin_amdgcn_cvt_pk_fp8_f32(a, b, 0, false);
    r = __builtin_amdgcn_cvt_pk_fp8_f32(c, d, r, true);
    return (unsigned)r;
#else
    return (unsigned)f2fp8(a) | ((unsigned)f2fp8(b) << 8)
         | ((unsigned)f2fp8(c) << 16) | ((unsigned)f2fp8(d) << 24);
#endif
}

__device__ __forceinline__ void wg_barrier() {
    asm volatile("" ::: "memory");
    __builtin_amdgcn_s_barrier();
    asm volatile("" ::: "memory");
}

// ================= 128^2 pipelines (fp8 qk/proj + wqk splitk) =================
// XOR swizzle byte(r,cb) = r*128 + (cb ^ ((r&7)<<4)); pre-applied to the
// per-lane GLOBAL source (rule 21), LDS dest linear.
__device__ __forceinline__ void stage128_bf16(
    const unsigned short* __restrict__ src, int R0, int kcol0,
    unsigned short* ldsDst, int w, int l)
{
    const int rsub = l >> 3;
    const int ce = 8 * ((l & 7) ^ rsub);
    #pragma unroll
    for (int s = 0; s < 4; ++s) {
        const int r = s*32 + w*8 + rsub;
        __builtin_amdgcn_global_load_lds(
            (glob_void*)(src + (size_t)(R0 + r) * HDIM + kcol0 + ce),
            (lds_void*)(ldsDst + s*2048 + w*512), 16, 0, 0);
    }
}

__device__ __forceinline__ void stage128_fp8(
    const unsigned char* __restrict__ src, int R0, int kcol0,
    unsigned char* ldsDst, int w, int l)
{
    const int rsub = l >> 3;
    const int cb = ((l & 7) ^ rsub) << 4;
    #pragma unroll
    for (int s = 0; s < 4; ++s) {
        const int r = s*32 + w*8 + rsub;
        __builtin_amdgcn_global_load_lds(
            (glob_void*)(src + (size_t)(R0 + r) * HDIM + kcol0 + cb),
            (lds_void*)(ldsDst + s*4096 + w*1024), 16, 0, 0);
    }
}

__device__ __forceinline__ void pipe128_bf16(
    const unsigned short* __restrict__ srcA,
    const unsigned short* __restrict__ srcB,
    int rowBase, int colBase, int k0, int nt,
    unsigned short* lds, f32x4 (&acc)[4][4])
{
    const int t = threadIdx.x, w = t >> 6, l = t & 63;
    const int wr = w >> 1, wc = w & 1;
    const int lr = l & 15;
    const int sw = (l & 7) << 4;
    const int aRB = (wr*64 + lr) * 128;
    const int bRB = (wc*64 + lr) * 128;
    const int c0 = ((l >> 4) * 16) ^ sw;
    const int c1 = (64 + ((l >> 4) * 16)) ^ sw;

    unsigned short* sA[2] = { lds,          lds + 2*(TB/2) };
    unsigned short* sB[2] = { lds + TB/2,   lds + 3*(TB/2) };

    stage128_bf16(srcA, rowBase, k0,      sA[0], w, l);
    stage128_bf16(srcB, colBase, k0,      sB[0], w, l);
    stage128_bf16(srcA, rowBase, k0 + BK, sA[1], w, l);
    stage128_bf16(srcB, colBase, k0 + BK, sB[1], w, l);
    asm volatile("s_waitcnt vmcnt(8)" ::: "memory");
    wg_barrier();

    for (int kt = 0; kt < nt; ++kt) {
        const char* bufA = (const char*)sA[kt & 1];
        const char* bufB = (const char*)sB[kt & 1];
        #pragma unroll
        for (int kk = 0; kk < 2; ++kk) {
            const int cc = kk ? c1 : c0;
            short8 af[4], bfr[4];
            #pragma unroll
            for (int mi = 0; mi < 4; ++mi)
                af[mi] = *(const short8*)(bufA + aRB + mi*2048 + cc);
            #pragma unroll
            for (int ni = 0; ni < 4; ++ni)
                bfr[ni] = *(const short8*)(bufB + bRB + ni*2048 + cc);
            #pragma unroll
            for (int mi = 0; mi < 4; ++mi)
                #pragma unroll
                for (int ni = 0; ni < 4; ++ni)
                    acc[mi][ni] = __builtin_amdgcn_mfma_f32_16x16x32_bf16(
                        af[mi], bfr[ni], acc[mi][ni], 0, 0, 0);
        }
        if (kt == nt - 1) break;
        wg_barrier();
        if (kt + 2 < nt) {
            stage128_bf16(srcA, rowBase, k0 + (kt+2)*BK, sA[kt&1], w, l);
            stage128_bf16(srcB, colBase, k0 + (kt+2)*BK, sB[kt&1], w, l);
            asm volatile("s_waitcnt vmcnt(8)" ::: "memory");
        } else {
            asm volatile("s_waitcnt vmcnt(0)" ::: "memory");
        }
        wg_barrier();
    }
}

__device__ __forceinline__ void pipe128_fp8(
    const unsigned char* __restrict__ srcA,
    const unsigned char* __restrict__ srcB,
    int rowBase, int colBase,
    unsigned char* lds, f32x4 (&acc)[4][4],
    unsigned sa, unsigned sb)
{
    const int t = threadIdx.x, w = t >> 6, l = t & 63;
    const int wr = w >> 1, wc = w & 1;
    const int lr = l & 15;
    const int sw = (l & 7) << 4;
    const int aRB = (wr*64 + lr) * 128;
    const int bRB = (wc*64 + lr) * 128;
    const int g0 = (l >> 4) * 32;
    const int cc0 = g0 ^ sw;
    const int cc1 = (g0 + 16) ^ sw;

    unsigned char* sA[2] = { lds,        lds + 2*TB };
    unsigned char* sB[2] = { lds + TB,   lds + 3*TB };

    stage128_fp8(srcA, rowBase, 0,   sA[0], w, l);
    stage128_fp8(srcB, colBase, 0,   sB[0], w, l);
    stage128_fp8(srcA, rowBase, 128, sA[1], w, l);
    stage128_fp8(srcB, colBase, 128, sB[1], w, l);
    asm volatile("s_waitcnt vmcnt(8)" ::: "memory");
    wg_barrier();

    for (int kt = 0; kt < NT_K8; ++kt) {
        const char* bufA = (const char*)sA[kt & 1];
        const char* bufB = (const char*)sB[kt & 1];
        int8v b8[4];
        #pragma unroll
        for (int ni = 0; ni < 4; ++ni)
            b8[ni] = __builtin_shufflevector(
                *(const int4v*)(bufB + bRB + ni*2048 + cc0),
                *(const int4v*)(bufB + bRB + ni*2048 + cc1),
                0, 1, 2, 3, 4, 5, 6, 7);
        #pragma unroll
        for (int mi = 0; mi < 4; ++mi) {
            int8v a8 = __builtin_shufflevector(
                *(const int4v*)(bufA + aRB + mi*2048 + cc0),
                *(const int4v*)(bufA + aRB + mi*2048 + cc1),
                0, 1, 2, 3, 4, 5, 6, 7);
            #pragma unroll
            for (int ni = 0; ni < 4; ++ni)
                acc[mi][ni] = __builtin_amdgcn_mfma_scale_f32_16x16x128_f8f6f4(
                    a8, b8[ni], acc[mi][ni], 0, 0, 0, sa, 0, sb);
        }
        if (kt == NT_K8 - 1) break;
        wg_barrier();
        if (kt + 2 < NT_K8) {
            stage128_fp8(srcA, rowBase, (kt+2)*128, sA[kt&1], w, l);
            stage128_fp8(srcB, colBase, (kt+2)*128, sB[kt&1], w, l);
            asm volatile("s_waitcnt vmcnt(8)" ::: "memory");
        } else {
            asm volatile("s_waitcnt vmcnt(0)" ::: "memory");
        }
        wg_barrier();
    }
}

// ================= 256^2 bf16 pipeline (FF only; round-14 proven) =================
__device__ __forceinline__ void stage256_bf16(
    const unsigned short* __restrict__ src, int R0, int kcol0,
    unsigned short* ldsDst, int w, int lane)
{
    const int rsub = lane >> 3;
    const int csw  = 8 * ((lane & 7) ^ rsub);
    #pragma unroll
    for (int s = 0; s < 4; ++s) {
        const int r = (s*8 + w)*8 + rsub;
        __builtin_amdgcn_global_load_lds(
            (glob_void*)(src + (size_t)(R0 + r) * HDIM + kcol0 + csw),
            (lds_void*)(ldsDst + (s*8 + w)*512), 16, 0, 0);
    }
}

__device__ __forceinline__ void pipe256_bf16(
    const unsigned short* __restrict__ srcA,
    const unsigned short* __restrict__ srcB,
    int rowBase, int colBase,
    unsigned short* lds, f32x4 (&acc)[8][4])
{
    const int t = threadIdx.x, w = t >> 6, l = t & 63;
    const int wr = w >> 2, wc = w & 3;
    const int lr = l & 15;
    const int sw = (l & 7) << 4;
    const int aRB = (wr*128 + lr) * 128;
    const int bRB = (wc*64  + lr) * 128;
    const int c0 = ((l >> 4) * 16) ^ sw;
    const int c1 = (64 + ((l >> 4) * 16)) ^ sw;

    unsigned short* sA[2] = { lds,            lds + 2*SLOT2 };
    unsigned short* sB[2] = { lds + SLOT2,    lds + 3*SLOT2 };

    stage256_bf16(srcA, rowBase, 0,  sA[0], w, l);
    stage256_bf16(srcB, colBase, 0,  sB[0], w, l);
    stage256_bf16(srcA, rowBase, BK, sA[1], w, l);
    stage256_bf16(srcB, colBase, BK, sB[1], w, l);
    asm volatile("s_waitcnt vmcnt(8)" ::: "memory");
    wg_barrier();

    for (int kt = 0; kt < NT_K; ++kt) {
        const char* bufA = (const char*)sA[kt & 1];
        const char* bufB = (const char*)sB[kt & 1];
        #pragma unroll
        for (int kk = 0; kk < 2; ++kk) {
            const int cc = kk ? c1 : c0;
            short8 af[8], bfr[4];
            #pragma unroll
            for (int mi = 0; mi < 8; ++mi)
                af[mi] = *(const short8*)(bufA + aRB + mi*2048 + cc);
            #pragma unroll
            for (int ni = 0; ni < 4; ++ni)
                bfr[ni] = *(const short8*)(bufB + bRB + ni*2048 + cc);
            #pragma unroll
            for (int mi = 0; mi < 8; ++mi)
                #pragma unroll
                for (int ni = 0; ni < 4; ++ni)
                    acc[mi][ni] = __builtin_amdgcn_mfma_f32_16x16x32_bf16(
                        af[mi], bfr[ni], acc[mi][ni], 0, 0, 0);
        }
        if (kt == NT_K - 1) break;
        wg_barrier();
        if (kt + 2 < NT_K) {
            stage256_bf16(srcA, rowBase, (kt+2)*BK, sA[kt&1], w, l);
            stage256_bf16(srcB, colBase, (kt+2)*BK, sB[kt&1], w, l);
            asm volatile("s_waitcnt vmcnt(8)" ::: "memory");
        } else {
            asm volatile("s_waitcnt vmcnt(0)" ::: "memory");
        }
        wg_barrier();
    }
}

// ---- FF GEMM (bf16, 256^2): C = bf16(A @ Bt^T + bias) ----
__global__ __launch_bounds__(NTHR2, 2) void gemm_ff(
    const unsigned short* __restrict__ A,
    const unsigned short* __restrict__ Bt,
    const float* __restrict__ bias,
    unsigned short* __restrict__ C, int gx)
{
    __shared__ __align__(16) unsigned short lds[4 * SLOT2];   // 128 KiB
    const int nwg = gridDim.x, bid = blockIdx.x;
    const int swz = (bid & 7) * (nwg >> 3) + (bid >> 3);
    const int bx = swz % gx, by = swz / gx;
    const int rowBase = by * BM2, colBase = bx * BM2;

    f32x4 acc[8][4] = {};
    pipe256_bf16(A, Bt, rowBase, colBase, lds, acc);

    const int t = threadIdx.x, w = t >> 6, l = t & 63;
    const int wr = w >> 2, wc = w & 3;
    const int lr = l & 15;

    #pragma unroll
    for (int ni = 0; ni < 4; ++ni) {
        const int col = colBase + wc*64 + ni*16 + lr;
        const float bv = bias[col];
        #pragma unroll
        for (int mi = 0; mi < 8; ++mi) {
            const int row0 = rowBase + wr*128 + mi*16 + (l >> 4) * 4;
            #pragma unroll
            for (int j = 0; j < 4; ++j)
                C[(size_t)(row0 + j) * HDIM + col] = f2bf(acc[mi][ni][j] + bv);
        }
    }
}

// ---- Wqk split-K (128^2): 64 tiles x 4 K-slices; f32 partial slabs ----
__global__ __launch_bounds__(NTHR) void gemm_wqk_splitk(
    const unsigned short* __restrict__ Wkb,
    const unsigned short* __restrict__ Wqb,
    float* __restrict__ slabs)
{
    __shared__ __align__(16) unsigned short lds[2 * TB];
    const int bid = blockIdx.x;      // 256
    const int kz = bid & 3, tile = bid >> 2;
    const int rowBase = (tile >> 3) * BM, colBase = (tile & 7) * BM;

    f32x4 acc[4][4] = {};
    pipe128_bf16(Wkb, Wqb, rowBase, colBase, kz * (HDIM/4), NT_K/4, lds, acc);

    float* out = slabs + (size_t)kz * HDIM * HDIM;
    const int t = threadIdx.x, w = t >> 6, l = t & 63;
    const int wr = w >> 1, wc = w & 1;
    const int lr = l & 15;

    #pragma unroll
    for (int ni = 0; ni < 4; ++ni) {
        const int col = colBase + wc*64 + ni*16 + lr;
        #pragma unroll
        for (int mi = 0; mi < 4; ++mi) {
            const int row0 = rowBase + wr*64 + mi*16 + (l >> 4) * 4;
            #pragma unroll
            for (int j = 0; j < 4; ++j)
                out[(size_t)(row0 + j) * HDIM + col] = acc[mi][ni][j];
        }
    }
}

// ---- sum 4 slabs, scale x64, write fp8 ----
__global__ __launch_bounds__(256) void wqk_reduce_cast(
    const float* __restrict__ slabs, unsigned char* __restrict__ out8)
{
    const size_t WEl = (size_t)HDIM * HDIM;
    const size_t i = ((size_t)blockIdx.x * 256 + threadIdx.x) * 4;
    float4 a = *reinterpret_cast<const float4*>(slabs + i);
    float4 b = *reinterpret_cast<const float4*>(slabs + WEl + i);
    float4 c = *reinterpret_cast<const float4*>(slabs + 2*WEl + i);
    float4 d = *reinterpret_cast<const float4*>(slabs + 3*WEl + i);
    unsigned wd = pack4_fp8(64.f*(a.x+b.x+c.x+d.x), 64.f*(a.y+b.y+c.y+d.y),
                            64.f*(a.z+b.z+c.z+d.z), 64.f*(a.w+b.w+c.w+d.w));
    *reinterpret_cast<unsigned*>(out8 + i) = wd;
}

// ---- fp8 fused proj (128^2): [Xq8 | V8] = fp8( al * (Xb8 @ W8^T + bias) ) ----
__global__ __launch_bounds__(NTHR) void gemm_proj_fp8(
    const unsigned char* __restrict__ A,
    const unsigned char* __restrict__ Bt,
    const float* __restrict__ bias0, const float* __restrict__ bias1,
    unsigned char* __restrict__ C0, unsigned char* __restrict__ C1,
    float al0, float al1, unsigned sb0, unsigned sb1, int gx)
{
    __shared__ __align__(16) unsigned char lds8[4 * TB];
    const int nwg = gridDim.x, bid = blockIdx.x;
    const int swz = (bid & 7) * (nwg >> 3) + (bid >> 3);
    const int bx = swz % gx, by = swz / gx;
    const int rowBase = by * BM, colBase = bx * BM;

    const int mat = colBase >> 10;

    f32x4 acc[4][4] = {};
    pipe128_fp8(A, Bt, rowBase, colBase, lds8, acc,
                0x7F7F7F7Fu, mat ? sb1 : sb0);

    const int t = threadIdx.x, w = t >> 6, l = t & 63;
    const int wr = w >> 1, wc = w & 1;
    const int lr = l & 15;

    unsigned char* Cm  = mat ? C1 : C0;
    const float* bm    = mat ? bias1 : bias0;
    const float am     = mat ? al1 : al0;
    const int lcb = colBase & (HDIM - 1);

    #pragma unroll
    for (int ni = 0; ni < 4; ++ni) {
        const int col = lcb + wc*64 + ni*16 + lr;
        const float bv = bm[col];
        #pragma unroll
        for (int mi = 0; mi < 4; ++mi) {
            const int row0 = rowBase + wr*64 + mi*16 + (l >> 4) * 4;
            const unsigned wd = pack4_fp8(
                am * (acc[mi][ni][0] + bv), am * (acc[mi][ni][1] + bv),
                am * (acc[mi][ni][2] + bv), am * (acc[mi][ni][3] + bv));
            #pragma unroll
            for (int j = 0; j < 4; ++j)
                Cm[(size_t)(row0 + j) * HDIM + col] = (unsigned char)(wd >> (8*j));
        }
    }
}

// ---- fp8 qk (128^2), batch-per-XCD grid: bid&7 = batch ----
__global__ __launch_bounds__(NTHR) void qk_colsum_diag_fp8(
    const unsigned char* __restrict__ Xq8,
    const unsigned char* __restrict__ Xb8,
    const float* __restrict__ uvec,
    float* __restrict__ colsum, float* __restrict__ diagv)
{
    __shared__ __align__(16) unsigned char lds8[4 * TB];
    const int bid = blockIdx.x;          // 2048
    const int n = bid & 7;
    const int rem = bid >> 3;            // 0..255
    const int rowBase = (rem & 15) * BM;
    const int colBase = (rem >> 4) * BM;
    const unsigned char* An = Xq8 + (size_t)n * LLEN * HDIM;
    const unsigned char* Bn = Xb8 + (size_t)n * LLEN * HDIM;

    f32x4 acc[4][4] = {};
    pipe128_fp8(An, Bn, rowBase, colBase, lds8, acc,
                0x75757575u, 0x7F7F7F7Fu);

    const int t = threadIdx.x, w = t >> 6, l = t & 63;
    const int wr = w >> 1, wc = w & 1;
    const int lr = l & 15;

    float ur[4][4];
    #pragma unroll
    for (int mi = 0; mi < 4; ++mi)
        #pragma unroll
        for (int j = 0; j < 4; ++j)
            ur[mi][j] = uvec[(size_t)n * LLEN + rowBase + wr*64 + mi*16 + (l>>4)*4 + j];

    #pragma unroll
    for (int ni = 0; ni < 4; ++ni) {
        float s = 0.f;
        #pragma unroll
        for (int mi = 0; mi < 4; ++mi)
            #pragma unroll
            for (int j = 0; j < 4; ++j)
                s += __expf(acc[mi][ni][j] + ur[mi][j]);
        s += __shfl_xor(s, 16);
        s += __shfl_xor(s, 32);
        if (l < 16)
            atomicAdd(&colsum[(size_t)n * LLEN + colBase + wc*64 + ni*16 + l], s);
    }

    if (rowBase == colBase && wr == wc) {
        #pragma unroll
        for (int mi = 0; mi < 4; ++mi)
            #pragma unroll
            for (int ni = 0; ni < 4; ++ni)
                #pragma unroll
                for (int j = 0; j < 4; ++j) {
                    const int rr = wr*64 + mi*16 + (l >> 4)*4 + j;
                    const int cc = wc*64 + ni*16 + lr;
                    if (rr == cc)
                        diagv[(size_t)n * LLEN + rowBase + rr] = acc[mi][ni][j];
                }
    }
}

// ---- X f32 -> Xb bf16 + Xb8 fp8, single pass ----
__global__ __launch_bounds__(256) void cast_x_dual(
    const float* __restrict__ in, unsigned short* __restrict__ outb,
    unsigned char* __restrict__ out8, int n8)
{
    int i = blockIdx.x * 256 + threadIdx.x;
    if (i >= n8) return;
    const float4* p = reinterpret_cast<const float4*>(in) + (size_t)i * 2;
    float4 a = p[0], b = p[1];
    short8 o;
    o[0] = (short)f2bf(a.x); o[1] = (short)f2bf(a.y);
    o[2] = (short)f2bf(a.z); o[3] = (short)f2bf(a.w);
    o[4] = (short)f2bf(b.x); o[5] = (short)f2bf(b.y);
    o[6] = (short)f2bf(b.z); o[7] = (short)f2bf(b.w);
    unsigned w0 = pack4_fp8(a.x, a.y, a.z, a.w);
    unsigned w1 = pack4_fp8(b.x, b.y, b.z, b.w);
    *(reinterpret_cast<short8*>(outb) + i) = o;
    uint2 pk; pk.x = w0; pk.y = w1;
    *(reinterpret_cast<uint2*>(out8) + i) = pk;
}

// ---- Wq,Wk f32 -> bf16 (blockIdx.y selects) ----
__global__ __launch_bounds__(256) void cast_w2(
    const float* __restrict__ W0, const float* __restrict__ W1,
    unsigned short* __restrict__ out0, unsigned short* __restrict__ out1, int n8)
{
    int i = blockIdx.x * 256 + threadIdx.x;
    if (i >= n8) return;
    const float* in = blockIdx.y ? W1 : W0;
    unsigned short* outp = blockIdx.y ? out1 : out0;
    const float4* p = reinterpret_cast<const float4*>(in) + (size_t)i * 2;
    float4 a = p[0], b = p[1];
    short8 o;
    o[0] = (short)f2bf(a.x); o[1] = (short)f2bf(a.y);
    o[2] = (short)f2bf(a.z); o[3] = (short)f2bf(a.w);
    o[4] = (short)f2bf(b.x); o[5] = (short)f2bf(b.y);
    o[6] = (short)f2bf(b.z); o[7] = (short)f2bf(b.w);
    *(reinterpret_cast<short8*>(outp) + i) = o;
}

// ---- W (K x N fp32) -> bf16 N x K ----
__global__ __launch_bounds__(256) void transpose_cast_bf16(
    const float* __restrict__ W, unsigned short* __restrict__ Wt)
{
    __shared__ float tile[32][33];
    const int tx = threadIdx.x & 31, ty = threadIdx.x >> 5;
    const int c0 = blockIdx.x * 32, r0 = blockIdx.y * 32;
    #pragma unroll
    for (int r = 0; r < 4; ++r)
        tile[ty + r*8][tx] = W[(size_t)(r0 + ty + r*8) * HDIM + c0 + tx];
    __syncthreads();
    #pragma unroll
    for (int r = 0; r < 4; ++r)
        Wt[(size_t)(c0 + ty + r*8) * HDIM + r0 + tx] = f2bf(tile[tx][ty + r*8]);
}

// ---- W (K x N fp32) -> fp8 N x K, value scaled ----
__global__ __launch_bounds__(256) void transpose_cast_fp8(
    const float* __restrict__ W, unsigned char* __restrict__ Wt, float scale)
{
    __shared__ float tile[32][33];
    const int tx = threadIdx.x & 31, ty = threadIdx.x >> 5;
    const int c0 = blockIdx.x * 32, r0 = blockIdx.y * 32;
    #pragma unroll
    for (int r = 0; r < 4; ++r)
        tile[ty + r*8][tx] = W[(size_t)(r0 + ty + r*8) * HDIM + c0 + tx];
    __syncthreads();
    #pragma unroll
    for (int r = 0; r < 4; ++r)
        Wt[(size_t)(c0 + ty + r*8) * HDIM + r0 + tx] = f2fp8(tile[tx][ty + r*8] * scale);
}

// ---- p[i] = Wq[i,:] . bk ----
__global__ __launch_bounds__(256) void pvec_kernel(
    const float* __restrict__ Wq, const float* __restrict__ bk,
    float* __restrict__ p)
{
    const int row = blockIdx.x * 4 + (threadIdx.x >> 6);
    const int l = threadIdx.x & 63;
    float s = 0.f;
    #pragma unroll
    for (int c = 0; c < HDIM; c += 64)
        s += Wq[(size_t)row * HDIM + c + l] * bk[c + l];
    #pragma unroll
    for (int off = 32; off > 0; off >>= 1) s += __shfl_down(s, off);
    if (l == 0) p[row] = s;
}

// ---- u[a] = sc2 * Xb[a,:] . p ----
__global__ __launch_bounds__(256) void uvec_kernel(
    const unsigned short* __restrict__ Xb, const float* __restrict__ p,
    float* __restrict__ u, float sc2)
{
    const int row = blockIdx.x * 4 + (threadIdx.x >> 6);
    const int l = threadIdx.x & 63;
    const unsigned short* xr = Xb + (size_t)row * HDIM + l * 16;
    float s = 0.f;
    #pragma unroll
    for (int k = 0; k < 2; ++k) {
        short8 v = *reinterpret_cast<const short8*>(xr + k*8);
        #pragma unroll
        for (int j = 0; j < 8; ++j)
            s += bf2f((unsigned short)v[j]) * p[l*16 + k*8 + j];
    }
    #pragma unroll
    for (int off = 32; off > 0; off >>= 1) s += __shfl_down(s, off);
    if (l == 0) u[row] = s * sc2;
}

// ---- h1 = bf16( LN(diag*V8 + Xb) * g1 + b1 ) ----
__global__ __launch_bounds__(256) void ln1_kernel(
    const unsigned char* __restrict__ V8, const unsigned short* __restrict__ Xbp,
    const float* __restrict__ colsum, const float* __restrict__ diagval,
    const float* __restrict__ uvec,
    const float* __restrict__ g1, const float* __restrict__ b1,
    unsigned short* __restrict__ h1)
{
    const int row = blockIdx.x;
    const size_t base = (size_t)row * HDIM;
    const float dv = __expf(diagval[row] + uvec[row]) / colsum[row];
    const int h0 = threadIdx.x * 4;

    unsigned vv = *reinterpret_cast<const unsigned*>(&V8[base + h0]);
    ushort4v xx = *reinterpret_cast<const ushort4v*>(&Xbp[base + h0]);
    float y[4];
    y[0] = dv * fp8d((unsigned char)(vv      )) + bf2f(xx[0]);
    y[1] = dv * fp8d((unsigned char)(vv >>  8)) + bf2f(xx[1]);
    y[2] = dv * fp8d((unsigned char)(vv >> 16)) + bf2f(xx[2]);
    y[3] = dv * fp8d((unsigned char)(vv >> 24)) + bf2f(xx[3]);

    float s = y[0]+y[1]+y[2]+y[3];
    float s2 = y[0]*y[0]+y[1]*y[1]+y[2]*y[2]+y[3]*y[3];
    #pragma unroll
    for (int off = 32; off > 0; off >>= 1) {
        s  += __shfl_down(s,  off);
        s2 += __shfl_down(s2, off);
    }
    __shared__ float ws1[4], ws2[4];
    const int wid = threadIdx.x >> 6;
    if ((threadIdx.x & 63) == 0) { ws1[wid] = s; ws2[wid] = s2; }
    __syncthreads();
    const float S  = ws1[0]+ws1[1]+ws1[2]+ws1[3];
    const float S2 = ws2[0]+ws2[1]+ws2[2]+ws2[3];
    const float m   = S  * (1.0f / HDIM);
    const float var = S2 * (1.0f / HDIM) - m*m;
    const float inv = rsqrtf(var + LNEPS);

    float4 gg = *reinterpret_cast<const float4*>(&g1[h0]);
    float4 bb = *reinterpret_cast<const float4*>(&b1[h0]);
    ushort4v o;
    o[0] = f2bf((y[0]-m)*inv*gg.x + bb.x);
    o[1] = f2bf((y[1]-m)*inv*gg.y + bb.y);
    o[2] = f2bf((y[2]-m)*inv*gg.z + bb.z);
    o[3] = f2bf((y[3]-m)*inv*gg.w + bb.w);
    *reinterpret_cast<ushort4v*>(&h1[base + h0]) = o;
}

// ---- out = fp32( LN(G + h1) * g2 + b2 ) ----
__global__ __launch_bounds__(256) void ln2_kernel(
    const unsigned short* __restrict__ Gb, const unsigned short* __restrict__ h1b,
    const float* __restrict__ g2, const float* __restrict__ b2,
    float* __restrict__ out)
{
    const int row = blockIdx.x;
    const size_t base = (size_t)row * HDIM;
    const int h0 = threadIdx.x * 4;

    ushort4v gv = *reinterpret_cast<const ushort4v*>(&Gb[base + h0]);
    ushort4v hv = *reinterpret_cast<const ushort4v*>(&h1b[base + h0]);
    float y[4];
    y[0] = bf2f(gv[0]) + bf2f(hv[0]); y[1] = bf2f(gv[1]) + bf2f(hv[1]);
    y[2] = bf2f(gv[2]) + bf2f(hv[2]); y[3] = bf2f(gv[3]) + bf2f(hv[3]);

    float s = y[0]+y[1]+y[2]+y[3];
    float s2 = y[0]*y[0]+y[1]*y[1]+y[2]*y[2]+y[3]*y[3];
    #pragma unroll
    for (int off = 32; off > 0; off >>= 1) {
        s  += __shfl_down(s,  off);
        s2 += __shfl_down(s2, off);
    }
    __shared__ float ws1[4], ws2[4];
    const int wid = threadIdx.x >> 6;
    if ((threadIdx.x & 63) == 0) { ws1[wid] = s; ws2[wid] = s2; }
    __syncthreads();
    const float S  = ws1[0]+ws1[1]+ws1[2]+ws1[3];
    const float S2 = ws2[0]+ws2[1]+ws2[2]+ws2[3];
    const float m   = S  * (1.0f / HDIM);
    const float var = S2 * (1.0f / HDIM) - m*m;
    const float inv = rsqrtf(var + LNEPS);

    float4 gg = *reinterpret_cast<const float4*>(&g2[h0]);
    float4 bb = *reinterpret_cast<const float4*>(&b2[h0]);
    float4 o;
    o.x = (y[0]-m)*inv*gg.x + bb.x;
    o.y = (y[1]-m)*inv*gg.y + bb.y;
    o.z = (y[2]-m)*inv*gg.z + bb.z;
    o.w = (y[3]-m)*inv*gg.w + bb.w;
    *reinterpret_cast<float4*>(&out[base + h0]) = o;
}

extern "C" void kernel_launch(void* const* d_in, const int* in_sizes, int n_in,
                              void* d_out, int out_size, void* d_ws, size_t ws_size,
                              hipStream_t stream) {
    (void)in_sizes; (void)n_in; (void)out_size; (void)ws_size;
    const float* X  = (const float*)d_in[0];
    const float* Wq = (const float*)d_in[1];
    const float* bq = (const float*)d_in[2];   (void)bq; // cancels in diag/colsum ratio
    const float* Wk = (const float*)d_in[3];
    const float* bk = (const float*)d_in[4];
    const float* Wv = (const float*)d_in[5];
    const float* bv = (const float*)d_in[6];
    const float* Wf = (const float*)d_in[7];
    const float* bf = (const float*)d_in[8];
    const float* g1 = (const float*)d_in[9];
    const float* b1 = (const float*)d_in[10];
    const float* g2 = (const float*)d_in[11];
    const float* b2 = (const float*)d_in[12];
    float* out = (float*)d_out;

    const size_t MATE = (size_t)NB * LLEN * HDIM;   // 16,777,216 elements
    const size_t WE   = (size_t)HDIM * HDIM;

    // d_out staging: Xb bf16 [0,32MiB), V8 fp8 [32,48MiB). Dead before ln2 writes out.
    unsigned short* Xb  = (unsigned short*)d_out;
    unsigned char*  V8  = (unsigned char*)(Xb + MATE);

    unsigned short* h1b   = (unsigned short*)d_ws;      // 32 MiB
    unsigned short* Gb    = h1b + MATE;                 // 32 MiB
    unsigned short* WfT   = Gb + MATE;                  // 2 MiB
    unsigned short* Wqb   = WfT + WE;                   // 2 MiB
    unsigned short* Wkb   = Wqb + WE;                   // 2 MiB
    unsigned char*  Wqk8T = (unsigned char*)(Wkb + WE); // 1 MiB; [Wqk8T|Wv8T] contiguous
    unsigned char*  Wv8T  = Wqk8T + WE;                 // 1 MiB
    // colsum..zvec: one contiguous memset region (diagv/pv/uv fully overwritten later)
    float* colsum = (float*)(Wv8T + WE);                // 64 KiB
    float* diagv  = colsum + (size_t)NB * LLEN;         // 64 KiB
    float* pv     = diagv + (size_t)NB * LLEN;          // 4 KiB
    float* uv     = pv + HDIM;                          // 64 KiB
    float* zvec   = uv + (size_t)NB * LLEN;             // 4 KiB
    unsigned char* Xq8 = (unsigned char*)(zvec + HDIM); // 16 MiB
    unsigned char* Xb8 = Xq8 + MATE;                    // 16 MiB
    float* wqkSlabs = (float*)(Xb8 + MATE);             // 16 MiB (4 x f32 1024^2)

    const int M = NB * LLEN;            // 16384
    const float sc2 = 1.0f / 1024.0f;   // (1/sqrt(H))^2

    const size_t mset = (3*(size_t)NB*LLEN + 2*HDIM) * sizeof(float);
    hipMemsetAsync(colsum, 0, mset, stream);

    cast_x_dual<<<(int)(MATE/8) / 256, 256, 0, stream>>>(X, Xb, Xb8, (int)(MATE/8));
    {
        dim3 cg((int)(WE/8) / 256, 2);
        cast_w2<<<cg, 256, 0, stream>>>(Wq, Wk, Wqb, Wkb, (int)(WE/8));
    }
    {
        dim3 tgrid(HDIM / 32, HDIM / 32);
        transpose_cast_bf16<<<tgrid, 256, 0, stream>>>(Wf, WfT);
        transpose_cast_fp8<<<tgrid, 256, 0, stream>>>(Wv, Wv8T, 16.0f);   // x2^4
    }

    // Wqk split-K (128^2): 256 blocks -> f32 slabs -> x64 fp8
    gemm_wqk_splitk<<<256, NTHR, 0, stream>>>(Wkb, Wqb, wqkSlabs);
    wqk_reduce_cast<<<(int)(WE/4) / 256, 256, 0, stream>>>(wqkSlabs, Wqk8T);

    // u'[a] = sc2 * X[a,:].(Wq @ bk)
    pvec_kernel<<<HDIM / 4, 256, 0, stream>>>(Wq, bk, pv);
    uvec_kernel<<<M / 4, 256, 0, stream>>>(Xb, pv, uv, sc2);

    // fp8 fused proj (128^2): [Xq8 | V8] = Xb8 @ [Wqk8T | Wv8T]^T
    // mat0: sb=2^-16 (Wqk x2^16 = x64/sc2), epilogue x1024 -> Xq8 (qk sa=2^-10 undoes)
    // mat1: sb=2^-4  (Wv  x2^4),            epilogue +bv   -> V8
    {
        const int gx = 2 * HDIM / BM;       // 16
        const int nwg = gx * (M / BM);      // 2048 (%8==0)
        gemm_proj_fp8<<<nwg, NTHR, 0, stream>>>(Xb8, Wqk8T, zvec, bv,
                                                Xq8, V8, 1024.0f, 1.0f,
                                                0x6F6F6F6Fu /*2^-16*/,
                                                0x7B7B7B7Bu /*2^-4*/, gx);
    }

    // qk (128^2): 2048 blocks, bid&7 = batch -> per-XCD L2 residency
    qk_colsum_diag_fp8<<<2048, NTHR, 0, stream>>>(Xq8, Xb8, uv, colsum, diagv);

    ln1_kernel<<<M, 256, 0, stream>>>(V8, Xb, colsum, diagv, uv, g1, b1, h1b);

    // FF GEMM (bf16, 256^2 — the faster structure for the 16-K-tile bf16 loop)
    {
        const int gx = HDIM / BM2;          // 4
        const int nwg = gx * (M / BM2);     // 256
        gemm_ff<<<nwg, NTHR2, 0, stream>>>(h1b, WfT, bf, Gb, gx);
    }

    ln2_kernel<<<M, 256, 0, stream>>>(Gb, h1b, g2, b2, out);
}